// Round 11
// baseline (1835.628 us; speedup 1.0000x reference)
//
#include <hip/hip_runtime.h>

typedef unsigned short US;
typedef unsigned int   UI;
typedef short  short8 __attribute__((ext_vector_type(8)));
typedef US     u16x8  __attribute__((ext_vector_type(8)));
typedef float  f32x4  __attribute__((ext_vector_type(4)));

#define DEVI __device__ __forceinline__

DEVI float bf2f(US u){ UI i = ((UI)u) << 16; float f; __builtin_memcpy(&f, &i, 4); return f; }
DEVI US f2bf(float x){ UI i; __builtin_memcpy(&i, &x, 4); UI r = (i + 0x7FFFu + ((i >> 16) & 1u)) >> 16; return (US)r; }
// gelu via tanh-form written as sigmoid: x * sigmoid(1.5957691*(x + 0.044715 x^3))
DEVI float gelu_f(float x){
    float x2 = x * x;
    float u  = x * fmaf(x2, 0.0713548193f, 1.5957691216f);
    float e  = __expf(-u);
    return x / (1.0f + e);
}
DEVI UI encf(float f){ UI u; __builtin_memcpy(&u, &f, 4); return (u & 0x80000000u) ? ~u : (u | 0x80000000u); }
DEVI float decf(UI u){ UI b = (u & 0x80000000u) ? (u ^ 0x80000000u) : ~u; float f; __builtin_memcpy(&f, &b, 4); return f; }
DEVI int swz(int r, int c, int ld){ int i = r * ld + c; return i ^ ((r & 7) << 3); }

// packed f32x2 -> bf16x2 (hardware RNE)
DEVI UI pkbf(float a, float b){ UI u; asm("v_cvt_pk_bf16_f32 %0, %1, %2" : "=v"(u) : "v"(a), "v"(b)); return u; }
DEVI void st4(US* T, int row, int col, float v0, float v1, float v2, float v3){
    uint2 p; p.x = pkbf(v0, v1); p.y = pkbf(v2, v3);
    *(uint2*)&T[swz(row, col, 256)] = p;
}
DEVI void ld4(const US* T, int row, int col, float& v0, float& v1, float& v2, float& v3){
    uint2 q = *(const uint2*)&T[swz(row, col, 256)];
    v0 = bf2f((US)(q.x & 0xffff)); v1 = bf2f((US)(q.x >> 16));
    v2 = bf2f((US)(q.y & 0xffff)); v3 = bf2f((US)(q.y >> 16));
}

// bf16 weight-buffer offsets (elements)
enum : int { O_EmW1 = 0, O_EmWh = 131072, O_EmWo = 147456, O_RhoW1 = 212992,
             O_RhoWh = 344064, O_RhoWo = 360448, O_Cat1 = 368640, O_Cat2 = 376832,
             O_Cat3 = 385024, O_H1W1 = 393216, O_H1Wh = 442368, O_H1Wo = 458752,
             O_H2W1 = 475136, O_H2Wh = 491520, W_TOTAL = 507904 };

// ---------------------------------------------------------------------------
// Double-buffered W-streaming stage (A from LDS). SWAP=true: C^T, thread
// holds 4 consecutive feature-cols of row lane&15. ONE barrier per kc.
// ---------------------------------------------------------------------------
template<int NT, int NKC, int NTHR, bool SWAP = false>
DEVI void stageWD(const US* __restrict__ Wg, int Kw, const US* __restrict__ A, int lda,
                  int ab0, int ab1, int ab2, int arow0, US* Wb, int tid, f32x4 (&acc)[NT])
{
    const int lane = tid & 63;
    const int wc = (tid >> 6) & 1;
    constexpr int SLAB = NT * 32 * 64;
    #pragma unroll
    for (int n = 0; n < NT; ++n) acc[n] = (f32x4){0.f, 0.f, 0.f, 0.f};
    constexpr int J = (NT * 256) / NTHR;
    u16x8 wreg[J];
    #pragma unroll
    for (int j = 0; j < J; ++j) {
        const int c = tid + NTHR * j;
        wreg[j] = *(const u16x8*)(Wg + (size_t)(c >> 3) * Kw + (c & 7) * 8);
    }
    #pragma unroll
    for (int j = 0; j < J; ++j) {
        const int c = tid + NTHR * j;
        *(u16x8*)&Wb[swz(c >> 3, (c & 7) * 8, 64)] = wreg[j];
    }
    #pragma unroll
    for (int kc = 0; kc < NKC; ++kc) {
        __syncthreads();            // slab kc&1 + prior-stage T1 visible
        if (kc + 1 < NKC) {
            #pragma unroll
            for (int j = 0; j < J; ++j) {
                const int c = tid + NTHR * j;
                wreg[j] = *(const u16x8*)(Wg + (size_t)(c >> 3) * Kw + (kc + 1) * 64 + (c & 7) * 8);
            }
        }
        const int ab = (kc == 0) ? ab0 : ((kc == 1) ? ab1 : ab2);
        const int bufr = (kc & 1) * SLAB;
        #pragma unroll
        for (int sub = 0; sub < 2; ++sub) {
            const int kk = sub * 32 + ((lane >> 4) << 3);
            short8 a = *(const short8*)&A[swz(arow0 + (lane & 15), ab + kk, lda)];
            #pragma unroll
            for (int n = 0; n < NT; ++n) {
                short8 b = *(const short8*)&Wb[bufr + swz(wc * (NT * 16) + n * 16 + (lane & 15), kk, 64)];
                if (SWAP) acc[n] = __builtin_amdgcn_mfma_f32_16x16x32_bf16(b, a, acc[n], 0, 0, 0);
                else      acc[n] = __builtin_amdgcn_mfma_f32_16x16x32_bf16(a, b, acc[n], 0, 0, 0);
            }
        }
        if (kc + 1 < NKC) {
            const int bufw = ((kc + 1) & 1) * SLAB;
            #pragma unroll
            for (int j = 0; j < J; ++j) {
                const int c = tid + NTHR * j;
                *(u16x8*)&Wb[bufw + swz(c >> 3, (c & 7) * 8, 64)] = wreg[j];
            }
        }
    }
    __syncthreads();                // all Wb/T1 reads done before reuse
}

// ---------------------------------------------------------------------------
// Fused embedder v2: 128 point-rows per block, 1024 threads (16 waves).
// S1: A-fragments DIRECT FROM GLOBAL x (8 consecutive f32 -> pkbf), SWAP'd,
// double-buffered Wb, 1 barrier/kc, packed st4 epilogue. No As buffer.
// LDS: T1 64KB + Wb 64KB = 128.5KB -> 1 block/CU, 16 waves.
// ---------------------------------------------------------------------------
__global__ __launch_bounds__(1024, 4)
void embed_fused(const float* __restrict__ x, const US* __restrict__ WB,
                 const float* __restrict__ b_in, const float* __restrict__ b_proj,
                 const float* __restrict__ b_hid, const float* __restrict__ b_out,
                 US* __restrict__ Ss)
{
    __shared__ __align__(16) US T1[128 * 256];
    __shared__ __align__(16) US Wb[2 * 16384];
    const int tid = threadIdx.x, lane = tid & 63, w = tid >> 6;
    const int wr = w >> 1, wc = w & 1;
    const int h = lane >> 4;
    const int grow0 = blockIdx.x * 128;
    const int rowT = wr * 16 + (lane & 15);

    { // ---- S1: [gelu(x@Wi+bi) | x@Wp+bp], K=512 (8 kc), SWAP ----
        f32x4 acc[8];
        #pragma unroll
        for (int n = 0; n < 8; ++n) acc[n] = (f32x4){0.f, 0.f, 0.f, 0.f};
        const float* xp = x + (size_t)(grow0 + rowT) * 512 + h * 8;
        float4 p00, p01, p10, p11;
        u16x8 wreg[2];
        auto loadA = [&](int kc) {
            p00 = *(const float4*)(xp + kc * 64);
            p01 = *(const float4*)(xp + kc * 64 + 4);
            p10 = *(const float4*)(xp + kc * 64 + 32);
            p11 = *(const float4*)(xp + kc * 64 + 36);
        };
        auto loadW = [&](int kc) {
            #pragma unroll
            for (int j = 0; j < 2; ++j) {
                const int c = tid + 1024 * j;
                wreg[j] = *(const u16x8*)(WB + O_EmW1 + (size_t)(c >> 3) * 512 + kc * 64 + (c & 7) * 8);
            }
        };
        auto writeW = [&](int buf) {
            #pragma unroll
            for (int j = 0; j < 2; ++j) {
                const int c = tid + 1024 * j;
                *(u16x8*)&Wb[buf * 16384 + swz(c >> 3, (c & 7) * 8, 64)] = wreg[j];
            }
        };
        loadA(0); loadW(0); writeW(0);
        for (int kc = 0; kc < 8; ++kc) {
            __syncthreads();        // slab kc&1 visible
            short8 a0, a1;
            {
                uint4 q;
                q.x = pkbf(p00.x, p00.y); q.y = pkbf(p00.z, p00.w);
                q.z = pkbf(p01.x, p01.y); q.w = pkbf(p01.z, p01.w);
                __builtin_memcpy(&a0, &q, 16);
                q.x = pkbf(p10.x, p10.y); q.y = pkbf(p10.z, p10.w);
                q.z = pkbf(p11.x, p11.y); q.w = pkbf(p11.z, p11.w);
                __builtin_memcpy(&a1, &q, 16);
            }
            if (kc < 7) { loadA(kc + 1); loadW(kc + 1); }
            const int bufr = (kc & 1) * 16384;
            #pragma unroll
            for (int n = 0; n < 8; ++n) {
                short8 b = *(const short8*)&Wb[bufr + swz(wc * 128 + n * 16 + (lane & 15), h * 8, 64)];
                acc[n] = __builtin_amdgcn_mfma_f32_16x16x32_bf16(b, a0, acc[n], 0, 0, 0);
            }
            #pragma unroll
            for (int n = 0; n < 8; ++n) {
                short8 b = *(const short8*)&Wb[bufr + swz(wc * 128 + n * 16 + (lane & 15), 32 + h * 8, 64)];
                acc[n] = __builtin_amdgcn_mfma_f32_16x16x32_bf16(b, a1, acc[n], 0, 0, 0);
            }
            if (kc < 7) writeW((kc + 1) & 1);
        }
        #pragma unroll
        for (int n = 0; n < 8; ++n) {
            const int col = wc * 128 + n * 16 + h * 4;
            float4 bv = (col < 128) ? *(const float4*)&b_in[col]
                                    : *(const float4*)&b_proj[col - 128];
            float v0 = acc[n][0] + bv.x, v1 = acc[n][1] + bv.y;
            float v2 = acc[n][2] + bv.z, v3 = acc[n][3] + bv.w;
            if (col < 128) { v0 = gelu_f(v0); v1 = gelu_f(v1); v2 = gelu_f(v2); v3 = gelu_f(v3); }
            st4(T1, rowT, col, v0, v1, v2, v3);
        }
    }
    { // ---- S2: U = s + gelu(t1@Wh+bh) -> T1 lo, SWAP ----
        f32x4 acc[4];
        stageWD<4, 2, 1024, true>(WB + O_EmWh, 128, T1, 256, 0, 64, 0, wr * 16, Wb, tid, acc);
        #pragma unroll
        for (int n = 0; n < 4; ++n) {
            const int col = wc * 64 + n * 16 + h * 4;
            float4 bv = *(const float4*)&b_hid[col];
            float s0, s1, s2, s3;
            ld4(T1, rowT, 128 + col, s0, s1, s2, s3);
            st4(T1, rowT, col,
                gelu_f(acc[n][0] + bv.x) + s0, gelu_f(acc[n][1] + bv.y) + s1,
                gelu_f(acc[n][2] + bv.z) + s2, gelu_f(acc[n][3] + bv.w) + s3);
        }
    }
    // ---- S3: 2 merged passes (NT=8, 256 cols each), sum8 epilogue ----
    for (int p2 = 0; p2 < 2; ++p2) {
        f32x4 acc[8];
        stageWD<8, 2, 1024>(WB + O_EmWo + (size_t)(p2 * 256) * 128, 128, T1, 256, 0, 64, 0, wr * 16, Wb, tid, acc);
        #pragma unroll
        for (int n = 0; n < 8; ++n) {
            const int col = wc * 128 + n * 16 + (lane & 15);
            const float bv = b_out[p2 * 256 + col];
            float s = 0.f;
            #pragma unroll
            for (int r = 0; r < 4; ++r) s += gelu_f(acc[n][r] + bv);
            s += __shfl_xor(s, 16);
            if (((lane >> 4) & 1) == 0) {
                const int node = (grow0 >> 3) + wr * 2 + (lane >> 5);
                Ss[(size_t)node * 512 + p2 * 256 + col] = f2bf(s);
            }
        }
    }
}

// ---------------------------------------------------------------------------
// Fused rho v2: 64 nodes per block, 512 threads. S1 A-fragments direct from
// Ss (bf16 16B loads), SWAP + packed epilogue; single-buffered Wb (2 bar/kc,
// trailing bar). S2 SWAP. S3 unchanged. LDS: T1 32KB + Wb 32KB = 64.5KB.
// ---------------------------------------------------------------------------
__global__ __launch_bounds__(512, 2)
void rho_fused(const US* __restrict__ Ss, const US* __restrict__ WB,
               const float* __restrict__ b_in, const float* __restrict__ b_proj,
               const float* __restrict__ b_hid, const float* __restrict__ b_out,
               US* __restrict__ zo, int N)
{
    __shared__ __align__(16) US T1[64 * 256];
    __shared__ __align__(16) US Wb[256 * 64];
    const int tid = threadIdx.x, lane = tid & 63, w = tid >> 6;
    const int wr = w >> 1, wc = w & 1;
    const int h = lane >> 4;
    const int grow0 = blockIdx.x * 64;
    const int rowT = wr * 16 + (lane & 15);

    { // ---- S1: out 256, K=512, SWAP, A direct from global ----
        f32x4 acc[8];
        #pragma unroll
        for (int n = 0; n < 8; ++n) acc[n] = (f32x4){0.f, 0.f, 0.f, 0.f};
        int arow = grow0 + rowT; if (arow >= N) arow = N - 1;
        const US* sp = Ss + (size_t)arow * 512 + h * 8;
        u16x8 a0r, a1r, wreg[4];
        auto loadA = [&](int kc) {
            a0r = *(const u16x8*)(sp + kc * 64);
            a1r = *(const u16x8*)(sp + kc * 64 + 32);
        };
        auto loadW = [&](int kc) {
            #pragma unroll
            for (int j = 0; j < 4; ++j) {
                const int c = tid + 512 * j;
                wreg[j] = *(const u16x8*)(WB + O_RhoW1 + (size_t)(c >> 3) * 512 + kc * 64 + (c & 7) * 8);
            }
        };
        loadA(0); loadW(0);
        for (int kc = 0; kc < 8; ++kc) {
            __syncthreads();
            #pragma unroll
            for (int j = 0; j < 4; ++j) {
                const int c = tid + 512 * j;
                *(u16x8*)&Wb[swz(c >> 3, (c & 7) * 8, 64)] = wreg[j];
            }
            __syncthreads();
            if (kc < 7) loadW(kc + 1);
            short8 a0, a1;
            __builtin_memcpy(&a0, &a0r, 16);
            __builtin_memcpy(&a1, &a1r, 16);
            #pragma unroll
            for (int n = 0; n < 8; ++n) {
                short8 b = *(const short8*)&Wb[swz(wc * 128 + n * 16 + (lane & 15), h * 8, 64)];
                acc[n] = __builtin_amdgcn_mfma_f32_16x16x32_bf16(b, a0, acc[n], 0, 0, 0);
            }
            #pragma unroll
            for (int n = 0; n < 8; ++n) {
                short8 b = *(const short8*)&Wb[swz(wc * 128 + n * 16 + (lane & 15), 32 + h * 8, 64)];
                acc[n] = __builtin_amdgcn_mfma_f32_16x16x32_bf16(b, a1, acc[n], 0, 0, 0);
            }
            if (kc < 7) loadA(kc + 1);
        }
        __syncthreads();   // all Wb reads done before S2 reuses Wb
        #pragma unroll
        for (int n = 0; n < 8; ++n) {
            const int col = wc * 128 + n * 16 + h * 4;
            float4 bv = (col < 128) ? *(const float4*)&b_in[col]
                                    : *(const float4*)&b_proj[col - 128];
            float v0 = acc[n][0] + bv.x, v1 = acc[n][1] + bv.y;
            float v2 = acc[n][2] + bv.z, v3 = acc[n][3] + bv.w;
            if (col < 128) { v0 = gelu_f(v0); v1 = gelu_f(v1); v2 = gelu_f(v2); v3 = gelu_f(v3); }
            st4(T1, rowT, col, v0, v1, v2, v3);
        }
    }
    { // ---- S2: RU -> T1 lo, SWAP ----
        f32x4 acc[4];
        stageWD<4, 2, 512, true>(WB + O_RhoWh, 128, T1, 256, 0, 64, 0, wr * 16, Wb, tid, acc);
        #pragma unroll
        for (int n = 0; n < 4; ++n) {
            const int col = wc * 64 + n * 16 + h * 4;
            float4 bv = *(const float4*)&b_hid[col];
            float s0, s1, s2, s3;
            ld4(T1, rowT, 128 + col, s0, s1, s2, s3);
            st4(T1, rowT, col,
                gelu_f(acc[n][0] + bv.x) + s0, gelu_f(acc[n][1] + bv.y) + s1,
                gelu_f(acc[n][2] + bv.z) + s2, gelu_f(acc[n][3] + bv.w) + s3);
        }
    }
    { // ---- S3: out 64 (unchanged) ----
        f32x4 acc[2];
        stageWD<2, 2, 512>(WB + O_RhoWo, 128, T1, 256, 0, 64, 0, wr * 16, Wb, tid, acc);
        #pragma unroll
        for (int n = 0; n < 2; ++n) {
            const int col = wc * 32 + n * 16 + (lane & 15);
            const float bv = b_out[col];
            #pragma unroll
            for (int r = 0; r < 4; ++r) {
                const int node = grow0 + wr * 16 + h * 4 + r;
                if (node < N) zo[(size_t)node * 64 + col] = f2bf(acc[n][r] + bv);
            }
        }
    }
}

// ---------------------------------------------------------------------------
// Fused head v6.1: as R10 (which measured 763us) + xy-index div removal.
// ---------------------------------------------------------------------------
__global__ __launch_bounds__(1024, 4)
void head_fused(const int* __restrict__ srcq, const int* __restrict__ dstq,
                const int* __restrict__ batch, const US* __restrict__ z,
                const US* __restrict__ geb, const US* __restrict__ WB,
                const float* __restrict__ b1_in, const float* __restrict__ b1_proj,
                const float* __restrict__ b1_hid, const float* __restrict__ b1_out,
                const float* __restrict__ b2_in, const float* __restrict__ b2_hid,
                const float* __restrict__ w2_out, const float* __restrict__ b2_out,
                float* __restrict__ outH, float* __restrict__ outXY, int Q)
{
    __shared__ __align__(16) US A0[64 * 192];
    __shared__ __align__(16) US T1[128 * 256];
    __shared__ __align__(16) US Wb[2 * 16384];
    __shared__ float wout_s[128];
    const int tid = threadIdx.x, lane = tid & 63, w = tid >> 6;
    const int wr = w >> 1, wc = w & 1;
    const int q0 = blockIdx.x * 64;
    const int s1a = (wr < 4) ? 0 : 64;
    const int s1b = (wr < 4) ? 64 : 0;
    const int arowS1 = (wr & 3) * 16;
    const int rowS1 = (wr >> 2) * 64 + arowS1 + (lane & 15);
    const int rowT  = wr * 16 + (lane & 15);
    { // gather: 8 threads per query row (512 threads active)
        if (tid < 512) {
            const int r = tid >> 3, hh = tid & 7;
            const int q = q0 + r;
            const int qc = (q < Q) ? q : (Q - 1);
            const int s = srcq[qc], d = dstq[qc];
            const int g = batch[s];
            *(u16x8*)&A0[swz(r, hh * 8, 192)]       = *(const u16x8*)(z + (size_t)s * 64 + hh * 8);
            *(u16x8*)&A0[swz(r, 64 + hh * 8, 192)]  = *(const u16x8*)(z + (size_t)d * 64 + hh * 8);
            *(u16x8*)&A0[swz(r, 128 + hh * 8, 192)] = *(const u16x8*)(geb + (size_t)g * 64 + hh * 8);
        }
        if (tid < 128) wout_s[tid] = w2_out[tid];
    }
    __syncthreads();
    { // xy output (f32): row = tid>>4, quad = jj*16 + (tid&15) (no int div)
        const int row = tid >> 4;
        const int qu  = tid & 15;
        #pragma unroll
        for (int jj = 0; jj < 3; ++jj) {
            const int c4 = (jj * 16 + qu) * 4;
            if (q0 + row < Q) {
                const US* p = &A0[swz(row, c4, 192)];
                float4 o;
                o.x = bf2f(p[0]); o.y = bf2f(p[1]); o.z = bf2f(p[2]); o.w = bf2f(p[3]);
                *(float4*)&outXY[(size_t)(q0 + row) * 192 + c4] = o;
            }
        }
    }
    { // S1 merged: [t1 | s1] = A0 @ [W1in ; Wproj]^T, out 256 cols, K=192
        f32x4 acc8[8];
        stageWD<8, 3, 1024, true>(WB + O_H1W1, 192, A0, 192, s1a, s1b, 128, arowS1, Wb, tid, acc8);
        #pragma unroll
        for (int n = 0; n < 8; ++n) {
            const int col = wc * 128 + n * 16 + ((lane >> 4) << 2);
            float4 bv = (col < 128) ? *(const float4*)&b1_in[col]
                                    : *(const float4*)&b1_proj[col - 128];
            float v0 = acc8[n][0] + bv.x, v1 = acc8[n][1] + bv.y;
            float v2 = acc8[n][2] + bv.z, v3 = acc8[n][3] + bv.w;
            if (col < 128) { v0 = gelu_f(v0); v1 = gelu_f(v1); v2 = gelu_f(v2); v3 = gelu_f(v3); }
            st4(T1, rowS1, col, v0, v1, v2, v3);
        }
    }
    f32x4 acc[4];
    // S2: U = s1 + gelu(t1@Wh + bh) -> T1 lo
    stageWD<4, 2, 1024, true>(WB + O_H1Wh, 128, T1, 256, 0, 64, 0, wr * 16, Wb, tid, acc);
    #pragma unroll
    for (int n = 0; n < 4; ++n) {
        const int col = wc * 64 + n * 16 + ((lane >> 4) << 2);
        float4 bv = *(const float4*)&b1_hid[col];
        float s0, s1, s2, s3;
        ld4(T1, rowT, 128 + col, s0, s1, s2, s3);
        st4(T1, rowT, col,
            gelu_f(acc[n][0] + bv.x) + s0, gelu_f(acc[n][1] + bv.y) + s1,
            gelu_f(acc[n][2] + bv.z) + s2, gelu_f(acc[n][3] + bv.w) + s3);
    }
    // S3: T = relu(U@Wo + bo) -> T1 hi
    stageWD<4, 2, 1024, true>(WB + O_H1Wo, 128, T1, 256, 0, 64, 0, wr * 16, Wb, tid, acc);
    #pragma unroll
    for (int n = 0; n < 4; ++n) {
        const int col = wc * 64 + n * 16 + ((lane >> 4) << 2);
        float4 bv = *(const float4*)&b1_out[col];
        st4(T1, rowT, 128 + col,
            fmaxf(acc[n][0] + bv.x, 0.f), fmaxf(acc[n][1] + bv.y, 0.f),
            fmaxf(acc[n][2] + bv.z, 0.f), fmaxf(acc[n][3] + bv.w, 0.f));
    }
    // S4: B1 = gelu(T@W2 + b2) -> T1 lo (A = T1 hi)
    stageWD<4, 2, 1024, true>(WB + O_H2W1, 128, T1, 256, 128, 192, 0, wr * 16, Wb, tid, acc);
    #pragma unroll
    for (int n = 0; n < 4; ++n) {
        const int col = wc * 64 + n * 16 + ((lane >> 4) << 2);
        float4 bv = *(const float4*)&b2_in[col];
        st4(T1, rowT, col,
            gelu_f(acc[n][0] + bv.x), gelu_f(acc[n][1] + bv.y),
            gelu_f(acc[n][2] + bv.z), gelu_f(acc[n][3] + bv.w));
    }
    // S5: U2 = T + gelu(B1@Wh2 + bh2) -> T1 lo
    stageWD<4, 2, 1024, true>(WB + O_H2Wh, 128, T1, 256, 0, 64, 0, wr * 16, Wb, tid, acc);
    #pragma unroll
    for (int n = 0; n < 4; ++n) {
        const int col = wc * 64 + n * 16 + ((lane >> 4) << 2);
        float4 bv = *(const float4*)&b2_hid[col];
        float t0, t1, t2, t3;
        ld4(T1, rowT, 128 + col, t0, t1, t2, t3);
        st4(T1, rowT, col,
            gelu_f(acc[n][0] + bv.x) + t0, gelu_f(acc[n][1] + bv.y) + t1,
            gelu_f(acc[n][2] + bv.z) + t2, gelu_f(acc[n][3] + bv.w) + t3);
    }
    __syncthreads();   // U2 visible before dot (cross-wave rows)
    // S6: scalar head: 128 rows x 8 threads, 16 cols each
    {
        const int r = tid >> 3, hh = tid & 7;   // r 0..127: side = r>>6
        float a = 0.f;
        u16x8 v0 = *(const u16x8*)&T1[swz(r, hh * 16, 256)];
        u16x8 v1 = *(const u16x8*)&T1[swz(r, hh * 16 + 8, 256)];
        #pragma unroll
        for (int e = 0; e < 8; ++e) {
            a += bf2f(v0[e]) * wout_s[hh * 16 + e];
            a += bf2f(v1[e]) * wout_s[hh * 16 + 8 + e];
        }
        a += __shfl_xor(a, 4);
        a += __shfl_xor(a, 2);
        a += __shfl_xor(a, 1);
        const int q = q0 + (r & 63);
        if ((lane & 7) == 0 && q < Q) outH[(size_t)(r >> 6) * Q + q] = a + b2_out[0];
    }
}

// ---------------------------------------------------------------------------
// SAGE layer: zout = zin + gelu( [agg|zin] @ Wcat^T + bl ), K=128, out 64
// ---------------------------------------------------------------------------
__global__ __launch_bounds__(256, 2)
void sage_gemm(const US* __restrict__ zin, const US* __restrict__ agg,
               const US* __restrict__ Wc, const float* __restrict__ bias,
               US* __restrict__ zout, int N)
{
    __shared__ __align__(16) US As[128 * 128];
    __shared__ __align__(16) US Ws[64 * 128];
    const int tid = threadIdx.x, lane = tid & 63, w = tid >> 6;
    const int grow0 = blockIdx.x * 128;
    {
        const int r = tid >> 1, hh = tid & 1;
        int row = grow0 + r; if (row >= N) row = N - 1;
        const US* src = hh ? (zin + (size_t)row * 64) : (agg + (size_t)row * 64);
        #pragma unroll
        for (int j = 0; j < 8; ++j)
            *(u16x8*)&As[swz(r, hh * 64 + 8 * j, 128)] = *(const u16x8*)(src + 8 * j);
    }
    #pragma unroll
    for (int j = 0; j < 4; ++j) {
        const int c = tid + 256 * j;
        *(u16x8*)&Ws[swz(c >> 4, (c & 15) * 8, 128)] =
            *(const u16x8*)(Wc + (size_t)(c >> 4) * 128 + (c & 15) * 8);
    }
    __syncthreads();
    const int rbw = w * 32;
    f32x4 acc[2][4];
    #pragma unroll
    for (int m = 0; m < 2; ++m)
        #pragma unroll
        for (int n = 0; n < 4; ++n) acc[m][n] = (f32x4){0.f, 0.f, 0.f, 0.f};
    #pragma unroll
    for (int kc = 0; kc < 2; ++kc)
        #pragma unroll
        for (int sub = 0; sub < 2; ++sub) {
            const int kk = kc * 64 + sub * 32 + ((lane >> 4) << 3);
            short8 a[2], b[4];
            #pragma unroll
            for (int m = 0; m < 2; ++m) a[m] = *(const short8*)&As[swz(rbw + m * 16 + (lane & 15), kk, 128)];
            #pragma unroll
            for (int n = 0; n < 4; ++n) b[n] = *(const short8*)&Ws[swz(n * 16 + (lane & 15), kk, 128)];
            #pragma unroll
            for (int m = 0; m < 2; ++m)
                #pragma unroll
                for (int n = 0; n < 4; ++n)
                    acc[m][n] = __builtin_amdgcn_mfma_f32_16x16x32_bf16(a[m], b[n], acc[m][n], 0, 0, 0);
        }
    #pragma unroll
    for (int m = 0; m < 2; ++m) {
        const int row0 = rbw + m * 16 + ((lane >> 4) << 2);
        #pragma unroll
        for (int n = 0; n < 4; ++n) {
            const int col = n * 16 + (lane & 15);
            const float bv = bias[col];
            #pragma unroll
            for (int r = 0; r < 4; ++r) {
                const int node = grow0 + row0 + r;
                if (node < N) {
                    const float v = gelu_f(acc[m][n][r] + bv) + bf2f(zin[(size_t)node * 64 + col]);
                    zout[(size_t)node * 64 + col] = f2bf(v);
                }
            }
        }
    }
}

// ---------------------------------------------------------------------------
// Weight prep (f32 -> bf16, strided stacking)
// ---------------------------------------------------------------------------
struct WSeg { const float* src; int dst; int n; int rl; int ldd; };
struct WPrm { WSeg s[20]; };

__global__ void prep_w(WPrm p, US* __restrict__ wb)
{
    WSeg sg = p.s[blockIdx.x];
    for (int i = threadIdx.x; i < sg.n; i += 256) {
        const int idx = sg.dst + (i / sg.rl) * sg.ldd + (i % sg.rl);
        wb[idx] = f2bf(sg.src[i]);
    }
}

// ---------------------------------------------------------------------------
// CSR build + aggregate + segment max + misc
// ---------------------------------------------------------------------------
__global__ void count_k(const int* __restrict__ dst, int* __restrict__ cnt, int E)
{
    int e = blockIdx.x * 256 + threadIdx.x;
    if (e < E) atomicAdd(&cnt[dst[e]], 1);
}

__global__ void scan_csr(const int* __restrict__ cnt, int n, int* __restrict__ indp, int* __restrict__ curs)
{
    __shared__ int wsum[16];
    __shared__ int carry_s;
    const int tid = threadIdx.x, lane = tid & 63, w = tid >> 6;
    if (tid == 0) carry_s = 0;
    __syncthreads();
    for (int base = 0; base < n; base += 1024) {
        const int i = base + tid;
        const int v = (i < n) ? cnt[i] : 0;
        int s = v;
        #pragma unroll
        for (int o = 1; o < 64; o <<= 1) { int t = __shfl_up(s, o); if (lane >= o) s += t; }
        if (lane == 63) wsum[w] = s;
        __syncthreads();
        if (w == 0 && lane < 16) {
            int ws2 = wsum[lane];
            #pragma unroll
            for (int o = 1; o < 16; o <<= 1) { int t = __shfl_up(ws2, o); if (lane >= o) ws2 += t; }
            wsum[lane] = ws2;
        }
        __syncthreads();
        const int carry = carry_s;
        const int woff  = (w == 0) ? 0 : wsum[w - 1];
        if (i < n) { const int excl = carry + woff + s - v; indp[i] = excl; curs[i] = excl; }
        __syncthreads();
        if (tid == 0) carry_s = carry + wsum[15];
        __syncthreads();
    }
    if (threadIdx.x == 0) indp[n] = carry_s;
}

__global__ void fill_k(const int* __restrict__ src, const int* __restrict__ dst,
                       int* __restrict__ curs, int* __restrict__ esrc, int E)
{
    int e = blockIdx.x * 256 + threadIdx.x;
    if (e < E) { int p = atomicAdd(&curs[dst[e]], 1); esrc[p] = src[e]; }
}

__global__ void sage_agg(const US* __restrict__ z, const int* __restrict__ indp,
                         const int* __restrict__ esrc, US* __restrict__ agg, int n)
{
    const int w = blockIdx.x * 4 + (threadIdx.x >> 6);
    const int lane = threadIdx.x & 63;
    if (w >= n) return;
    const int beg = indp[w], end = indp[w + 1];
    float acc = 0.f;
    int j = beg;
    for (; j + 4 <= end; j += 4) {
        const int s0 = esrc[j], s1 = esrc[j + 1], s2 = esrc[j + 2], s3 = esrc[j + 3];
        const float v0 = bf2f(z[(size_t)s0 * 64 + lane]);
        const float v1 = bf2f(z[(size_t)s1 * 64 + lane]);
        const float v2 = bf2f(z[(size_t)s2 * 64 + lane]);
        const float v3 = bf2f(z[(size_t)s3 * 64 + lane]);
        acc += (v0 + v1) + (v2 + v3);
    }
    for (; j < end; ++j) acc += bf2f(z[(size_t)esrc[j] * 64 + lane]);
    const float d = (float)(end - beg);
    agg[(size_t)w * 64 + lane] = f2bf(acc / fmaxf(d, 1.0f));
}

__global__ void segmax_k(const US* __restrict__ z, const int* __restrict__ batch,
                         UI* __restrict__ enc, int n, int per)
{
    const int w = blockIdx.x * 4 + (threadIdx.x >> 6);
    const int lane = threadIdx.x & 63;
    const int start = w * per;
    if (start >= n) return;
    const int end = (start + per < n) ? start + per : n;
    int g = batch[start];
    float m = -3.0e38f;
    for (int i = start; i < end; ++i) {
        const int b = batch[i];
        if (b != g) { atomicMax(&enc[(size_t)g * 64 + lane], encf(m)); g = b; m = -3.0e38f; }
        m = fmaxf(m, bf2f(z[(size_t)i * 64 + lane]));
    }
    atomicMax(&enc[(size_t)g * 64 + lane], encf(m));
}

__global__ void decode_ge(const UI* __restrict__ enc, US* __restrict__ geb)
{
    const int i = blockIdx.x * 256 + threadIdx.x;
    if (i < 4096) geb[i] = f2bf(decf(enc[i]));
}

__global__ void copy_bf2f(const US* __restrict__ z, float* __restrict__ o, long n)
{
    long i = (long)blockIdx.x * blockDim.x + threadIdx.x;
    const long stride = (long)gridDim.x * blockDim.x;
    for (; i < n; i += stride) o[i] = bf2f(z[i]);
}

// ---------------------------------------------------------------------------
extern "C" void kernel_launch(void* const* d_in, const int* in_sizes, int n_in,
                              void* d_out, int out_size, void* d_ws, size_t ws_size,
                              hipStream_t stream)
{
    (void)in_sizes; (void)n_in; (void)out_size; (void)ws_size;

    const float* x      = (const float*)d_in[0];
    const int*   batch  = (const int*)d_in[1];
    const int*   eidx   = (const int*)d_in[2];
    const int*   srcq   = (const int*)d_in[3];
    const int*   dstq   = (const int*)d_in[4];
    const float* em_in_b   = (const float*)d_in[6];
    const float* em_hid_b  = (const float*)d_in[8];
    const float* em_out_b  = (const float*)d_in[10];
    const float* em_proj_b = (const float*)d_in[12];
    const float* rho_in_b  = (const float*)d_in[14];
    const float* rho_hid_b = (const float*)d_in[16];
    const float* rho_out_b = (const float*)d_in[18];
    const float* rho_proj_b= (const float*)d_in[20];
    const float* c_ll_W[3] = {(const float*)d_in[21], (const float*)d_in[24], (const float*)d_in[27]};
    const float* c_ll_b[3] = {(const float*)d_in[22], (const float*)d_in[25], (const float*)d_in[28]};
    const float* c_lr_W[3] = {(const float*)d_in[23], (const float*)d_in[26], (const float*)d_in[29]};
    const float* h1_in_b   = (const float*)d_in[31];
    const float* h1_hid_b  = (const float*)d_in[33];
    const float* h1_out_b  = (const float*)d_in[35];
    const float* h1_proj_b = (const float*)d_in[37];
    const float* h2_in_b   = (const float*)d_in[39];
    const float* h2_hid_b  = (const float*)d_in[41];
    const float* h2_out_W  = (const float*)d_in[42];
    const float* h2_out_b  = (const float*)d_in[43];

    const int N = 50000, E = 1600000, Q = 500000;
    float* out = (float*)d_out;

    // ---- workspace layout ----
    char* wsb = (char*)d_ws;
    size_t off = 0;
    auto ALLOC = [&](size_t bytes) -> char* {
        char* p = wsb + off; off = (off + bytes + 255) & ~(size_t)255; return p;
    };
    US*  WB   = (US*)ALLOC((size_t)W_TOTAL * 2);
    US*  Ss   = (US*)ALLOC((size_t)N * 512 * 2);
    US*  z0   = (US*)ALLOC((size_t)N * 64 * 2);
    US*  z1   = (US*)ALLOC((size_t)N * 64 * 2);
    US*  aggB = (US*)ALLOC((size_t)N * 64 * 2);
    int* cnt  = (int*)ALLOC((size_t)N * 4);
    int* indp = (int*)ALLOC((size_t)(N + 1) * 4);
    int* curs = (int*)ALLOC((size_t)N * 4);
    int* esrc = (int*)ALLOC((size_t)E * 4);
    UI*  enc  = (UI*)ALLOC(4096 * 4);
    US*  geb  = (US*)ALLOC(4096 * 2);

    const int catOff[3] = {O_Cat1, O_Cat2, O_Cat3};

    WPrm pw; int si = 0;
    auto SEG = [&](const float* s, int o, int n, int rl, int ldd) {
        pw.s[si].src = s; pw.s[si].dst = o; pw.s[si].n = n; pw.s[si].rl = rl; pw.s[si].ldd = ldd; ++si;
    };
    SEG((const float*)d_in[5],  O_EmW1,          65536, 65536, 65536);
    SEG((const float*)d_in[11], O_EmW1 + 65536,  65536, 65536, 65536);
    SEG((const float*)d_in[7],  O_EmWh,          16384, 16384, 16384);
    SEG((const float*)d_in[9],  O_EmWo,          65536, 65536, 65536);
    SEG((const float*)d_in[13], O_RhoW1,         65536, 65536, 65536);
    SEG((const float*)d_in[19], O_RhoW1 + 65536, 65536, 65536, 65536);
    SEG((const float*)d_in[15], O_RhoWh,         16384, 16384, 16384);
    SEG((const float*)d_in[17], O_RhoWo,          8192,  8192,  8192);
    for (int i = 0; i < 3; ++i) {
        SEG(c_ll_W[i], catOff[i],      4096, 64, 128);
        SEG(c_lr_W[i], catOff[i] + 64, 4096, 64, 128);
    }
    SEG((const float*)d_in[30], O_H1W1,          24576, 24576, 24576);
    SEG((const float*)d_in[36], O_H1W1 + 24576,  24576, 24576, 24576);
    SEG((const float*)d_in[32], O_H1Wh,          16384, 16384, 16384);
    SEG((const float*)d_in[34], O_H1Wo,          16384, 16384, 16384);
    SEG((const float*)d_in[38], O_H2W1,          16384, 16384, 16384);
    SEG((const float*)d_in[40], O_H2Wh,          16384, 16384, 16384);
    prep_w<<<dim3(20), dim3(256), 0, stream>>>(pw, WB);

    // ---- CSR build ----
    hipMemsetAsync(cnt, 0, (size_t)N * 4, stream);
    count_k<<<dim3((E + 255) / 256), dim3(256), 0, stream>>>(eidx + E, cnt, E);
    scan_csr<<<dim3(1), dim3(1024), 0, stream>>>(cnt, N, indp, curs);
    fill_k<<<dim3((E + 255) / 256), dim3(256), 0, stream>>>(eidx, eidx + E, curs, esrc, E);

    // ---- Embedder + rho ----
    embed_fused<<<dim3(3125), dim3(1024), 0, stream>>>(x, WB, em_in_b, em_proj_b, em_hid_b, em_out_b, Ss);
    rho_fused<<<dim3((N + 63) / 64), dim3(512), 0, stream>>>(Ss, WB, rho_in_b, rho_proj_b, rho_hid_b, rho_out_b, z0, N);

    // ---- 3x SAGE residual ----
    US* zin = z0; US* zout = z1;
    for (int ci = 0; ci < 3; ++ci) {
        sage_agg<<<dim3((N + 3) / 4), dim3(256), 0, stream>>>(zin, indp, esrc, aggB, N);
        sage_gemm<<<dim3((N + 127) / 128), dim3(256), 0, stream>>>(zin, aggB, WB + catOff[ci], c_ll_b[ci], zout, N);
        US* t = zin; zin = zout; zout = t;
    }
    US* zf = zin;

    // ---- graph max-pool ----
    hipMemsetAsync(enc, 0, 4096 * 4, stream);
    segmax_k<<<dim3((N + 511) / 512), dim3(256), 0, stream>>>(zf, batch, enc, N, 128);
    decode_ge<<<dim3(16), dim3(256), 0, stream>>>(enc, geb);

    // ---- node_embeddings output ----
    copy_bf2f<<<dim3(2048), dim3(256), 0, stream>>>(zf, out, (long)N * 64);

    // ---- fused heads (64 queries/block, both sides, 16 waves/block) ----
    head_fused<<<dim3((Q + 63) / 64), dim3(1024), 0, stream>>>(
        srcq, dstq, batch, zf, geb, WB,
        h1_in_b, h1_proj_b, h1_hid_b, h1_out_b, h2_in_b, h2_hid_b, h2_out_W, h2_out_b,
        out + (size_t)N * 64, out + (size_t)N * 64 + 2 * (size_t)Q, Q);
}

// Round 12
// 1567.046 us; speedup vs baseline: 1.1714x; 1.1714x over previous
//
#include <hip/hip_runtime.h>

typedef unsigned short US;
typedef unsigned int   UI;
typedef short  short8 __attribute__((ext_vector_type(8)));
typedef US     u16x8  __attribute__((ext_vector_type(8)));
typedef float  f32x4  __attribute__((ext_vector_type(4)));

#define DEVI __device__ __forceinline__

DEVI float bf2f(US u){ UI i = ((UI)u) << 16; float f; __builtin_memcpy(&f, &i, 4); return f; }
DEVI US f2bf(float x){ UI i; __builtin_memcpy(&i, &x, 4); UI r = (i + 0x7FFFu + ((i >> 16) & 1u)) >> 16; return (US)r; }
// gelu (tanh-form as sigmoid), exp2+rcp hardware ops: ~6 inst, no float-div
// sequence. e = 2^(-1.4427*1.5958*(x + 0.044715 x^3)); g = x * rcp(1+e).
DEVI float gelu_f(float x){
    float x2 = x * x;
    float m  = x * fmaf(x2, -0.1029432f, -2.3022052f);
    float e  = __builtin_amdgcn_exp2f(m);
    return x * __builtin_amdgcn_rcpf(1.0f + e);
}
DEVI UI encf(float f){ UI u; __builtin_memcpy(&u, &f, 4); return (u & 0x80000000u) ? ~u : (u | 0x80000000u); }
DEVI float decf(UI u){ UI b = (u & 0x80000000u) ? (u ^ 0x80000000u) : ~u; float f; __builtin_memcpy(&f, &b, 4); return f; }
DEVI int swz(int r, int c, int ld){ int i = r * ld + c; return i ^ ((r & 7) << 3); }

// packed f32x2 -> bf16x2 (hardware RNE)
DEVI UI pkbf(float a, float b){ UI u; asm("v_cvt_pk_bf16_f32 %0, %1, %2" : "=v"(u) : "v"(a), "v"(b)); return u; }
DEVI void st4(US* T, int row, int col, float v0, float v1, float v2, float v3){
    uint2 p; p.x = pkbf(v0, v1); p.y = pkbf(v2, v3);
    *(uint2*)&T[swz(row, col, 256)] = p;
}
DEVI void ld4(const US* T, int row, int col, float& v0, float& v1, float& v2, float& v3){
    uint2 q = *(const uint2*)&T[swz(row, col, 256)];
    v0 = bf2f((US)(q.x & 0xffff)); v1 = bf2f((US)(q.x >> 16));
    v2 = bf2f((US)(q.y & 0xffff)); v3 = bf2f((US)(q.y >> 16));
}

// bf16 weight-buffer offsets (elements)
enum : int { O_EmW1 = 0, O_EmWh = 131072, O_EmWo = 147456, O_RhoW1 = 212992,
             O_RhoWh = 344064, O_RhoWo = 360448, O_Cat1 = 368640, O_Cat2 = 376832,
             O_Cat3 = 385024, O_H1W1 = 393216, O_H1Wh = 442368, O_H1Wo = 458752,
             O_H2W1 = 475136, O_H2Wh = 491520, W_TOTAL = 507904 };

// ---------------------------------------------------------------------------
// Double-buffered W-streaming stage (embed/rho). SWAP=true: C^T epilogue.
// ---------------------------------------------------------------------------
template<int NT, int NKC, int NTHR, bool SWAP = false>
DEVI void stageWD(const US* __restrict__ Wg, int Kw, const US* __restrict__ A, int lda,
                  int ab0, int ab1, int ab2, int arow0, US* Wb, int tid, f32x4 (&acc)[NT])
{
    const int lane = tid & 63;
    const int wc = (tid >> 6) & 1;
    constexpr int SLAB = NT * 32 * 64;
    #pragma unroll
    for (int n = 0; n < NT; ++n) acc[n] = (f32x4){0.f, 0.f, 0.f, 0.f};
    constexpr int J = (NT * 256) / NTHR;
    u16x8 wreg[J];
    #pragma unroll
    for (int j = 0; j < J; ++j) {
        const int c = tid + NTHR * j;
        wreg[j] = *(const u16x8*)(Wg + (size_t)(c >> 3) * Kw + (c & 7) * 8);
    }
    #pragma unroll
    for (int j = 0; j < J; ++j) {
        const int c = tid + NTHR * j;
        *(u16x8*)&Wb[swz(c >> 3, (c & 7) * 8, 64)] = wreg[j];
    }
    #pragma unroll
    for (int kc = 0; kc < NKC; ++kc) {
        __syncthreads();
        if (kc + 1 < NKC) {
            #pragma unroll
            for (int j = 0; j < J; ++j) {
                const int c = tid + NTHR * j;
                wreg[j] = *(const u16x8*)(Wg + (size_t)(c >> 3) * Kw + (kc + 1) * 64 + (c & 7) * 8);
            }
        }
        const int ab = (kc == 0) ? ab0 : ((kc == 1) ? ab1 : ab2);
        const int bufr = (kc & 1) * SLAB;
        #pragma unroll
        for (int sub = 0; sub < 2; ++sub) {
            const int kk = sub * 32 + ((lane >> 4) << 3);
            short8 a = *(const short8*)&A[swz(arow0 + (lane & 15), ab + kk, lda)];
            #pragma unroll
            for (int n = 0; n < NT; ++n) {
                short8 b = *(const short8*)&Wb[bufr + swz(wc * (NT * 16) + n * 16 + (lane & 15), kk, 64)];
                if (SWAP) acc[n] = __builtin_amdgcn_mfma_f32_16x16x32_bf16(b, a, acc[n], 0, 0, 0);
                else      acc[n] = __builtin_amdgcn_mfma_f32_16x16x32_bf16(a, b, acc[n], 0, 0, 0);
            }
        }
        if (kc + 1 < NKC) {
            const int bufw = ((kc + 1) & 1) * SLAB;
            #pragma unroll
            for (int j = 0; j < J; ++j) {
                const int c = tid + NTHR * j;
                *(u16x8*)&Wb[bufw + swz(c >> 3, (c & 7) * 8, 64)] = wreg[j];
            }
        }
    }
    __syncthreads();
}

// ---------------------------------------------------------------------------
// Head-only chained stage: per kc [bar; prefetch regs (next kc, or NEXT
// STAGE's slab0); MFMA (always SWAP'd); write regs to the slab not being
// read]. Next stage starts with its slab0 already resident -> no per-stage
// serial load-wait-write preamble. Parity-safe by construction:
//   S1: off0=0, off1=16384, wrN=16384 (NKC=3: reads 0,1,0)
//   S2-5: off0=16384, off1=24576, wrN=16384 (NKC=2: reads X,Y; next->X)
// ---------------------------------------------------------------------------
template<int NT, int NTN, int NKC, int NTHR, bool LAST>
DEVI void stageWC(const US* __restrict__ Wg, int Kw, const US* __restrict__ nextWg, int nKw,
                  const US* __restrict__ A, int lda, int ab0, int ab1, int ab2, int arow0,
                  US* Wb, int off0, int off1, int wrN, int tid, f32x4 (&acc)[NT])
{
    const int lane = tid & 63;
    const int wc = (tid >> 6) & 1;
    #pragma unroll
    for (int n = 0; n < NT; ++n) acc[n] = (f32x4){0.f, 0.f, 0.f, 0.f};
    constexpr int J  = (NT  * 256) / NTHR;
    constexpr int JN = (NTN * 256) / NTHR;   // JN <= J in all uses
    u16x8 wreg[J];
    #pragma unroll
    for (int kc = 0; kc < NKC; ++kc) {
        __syncthreads();
        if (kc + 1 < NKC) {
            #pragma unroll
            for (int j = 0; j < J; ++j) {
                const int c = tid + NTHR * j;
                wreg[j] = *(const u16x8*)(Wg + (size_t)(c >> 3) * Kw + (kc + 1) * 64 + (c & 7) * 8);
            }
        } else if (!LAST) {
            #pragma unroll
            for (int j = 0; j < JN; ++j) {
                const int c = tid + NTHR * j;
                wreg[j] = *(const u16x8*)(nextWg + (size_t)(c >> 3) * nKw + (c & 7) * 8);
            }
        }
        const int ab = (kc == 0) ? ab0 : ((kc == 1) ? ab1 : ab2);
        const int rd = (kc & 1) ? off1 : off0;
        #pragma unroll
        for (int sub = 0; sub < 2; ++sub) {
            const int kk = sub * 32 + ((lane >> 4) << 3);
            short8 a = *(const short8*)&A[swz(arow0 + (lane & 15), ab + kk, lda)];
            #pragma unroll
            for (int n = 0; n < NT; ++n) {
                short8 b = *(const short8*)&Wb[rd + swz(wc * (NT * 16) + n * 16 + (lane & 15), kk, 64)];
                acc[n] = __builtin_amdgcn_mfma_f32_16x16x32_bf16(b, a, acc[n], 0, 0, 0);
            }
        }
        if (kc + 1 < NKC) {
            const int wr_ = (kc & 1) ? off0 : off1;
            #pragma unroll
            for (int j = 0; j < J; ++j) {
                const int c = tid + NTHR * j;
                *(u16x8*)&Wb[wr_ + swz(c >> 3, (c & 7) * 8, 64)] = wreg[j];
            }
        } else if (!LAST) {
            #pragma unroll
            for (int j = 0; j < JN; ++j) {
                const int c = tid + NTHR * j;
                *(u16x8*)&Wb[wrN + swz(c >> 3, (c & 7) * 8, 64)] = wreg[j];
            }
        }
    }
    __syncthreads();
}

template<int NT, int NTHR>
DEVI void preloadW(const US* __restrict__ Wg, int Kw, US* Wb, int off, int tid)
{
    constexpr int J = (NT * 256) / NTHR;
    #pragma unroll
    for (int j = 0; j < J; ++j) {
        const int c = tid + NTHR * j;
        u16x8 v = *(const u16x8*)(Wg + (size_t)(c >> 3) * Kw + (c & 7) * 8);
        *(u16x8*)&Wb[off + swz(c >> 3, (c & 7) * 8, 64)] = v;
    }
}

// ---------------------------------------------------------------------------
// Fused embedder v2 (as R11, gelu updated).
// ---------------------------------------------------------------------------
__global__ __launch_bounds__(1024, 4)
void embed_fused(const float* __restrict__ x, const US* __restrict__ WB,
                 const float* __restrict__ b_in, const float* __restrict__ b_proj,
                 const float* __restrict__ b_hid, const float* __restrict__ b_out,
                 US* __restrict__ Ss)
{
    __shared__ __align__(16) US T1[128 * 256];
    __shared__ __align__(16) US Wb[2 * 16384];
    const int tid = threadIdx.x, lane = tid & 63, w = tid >> 6;
    const int wr = w >> 1, wc = w & 1;
    const int h = lane >> 4;
    const int grow0 = blockIdx.x * 128;
    const int rowT = wr * 16 + (lane & 15);

    { // ---- S1: [gelu(x@Wi+bi) | x@Wp+bp], K=512 (8 kc), SWAP ----
        f32x4 acc[8];
        #pragma unroll
        for (int n = 0; n < 8; ++n) acc[n] = (f32x4){0.f, 0.f, 0.f, 0.f};
        const float* xp = x + (size_t)(grow0 + rowT) * 512 + h * 8;
        float4 p00, p01, p10, p11;
        u16x8 wreg[2];
        auto loadA = [&](int kc) {
            p00 = *(const float4*)(xp + kc * 64);
            p01 = *(const float4*)(xp + kc * 64 + 4);
            p10 = *(const float4*)(xp + kc * 64 + 32);
            p11 = *(const float4*)(xp + kc * 64 + 36);
        };
        auto loadW = [&](int kc) {
            #pragma unroll
            for (int j = 0; j < 2; ++j) {
                const int c = tid + 1024 * j;
                wreg[j] = *(const u16x8*)(WB + O_EmW1 + (size_t)(c >> 3) * 512 + kc * 64 + (c & 7) * 8);
            }
        };
        auto writeW = [&](int buf) {
            #pragma unroll
            for (int j = 0; j < 2; ++j) {
                const int c = tid + 1024 * j;
                *(u16x8*)&Wb[buf * 16384 + swz(c >> 3, (c & 7) * 8, 64)] = wreg[j];
            }
        };
        loadA(0); loadW(0); writeW(0);
        for (int kc = 0; kc < 8; ++kc) {
            __syncthreads();
            short8 a0, a1;
            {
                uint4 q;
                q.x = pkbf(p00.x, p00.y); q.y = pkbf(p00.z, p00.w);
                q.z = pkbf(p01.x, p01.y); q.w = pkbf(p01.z, p01.w);
                __builtin_memcpy(&a0, &q, 16);
                q.x = pkbf(p10.x, p10.y); q.y = pkbf(p10.z, p10.w);
                q.z = pkbf(p11.x, p11.y); q.w = pkbf(p11.z, p11.w);
                __builtin_memcpy(&a1, &q, 16);
            }
            if (kc < 7) { loadA(kc + 1); loadW(kc + 1); }
            const int bufr = (kc & 1) * 16384;
            #pragma unroll
            for (int n = 0; n < 8; ++n) {
                short8 b = *(const short8*)&Wb[bufr + swz(wc * 128 + n * 16 + (lane & 15), h * 8, 64)];
                acc[n] = __builtin_amdgcn_mfma_f32_16x16x32_bf16(b, a0, acc[n], 0, 0, 0);
            }
            #pragma unroll
            for (int n = 0; n < 8; ++n) {
                short8 b = *(const short8*)&Wb[bufr + swz(wc * 128 + n * 16 + (lane & 15), 32 + h * 8, 64)];
                acc[n] = __builtin_amdgcn_mfma_f32_16x16x32_bf16(b, a1, acc[n], 0, 0, 0);
            }
            if (kc < 7) writeW((kc + 1) & 1);
        }
        #pragma unroll
        for (int n = 0; n < 8; ++n) {
            const int col = wc * 128 + n * 16 + h * 4;
            float4 bv = (col < 128) ? *(const float4*)&b_in[col]
                                    : *(const float4*)&b_proj[col - 128];
            float v0 = acc[n][0] + bv.x, v1 = acc[n][1] + bv.y;
            float v2 = acc[n][2] + bv.z, v3 = acc[n][3] + bv.w;
            if (col < 128) { v0 = gelu_f(v0); v1 = gelu_f(v1); v2 = gelu_f(v2); v3 = gelu_f(v3); }
            st4(T1, rowT, col, v0, v1, v2, v3);
        }
    }
    { // ---- S2: U = s + gelu(t1@Wh+bh) -> T1 lo, SWAP ----
        f32x4 acc[4];
        stageWD<4, 2, 1024, true>(WB + O_EmWh, 128, T1, 256, 0, 64, 0, wr * 16, Wb, tid, acc);
        #pragma unroll
        for (int n = 0; n < 4; ++n) {
            const int col = wc * 64 + n * 16 + h * 4;
            float4 bv = *(const float4*)&b_hid[col];
            float s0, s1, s2, s3;
            ld4(T1, rowT, 128 + col, s0, s1, s2, s3);
            st4(T1, rowT, col,
                gelu_f(acc[n][0] + bv.x) + s0, gelu_f(acc[n][1] + bv.y) + s1,
                gelu_f(acc[n][2] + bv.z) + s2, gelu_f(acc[n][3] + bv.w) + s3);
        }
    }
    // ---- S3: 2 merged passes (NT=8, 256 cols each), sum8 epilogue ----
    for (int p2 = 0; p2 < 2; ++p2) {
        f32x4 acc[8];
        stageWD<8, 2, 1024>(WB + O_EmWo + (size_t)(p2 * 256) * 128, 128, T1, 256, 0, 64, 0, wr * 16, Wb, tid, acc);
        #pragma unroll
        for (int n = 0; n < 8; ++n) {
            const int col = wc * 128 + n * 16 + (lane & 15);
            const float bv = b_out[p2 * 256 + col];
            float s = 0.f;
            #pragma unroll
            for (int r = 0; r < 4; ++r) s += gelu_f(acc[n][r] + bv);
            s += __shfl_xor(s, 16);
            if (((lane >> 4) & 1) == 0) {
                const int node = (grow0 >> 3) + wr * 2 + (lane >> 5);
                Ss[(size_t)node * 512 + p2 * 256 + col] = f2bf(s);
            }
        }
    }
}

// ---------------------------------------------------------------------------
// Fused rho v2 (as R11, gelu updated).
// ---------------------------------------------------------------------------
__global__ __launch_bounds__(512, 2)
void rho_fused(const US* __restrict__ Ss, const US* __restrict__ WB,
               const float* __restrict__ b_in, const float* __restrict__ b_proj,
               const float* __restrict__ b_hid, const float* __restrict__ b_out,
               US* __restrict__ zo, int N)
{
    __shared__ __align__(16) US T1[64 * 256];
    __shared__ __align__(16) US Wb[256 * 64];
    const int tid = threadIdx.x, lane = tid & 63, w = tid >> 6;
    const int wr = w >> 1, wc = w & 1;
    const int h = lane >> 4;
    const int grow0 = blockIdx.x * 64;
    const int rowT = wr * 16 + (lane & 15);

    { // ---- S1: out 256, K=512, SWAP, A direct from global ----
        f32x4 acc[8];
        #pragma unroll
        for (int n = 0; n < 8; ++n) acc[n] = (f32x4){0.f, 0.f, 0.f, 0.f};
        int arow = grow0 + rowT; if (arow >= N) arow = N - 1;
        const US* sp = Ss + (size_t)arow * 512 + h * 8;
        u16x8 a0r, a1r, wreg[4];
        auto loadA = [&](int kc) {
            a0r = *(const u16x8*)(sp + kc * 64);
            a1r = *(const u16x8*)(sp + kc * 64 + 32);
        };
        auto loadW = [&](int kc) {
            #pragma unroll
            for (int j = 0; j < 4; ++j) {
                const int c = tid + 512 * j;
                wreg[j] = *(const u16x8*)(WB + O_RhoW1 + (size_t)(c >> 3) * 512 + kc * 64 + (c & 7) * 8);
            }
        };
        loadA(0); loadW(0);
        for (int kc = 0; kc < 8; ++kc) {
            __syncthreads();
            #pragma unroll
            for (int j = 0; j < 4; ++j) {
                const int c = tid + 512 * j;
                *(u16x8*)&Wb[swz(c >> 3, (c & 7) * 8, 64)] = wreg[j];
            }
            __syncthreads();
            if (kc < 7) loadW(kc + 1);
            short8 a0, a1;
            __builtin_memcpy(&a0, &a0r, 16);
            __builtin_memcpy(&a1, &a1r, 16);
            #pragma unroll
            for (int n = 0; n < 8; ++n) {
                short8 b = *(const short8*)&Wb[swz(wc * 128 + n * 16 + (lane & 15), h * 8, 64)];
                acc[n] = __builtin_amdgcn_mfma_f32_16x16x32_bf16(b, a0, acc[n], 0, 0, 0);
            }
            #pragma unroll
            for (int n = 0; n < 8; ++n) {
                short8 b = *(const short8*)&Wb[swz(wc * 128 + n * 16 + (lane & 15), 32 + h * 8, 64)];
                acc[n] = __builtin_amdgcn_mfma_f32_16x16x32_bf16(b, a1, acc[n], 0, 0, 0);
            }
            if (kc < 7) loadA(kc + 1);
        }
        __syncthreads();
        #pragma unroll
        for (int n = 0; n < 8; ++n) {
            const int col = wc * 128 + n * 16 + h * 4;
            float4 bv = (col < 128) ? *(const float4*)&b_in[col]
                                    : *(const float4*)&b_proj[col - 128];
            float v0 = acc[n][0] + bv.x, v1 = acc[n][1] + bv.y;
            float v2 = acc[n][2] + bv.z, v3 = acc[n][3] + bv.w;
            if (col < 128) { v0 = gelu_f(v0); v1 = gelu_f(v1); v2 = gelu_f(v2); v3 = gelu_f(v3); }
            st4(T1, rowT, col, v0, v1, v2, v3);
        }
    }
    { // ---- S2: RU -> T1 lo, SWAP ----
        f32x4 acc[4];
        stageWD<4, 2, 512, true>(WB + O_RhoWh, 128, T1, 256, 0, 64, 0, wr * 16, Wb, tid, acc);
        #pragma unroll
        for (int n = 0; n < 4; ++n) {
            const int col = wc * 64 + n * 16 + h * 4;
            float4 bv = *(const float4*)&b_hid[col];
            float s0, s1, s2, s3;
            ld4(T1, rowT, 128 + col, s0, s1, s2, s3);
            st4(T1, rowT, col,
                gelu_f(acc[n][0] + bv.x) + s0, gelu_f(acc[n][1] + bv.y) + s1,
                gelu_f(acc[n][2] + bv.z) + s2, gelu_f(acc[n][3] + bv.w) + s3);
        }
    }
    { // ---- S3: out 64 ----
        f32x4 acc[2];
        stageWD<2, 2, 512>(WB + O_RhoWo, 128, T1, 256, 0, 64, 0, wr * 16, Wb, tid, acc);
        #pragma unroll
        for (int n = 0; n < 2; ++n) {
            const int col = wc * 32 + n * 16 + (lane & 15);
            const float bv = b_out[col];
            #pragma unroll
            for (int r = 0; r < 4; ++r) {
                const int node = grow0 + wr * 16 + h * 4 + r;
                if (node < N) zo[(size_t)node * 64 + col] = f2bf(acc[n][r] + bv);
            }
        }
    }
}

// ---------------------------------------------------------------------------
// Fused head v7: R11 geometry + chained W-prefetch (stageWC).
// ---------------------------------------------------------------------------
__global__ __launch_bounds__(1024, 4)
void head_fused(const int* __restrict__ srcq, const int* __restrict__ dstq,
                const int* __restrict__ batch, const US* __restrict__ z,
                const US* __restrict__ geb, const US* __restrict__ WB,
                const float* __restrict__ b1_in, const float* __restrict__ b1_proj,
                const float* __restrict__ b1_hid, const float* __restrict__ b1_out,
                const float* __restrict__ b2_in, const float* __restrict__ b2_hid,
                const float* __restrict__ w2_out, const float* __restrict__ b2_out,
                float* __restrict__ outH, float* __restrict__ outXY, int Q)
{
    __shared__ __align__(16) US A0[64 * 192];
    __shared__ __align__(16) US T1[128 * 256];
    __shared__ __align__(16) US Wb[2 * 16384];
    __shared__ float wout_s[128];
    const int tid = threadIdx.x, lane = tid & 63, w = tid >> 6;
    const int wr = w >> 1, wc = w & 1;
    const int q0 = blockIdx.x * 64;
    const int s1a = (wr < 4) ? 0 : 64;
    const int s1b = (wr < 4) ? 64 : 0;
    const int arowS1 = (wr & 3) * 16;
    const int rowS1 = (wr >> 2) * 64 + arowS1 + (lane & 15);
    const int rowT  = wr * 16 + (lane & 15);

    // S1 slab0 preload (completes under the gather phase; kc0 barrier orders)
    preloadW<8, 1024>(WB + O_H1W1, 192, Wb, 0, tid);

    { // gather: 8 threads per query row (512 threads active)
        if (tid < 512) {
            const int r = tid >> 3, hh = tid & 7;
            const int q = q0 + r;
            const int qc = (q < Q) ? q : (Q - 1);
            const int s = srcq[qc], d = dstq[qc];
            const int g = batch[s];
            *(u16x8*)&A0[swz(r, hh * 8, 192)]       = *(const u16x8*)(z + (size_t)s * 64 + hh * 8);
            *(u16x8*)&A0[swz(r, 64 + hh * 8, 192)]  = *(const u16x8*)(z + (size_t)d * 64 + hh * 8);
            *(u16x8*)&A0[swz(r, 128 + hh * 8, 192)] = *(const u16x8*)(geb + (size_t)g * 64 + hh * 8);
        }
        if (tid < 128) wout_s[tid] = w2_out[tid];
    }
    __syncthreads();
    { // xy output (f32)
        const int row = tid >> 4;
        const int qu  = tid & 15;
        #pragma unroll
        for (int jj = 0; jj < 3; ++jj) {
            const int c4 = (jj * 16 + qu) * 4;
            if (q0 + row < Q) {
                const US* p = &A0[swz(row, c4, 192)];
                float4 o;
                o.x = bf2f(p[0]); o.y = bf2f(p[1]); o.z = bf2f(p[2]); o.w = bf2f(p[3]);
                *(float4*)&outXY[(size_t)(q0 + row) * 192 + c4] = o;
            }
        }
    }
    { // S1 merged: [t1 | s1], out 256 cols, K=192 (chained: next = H1Wh)
        f32x4 acc8[8];
        stageWC<8, 4, 3, 1024, false>(WB + O_H1W1, 192, WB + O_H1Wh, 128,
                                      A0, 192, s1a, s1b, 128, arowS1,
                                      Wb, 0, 16384, 16384, tid, acc8);
        #pragma unroll
        for (int n = 0; n < 8; ++n) {
            const int col = wc * 128 + n * 16 + ((lane >> 4) << 2);
            float4 bv = (col < 128) ? *(const float4*)&b1_in[col]
                                    : *(const float4*)&b1_proj[col - 128];
            float v0 = acc8[n][0] + bv.x, v1 = acc8[n][1] + bv.y;
            float v2 = acc8[n][2] + bv.z, v3 = acc8[n][3] + bv.w;
            if (col < 128) { v0 = gelu_f(v0); v1 = gelu_f(v1); v2 = gelu_f(v2); v3 = gelu_f(v3); }
            st4(T1, rowS1, col, v0, v1, v2, v3);
        }
    }
    f32x4 acc[4];
    // S2: U = s1 + gelu(t1@Wh + bh) -> T1 lo (next = H1Wo)
    stageWC<4, 4, 2, 1024, false>(WB + O_H1Wh, 128, WB + O_H1Wo, 128,
                                  T1, 256, 0, 64, 0, wr * 16,
                                  Wb, 16384, 24576, 16384, tid, acc);
    #pragma unroll
    for (int n = 0; n < 4; ++n) {
        const int col = wc * 64 + n * 16 + ((lane >> 4) << 2);
        float4 bv = *(const float4*)&b1_hid[col];
        float s0, s1, s2, s3;
        ld4(T1, rowT, 128 + col, s0, s1, s2, s3);
        st4(T1, rowT, col,
            gelu_f(acc[n][0] + bv.x) + s0, gelu_f(acc[n][1] + bv.y) + s1,
            gelu_f(acc[n][2] + bv.z) + s2, gelu_f(acc[n][3] + bv.w) + s3);
    }
    // S3: T = relu(U@Wo + bo) -> T1 hi (next = H2W1)
    stageWC<4, 4, 2, 1024, false>(WB + O_H1Wo, 128, WB + O_H2W1, 128,
                                  T1, 256, 0, 64, 0, wr * 16,
                                  Wb, 16384, 24576, 16384, tid, acc);
    #pragma unroll
    for (int n = 0; n < 4; ++n) {
        const int col = wc * 64 + n * 16 + ((lane >> 4) << 2);
        float4 bv = *(const float4*)&b1_out[col];
        st4(T1, rowT, 128 + col,
            fmaxf(acc[n][0] + bv.x, 0.f), fmaxf(acc[n][1] + bv.y, 0.f),
            fmaxf(acc[n][2] + bv.z, 0.f), fmaxf(acc[n][3] + bv.w, 0.f));
    }
    // S4: B1 = gelu(T@W2 + b2) -> T1 lo (A = T1 hi; next = H2Wh)
    stageWC<4, 4, 2, 1024, false>(WB + O_H2W1, 128, WB + O_H2Wh, 128,
                                  T1, 256, 128, 192, 0, wr * 16,
                                  Wb, 16384, 24576, 16384, tid, acc);
    #pragma unroll
    for (int n = 0; n < 4; ++n) {
        const int col = wc * 64 + n * 16 + ((lane >> 4) << 2);
        float4 bv = *(const float4*)&b2_in[col];
        st4(T1, rowT, col,
            gelu_f(acc[n][0] + bv.x), gelu_f(acc[n][1] + bv.y),
            gelu_f(acc[n][2] + bv.z), gelu_f(acc[n][3] + bv.w));
    }
    // S5: U2 = T + gelu(B1@Wh2 + bh2) -> T1 lo (last stage)
    stageWC<4, 4, 2, 1024, true>(WB + O_H2Wh, 128, (const US*)nullptr, 0,
                                 T1, 256, 0, 64, 0, wr * 16,
                                 Wb, 16384, 24576, 16384, tid, acc);
    #pragma unroll
    for (int n = 0; n < 4; ++n) {
        const int col = wc * 64 + n * 16 + ((lane >> 4) << 2);
        float4 bv = *(const float4*)&b2_hid[col];
        float t0, t1, t2, t3;
        ld4(T1, rowT, 128 + col, t0, t1, t2, t3);
        st4(T1, rowT, col,
            gelu_f(acc[n][0] + bv.x) + t0, gelu_f(acc[n][1] + bv.y) + t1,
            gelu_f(acc[n][2] + bv.z) + t2, gelu_f(acc[n][3] + bv.w) + t3);
    }
    __syncthreads();   // U2 visible before dot (cross-wave rows)
    // S6: scalar head: 128 rows x 8 threads, 16 cols each
    {
        const int r = tid >> 3, hh = tid & 7;   // r 0..127: side = r>>6
        float a = 0.f;
        u16x8 v0 = *(const u16x8*)&T1[swz(r, hh * 16, 256)];
        u16x8 v1 = *(const u16x8*)&T1[swz(r, hh * 16 + 8, 256)];
        #pragma unroll
        for (int e = 0; e < 8; ++e) {
            a += bf2f(v0[e]) * wout_s[hh * 16 + e];
            a += bf2f(v1[e]) * wout_s[hh * 16 + 8 + e];
        }
        a += __shfl_xor(a, 4);
        a += __shfl_xor(a, 2);
        a += __shfl_xor(a, 1);
        const int q = q0 + (r & 63);
        if ((lane & 7) == 0 && q < Q) outH[(size_t)(r >> 6) * Q + q] = a + b2_out[0];
    }
}

// ---------------------------------------------------------------------------
// SAGE layer: zout = zin + gelu( [agg|zin] @ Wcat^T + bl ), K=128, out 64
// ---------------------------------------------------------------------------
__global__ __launch_bounds__(256, 2)
void sage_gemm(const US* __restrict__ zin, const US* __restrict__ agg,
               const US* __restrict__ Wc, const float* __restrict__ bias,
               US* __restrict__ zout, int N)
{
    __shared__ __align__(16) US As[128 * 128];
    __shared__ __align__(16) US Ws[64 * 128];
    const int tid = threadIdx.x, lane = tid & 63, w = tid >> 6;
    const int grow0 = blockIdx.x * 128;
    {
        const int r = tid >> 1, hh = tid & 1;
        int row = grow0 + r; if (row >= N) row = N - 1;
        const US* src = hh ? (zin + (size_t)row * 64) : (agg + (size_t)row * 64);
        #pragma unroll
        for (int j = 0; j < 8; ++j)
            *(u16x8*)&As[swz(r, hh * 64 + 8 * j, 128)] = *(const u16x8*)(src + 8 * j);
    }
    #pragma unroll
    for (int j = 0; j < 4; ++j) {
        const int c = tid + 256 * j;
        *(u16x8*)&Ws[swz(c >> 4, (c & 15) * 8, 128)] =
            *(const u16x8*)(Wc + (size_t)(c >> 4) * 128 + (c & 15) * 8);
    }
    __syncthreads();
    const int rbw = w * 32;
    f32x4 acc[2][4];
    #pragma unroll
    for (int m = 0; m < 2; ++m)
        #pragma unroll
        for (int n = 0; n < 4; ++n) acc[m][n] = (f32x4){0.f, 0.f, 0.f, 0.f};
    #pragma unroll
    for (int kc = 0; kc < 2; ++kc)
        #pragma unroll
        for (int sub = 0; sub < 2; ++sub) {
            const int kk = kc * 64 + sub * 32 + ((lane >> 4) << 3);
            short8 a[2], b[4];
            #pragma unroll
            for (int m = 0; m < 2; ++m) a[m] = *(const short8*)&As[swz(rbw + m * 16 + (lane & 15), kk, 128)];
            #pragma unroll
            for (int n = 0; n < 4; ++n) b[n] = *(const short8*)&Ws[swz(n * 16 + (lane & 15), kk, 128)];
            #pragma unroll
            for (int m = 0; m < 2; ++m)
                #pragma unroll
                for (int n = 0; n < 4; ++n)
                    acc[m][n] = __builtin_amdgcn_mfma_f32_16x16x32_bf16(a[m], b[n], acc[m][n], 0, 0, 0);
        }
    #pragma unroll
    for (int m = 0; m < 2; ++m) {
        const int row0 = rbw + m * 16 + ((lane >> 4) << 2);
        #pragma unroll
        for (int n = 0; n < 4; ++n) {
            const int col = n * 16 + (lane & 15);
            const float bv = bias[col];
            #pragma unroll
            for (int r = 0; r < 4; ++r) {
                const int node = grow0 + row0 + r;
                if (node < N) {
                    const float v = gelu_f(acc[m][n][r] + bv) + bf2f(zin[(size_t)node * 64 + col]);
                    zout[(size_t)node * 64 + col] = f2bf(v);
                }
            }
        }
    }
}

// ---------------------------------------------------------------------------
// Weight prep (f32 -> bf16, strided stacking)
// ---------------------------------------------------------------------------
struct WSeg { const float* src; int dst; int n; int rl; int ldd; };
struct WPrm { WSeg s[20]; };

__global__ void prep_w(WPrm p, US* __restrict__ wb)
{
    WSeg sg = p.s[blockIdx.x];
    for (int i = threadIdx.x; i < sg.n; i += 256) {
        const int idx = sg.dst + (i / sg.rl) * sg.ldd + (i % sg.rl);
        wb[idx] = f2bf(sg.src[i]);
    }
}

// ---------------------------------------------------------------------------
// CSR build + aggregate + segment max + misc
// ---------------------------------------------------------------------------
__global__ void count_k(const int* __restrict__ dst, int* __restrict__ cnt, int E)
{
    int e = blockIdx.x * 256 + threadIdx.x;
    if (e < E) atomicAdd(&cnt[dst[e]], 1);
}

__global__ void scan_csr(const int* __restrict__ cnt, int n, int* __restrict__ indp, int* __restrict__ curs)
{
    __shared__ int wsum[16];
    __shared__ int carry_s;
    const int tid = threadIdx.x, lane = tid & 63, w = tid >> 6;
    if (tid == 0) carry_s = 0;
    __syncthreads();
    for (int base = 0; base < n; base += 1024) {
        const int i = base + tid;
        const int v = (i < n) ? cnt[i] : 0;
        int s = v;
        #pragma unroll
        for (int o = 1; o < 64; o <<= 1) { int t = __shfl_up(s, o); if (lane >= o) s += t; }
        if (lane == 63) wsum[w] = s;
        __syncthreads();
        if (w == 0 && lane < 16) {
            int ws2 = wsum[lane];
            #pragma unroll
            for (int o = 1; o < 16; o <<= 1) { int t = __shfl_up(ws2, o); if (lane >= o) ws2 += t; }
            wsum[lane] = ws2;
        }
        __syncthreads();
        const int carry = carry_s;
        const int woff  = (w == 0) ? 0 : wsum[w - 1];
        if (i < n) { const int excl = carry + woff + s - v; indp[i] = excl; curs[i] = excl; }
        __syncthreads();
        if (tid == 0) carry_s = carry + wsum[15];
        __syncthreads();
    }
    if (threadIdx.x == 0) indp[n] = carry_s;
}

__global__ void fill_k(const int* __restrict__ src, const int* __restrict__ dst,
                       int* __restrict__ curs, int* __restrict__ esrc, int E)
{
    int e = blockIdx.x * 256 + threadIdx.x;
    if (e < E) { int p = atomicAdd(&curs[dst[e]], 1); esrc[p] = src[e]; }
}

__global__ void sage_agg(const US* __restrict__ z, const int* __restrict__ indp,
                         const int* __restrict__ esrc, US* __restrict__ agg, int n)
{
    const int w = blockIdx.x * 4 + (threadIdx.x >> 6);
    const int lane = threadIdx.x & 63;
    if (w >= n) return;
    const int beg = indp[w], end = indp[w + 1];
    float acc = 0.f;
    int j = beg;
    for (; j + 4 <= end; j += 4) {
        const int s0 = esrc[j], s1 = esrc[j + 1], s2 = esrc[j + 2], s3 = esrc[j + 3];
        const float v0 = bf2f(z[(size_t)s0 * 64 + lane]);
        const float v1 = bf2f(z[(size_t)s1 * 64 + lane]);
        const float v2 = bf2f(z[(size_t)s2 * 64 + lane]);
        const float v3 = bf2f(z[(size_t)s3 * 64 + lane]);
        acc += (v0 + v1) + (v2 + v3);
    }
    for (; j < end; ++j) acc += bf2f(z[(size_t)esrc[j] * 64 + lane]);
    const float d = (float)(end - beg);
    agg[(size_t)w * 64 + lane] = f2bf(acc / fmaxf(d, 1.0f));
}

__global__ void segmax_k(const US* __restrict__ z, const int* __restrict__ batch,
                         UI* __restrict__ enc, int n, int per)
{
    const int w = blockIdx.x * 4 + (threadIdx.x >> 6);
    const int lane = threadIdx.x & 63;
    const int start = w * per;
    if (start >= n) return;
    const int end = (start + per < n) ? start + per : n;
    int g = batch[start];
    float m = -3.0e38f;
    for (int i = start; i < end; ++i) {
        const int b = batch[i];
        if (b != g) { atomicMax(&enc[(size_t)g * 64 + lane], encf(m)); g = b; m = -3.0e38f; }
        m = fmaxf(m, bf2f(z[(size_t)i * 64 + lane]));
    }
    atomicMax(&enc[(size_t)g * 64 + lane], encf(m));
}

__global__ void decode_ge(const UI* __restrict__ enc, US* __restrict__ geb)
{
    const int i = blockIdx.x * 256 + threadIdx.x;
    if (i < 4096) geb[i] = f2bf(decf(enc[i]));
}

__global__ void copy_bf2f(const US* __restrict__ z, float* __restrict__ o, long n)
{
    long i = (long)blockIdx.x * blockDim.x + threadIdx.x;
    const long stride = (long)gridDim.x * blockDim.x;
    for (; i < n; i += stride) o[i] = bf2f(z[i]);
}

// ---------------------------------------------------------------------------
extern "C" void kernel_launch(void* const* d_in, const int* in_sizes, int n_in,
                              void* d_out, int out_size, void* d_ws, size_t ws_size,
                              hipStream_t stream)
{
    (void)in_sizes; (void)n_in; (void)out_size; (void)ws_size;

    const float* x      = (const float*)d_in[0];
    const int*   batch  = (const int*)d_in[1];
    const int*   eidx   = (const int*)d_in[2];
    const int*   srcq   = (const int*)d_in[3];
    const int*   dstq   = (const int*)d_in[4];
    const float* em_in_b   = (const float*)d_in[6];
    const float* em_hid_b  = (const float*)d_in[8];
    const float* em_out_b  = (const float*)d_in[10];
    const float* em_proj_b = (const float*)d_in[12];
    const float* rho_in_b  = (const float*)d_in[14];
    const float* rho_hid_b = (const float*)d_in[16];
    const float* rho_out_b = (const float*)d_in[18];
    const float* rho_proj_b= (const float*)d_in[20];
    const float* c_ll_W[3] = {(const float*)d_in[21], (const float*)d_in[24], (const float*)d_in[27]};
    const float* c_ll_b[3] = {(const float*)d_in[22], (const float*)d_in[25], (const float*)d_in[28]};
    const float* c_lr_W[3] = {(const float*)d_in[23], (const float*)d_in[26], (const float*)d_in[29]};
    const float* h1_in_b   = (const float*)d_in[31];
    const float* h1_hid_b  = (const float*)d_in[33];
    const float* h1_out_b  = (const float*)d_in[35];
    const float* h1_proj_b = (const float*)d_in[37];
    const float* h2_in_b   = (const float*)d_in[39];
    const float* h2_hid_b  = (const float*)d_in[41];
    const float* h2_out_W  = (const float*)d_in[42];
    const float* h2_out_b  = (const float*)d_in[43];

    const int N = 50000, E = 1600000, Q = 500000;
    float* out = (float*)d_out;

    // ---- workspace layout ----
    char* wsb = (char*)d_ws;
    size_t off = 0;
    auto ALLOC = [&](size_t bytes) -> char* {
        char* p = wsb + off; off = (off + bytes + 255) & ~(size_t)255; return p;
    };
    US*  WB   = (US*)ALLOC((size_t)W_TOTAL * 2);
    US*  Ss   = (US*)ALLOC((size_t)N * 512 * 2);
    US*  z0   = (US*)ALLOC((size_t)N * 64 * 2);
    US*  z1   = (US*)ALLOC((size_t)N * 64 * 2);
    US*  aggB = (US*)ALLOC((size_t)N * 64 * 2);
    int* cnt  = (int*)ALLOC((size_t)N * 4);
    int* indp = (int*)ALLOC((size_t)(N + 1) * 4);
    int* curs = (int*)ALLOC((size_t)N * 4);
    int* esrc = (int*)ALLOC((size_t)E * 4);
    UI*  enc  = (UI*)ALLOC(4096 * 4);
    US*  geb  = (US*)ALLOC(4096 * 2);

    const int catOff[3] = {O_Cat1, O_Cat2, O_Cat3};

    WPrm pw; int si = 0;
    auto SEG = [&](const float* s, int o, int n, int rl, int ldd) {
        pw.s[si].src = s; pw.s[si].dst = o; pw.s[si].n = n; pw.s[si].rl = rl; pw.s[si].ldd = ldd; ++si;
    };
    SEG((const float*)d_in[5],  O_EmW1,          65536, 65536, 65536);
    SEG((const float*)d_in[11], O_EmW1 + 65536,  65536, 65536, 65536);
    SEG((const float*)d_in[7],  O_EmWh,          16384, 16384, 16384);
    SEG((const float*)d_in[9],  O_EmWo,          65536, 65536, 65536);
    SEG((const float*)d_in[13], O_RhoW1,         65536, 65536, 65536);
    SEG((const float*)d_in[19], O_RhoW1 + 65536, 65536, 65536, 65536);
    SEG((const float*)d_in[15], O_RhoWh,         16384, 16384, 16384);
    SEG((const float*)d_in[17], O_RhoWo,          8192,  8192,  8192);
    for (int i = 0; i < 3; ++i) {
        SEG(c_ll_W[i], catOff[i],      4096, 64, 128);
        SEG(c_lr_W[i], catOff[i] + 64, 4096, 64, 128);
    }
    SEG((const float*)d_in[30], O_H1W1,          24576, 24576, 24576);
    SEG((const float*)d_in[36], O_H1W1 + 24576,  24576, 24576, 24576);
    SEG((const float*)d_in[32], O_H1Wh,          16384, 16384, 16384);
    SEG((const float*)d_in[34], O_H1Wo,          16384, 16384, 16384);
    SEG((const float*)d_in[38], O_H2W1,          16384, 16384, 16384);
    SEG((const float*)d_in[40], O_H2Wh,          16384, 16384, 16384);
    prep_w<<<dim3(20), dim3(256), 0, stream>>>(pw, WB);

    // ---- CSR build ----
    hipMemsetAsync(cnt, 0, (size_t)N * 4, stream);
    count_k<<<dim3((E + 255) / 256), dim3(256), 0, stream>>>(eidx + E, cnt, E);
    scan_csr<<<dim3(1), dim3(1024), 0, stream>>>(cnt, N, indp, curs);
    fill_k<<<dim3((E + 255) / 256), dim3(256), 0, stream>>>(eidx, eidx + E, curs, esrc, E);

    // ---- Embedder + rho ----
    embed_fused<<<dim3(3125), dim3(1024), 0, stream>>>(x, WB, em_in_b, em_proj_b, em_hid_b, em_out_b, Ss);
    rho_fused<<<dim3((N + 63) / 64), dim3(512), 0, stream>>>(Ss, WB, rho_in_b, rho_proj_b, rho_hid_b, rho_out_b, z0, N);

    // ---- 3x SAGE residual ----
    US* zin = z0; US* zout = z1;
    for (int ci = 0; ci < 3; ++ci) {
        sage_agg<<<dim3((N + 3) / 4), dim3(256), 0, stream>>>(zin, indp, esrc, aggB, N);
        sage_gemm<<<dim3((N + 127) / 128), dim3(256), 0, stream>>>(zin, aggB, WB + catOff[ci], c_ll_b[ci], zout, N);
        US* t = zin; zin = zout; zout = t;
    }
    US* zf = zin;

    // ---- graph max-pool ----
    hipMemsetAsync(enc, 0, 4096 * 4, stream);
    segmax_k<<<dim3((N + 511) / 512), dim3(256), 0, stream>>>(zf, batch, enc, N, 128);
    decode_ge<<<dim3(16), dim3(256), 0, stream>>>(enc, geb);

    // ---- node_embeddings output ----
    copy_bf2f<<<dim3(2048), dim3(256), 0, stream>>>(zf, out, (long)N * 64);

    // ---- fused heads (64 queries/block, both sides, 16 waves/block) ----
    head_fused<<<dim3((Q + 63) / 64), dim3(1024), 0, stream>>>(
        srcq, dstq, batch, zf, geb, WB,
        h1_in_b, h1_proj_b, h1_hid_b, h1_out_b, h2_in_b, h2_hid_b, h2_out_W, h2_out_b,
        out + (size_t)N * 64, out + (size_t)N * 64 + 2 * (size_t)Q, Q);
}

// Round 13
// 1550.439 us; speedup vs baseline: 1.1839x; 1.0107x over previous
//
#include <hip/hip_runtime.h>

typedef unsigned short US;
typedef unsigned int   UI;
typedef short  short8 __attribute__((ext_vector_type(8)));
typedef US     u16x8  __attribute__((ext_vector_type(8)));
typedef float  f32x4  __attribute__((ext_vector_type(4)));

#define DEVI __device__ __forceinline__

DEVI float bf2f(US u){ UI i = ((UI)u) << 16; float f; __builtin_memcpy(&f, &i, 4); return f; }
DEVI US f2bf(float x){ UI i; __builtin_memcpy(&i, &x, 4); UI r = (i + 0x7FFFu + ((i >> 16) & 1u)) >> 16; return (US)r; }
// gelu (tanh-form as sigmoid), exp2+rcp hardware ops, no float-div sequence.
DEVI float gelu_f(float x){
    float x2 = x * x;
    float m  = x * fmaf(x2, -0.1029432f, -2.3022052f);
    float e  = __builtin_amdgcn_exp2f(m);
    return x * __builtin_amdgcn_rcpf(1.0f + e);
}
DEVI UI encf(float f){ UI u; __builtin_memcpy(&u, &f, 4); return (u & 0x80000000u) ? ~u : (u | 0x80000000u); }
DEVI float decf(UI u){ UI b = (u & 0x80000000u) ? (u ^ 0x80000000u) : ~u; float f; __builtin_memcpy(&f, &b, 4); return f; }
DEVI int swz(int r, int c, int ld){ int i = r * ld + c; return i ^ ((r & 7) << 3); }

// packed f32x2 -> bf16x2 (hardware RNE)
DEVI UI pkbf(float a, float b){ UI u; asm("v_cvt_pk_bf16_f32 %0, %1, %2" : "=v"(u) : "v"(a), "v"(b)); return u; }
DEVI void st4(US* T, int row, int col, float v0, float v1, float v2, float v3){
    uint2 p; p.x = pkbf(v0, v1); p.y = pkbf(v2, v3);
    *(uint2*)&T[swz(row, col, 256)] = p;
}
DEVI void ld4(const US* T, int row, int col, float& v0, float& v1, float& v2, float& v3){
    uint2 q = *(const uint2*)&T[swz(row, col, 256)];
    v0 = bf2f((US)(q.x & 0xffff)); v1 = bf2f((US)(q.x >> 16));
    v2 = bf2f((US)(q.y & 0xffff)); v3 = bf2f((US)(q.y >> 16));
}

// bf16 weight-buffer offsets (elements)
enum : int { O_EmW1 = 0, O_EmWh = 131072, O_EmWo = 147456, O_RhoW1 = 212992,
             O_RhoWh = 344064, O_RhoWo = 360448, O_Cat1 = 368640, O_Cat2 = 376832,
             O_Cat3 = 385024, O_H1W1 = 393216, O_H1Wh = 442368, O_H1Wo = 458752,
             O_H2W1 = 475136, O_H2Wh = 491520, W_TOTAL = 507904 };

// ---------------------------------------------------------------------------
// Double-buffered W-streaming stage (rho). SWAP=true: C^T epilogue.
// ---------------------------------------------------------------------------
template<int NT, int NKC, int NTHR, bool SWAP = false>
DEVI void stageWD(const US* __restrict__ Wg, int Kw, const US* __restrict__ A, int lda,
                  int ab0, int ab1, int ab2, int arow0, US* Wb, int tid, f32x4 (&acc)[NT])
{
    const int lane = tid & 63;
    const int wc = (tid >> 6) & 1;
    constexpr int SLAB = NT * 32 * 64;
    #pragma unroll
    for (int n = 0; n < NT; ++n) acc[n] = (f32x4){0.f, 0.f, 0.f, 0.f};
    constexpr int J = (NT * 256) / NTHR;
    u16x8 wreg[J];
    #pragma unroll
    for (int j = 0; j < J; ++j) {
        const int c = tid + NTHR * j;
        wreg[j] = *(const u16x8*)(Wg + (size_t)(c >> 3) * Kw + (c & 7) * 8);
    }
    #pragma unroll
    for (int j = 0; j < J; ++j) {
        const int c = tid + NTHR * j;
        *(u16x8*)&Wb[swz(c >> 3, (c & 7) * 8, 64)] = wreg[j];
    }
    #pragma unroll
    for (int kc = 0; kc < NKC; ++kc) {
        __syncthreads();
        if (kc + 1 < NKC) {
            #pragma unroll
            for (int j = 0; j < J; ++j) {
                const int c = tid + NTHR * j;
                wreg[j] = *(const u16x8*)(Wg + (size_t)(c >> 3) * Kw + (kc + 1) * 64 + (c & 7) * 8);
            }
        }
        const int ab = (kc == 0) ? ab0 : ((kc == 1) ? ab1 : ab2);
        const int bufr = (kc & 1) * SLAB;
        #pragma unroll
        for (int sub = 0; sub < 2; ++sub) {
            const int kk = sub * 32 + ((lane >> 4) << 3);
            short8 a = *(const short8*)&A[swz(arow0 + (lane & 15), ab + kk, lda)];
            #pragma unroll
            for (int n = 0; n < NT; ++n) {
                short8 b = *(const short8*)&Wb[bufr + swz(wc * (NT * 16) + n * 16 + (lane & 15), kk, 64)];
                if (SWAP) acc[n] = __builtin_amdgcn_mfma_f32_16x16x32_bf16(b, a, acc[n], 0, 0, 0);
                else      acc[n] = __builtin_amdgcn_mfma_f32_16x16x32_bf16(a, b, acc[n], 0, 0, 0);
            }
        }
        if (kc + 1 < NKC) {
            const int bufw = ((kc + 1) & 1) * SLAB;
            #pragma unroll
            for (int j = 0; j < J; ++j) {
                const int c = tid + NTHR * j;
                *(u16x8*)&Wb[bufw + swz(c >> 3, (c & 7) * 8, 64)] = wreg[j];
            }
        }
    }
    __syncthreads();
}

// ---------------------------------------------------------------------------
// Chained stage: per kc [bar; prefetch regs (next kc, or NEXT STAGE's slab0);
// MFMA; write regs to the slab not being read]. SWAP selects operand order.
// Parity/offsets are caller-provided (off0/off1 read slabs, wrN next slab0).
// ---------------------------------------------------------------------------
template<int NT, int NTN, int NKC, int NTHR, bool LAST, bool SWAP = true>
DEVI void stageWC(const US* __restrict__ Wg, int Kw, const US* __restrict__ nextWg, int nKw,
                  const US* __restrict__ A, int lda, int ab0, int ab1, int ab2, int arow0,
                  US* Wb, int off0, int off1, int wrN, int tid, f32x4 (&acc)[NT])
{
    const int lane = tid & 63;
    const int wc = (tid >> 6) & 1;
    #pragma unroll
    for (int n = 0; n < NT; ++n) acc[n] = (f32x4){0.f, 0.f, 0.f, 0.f};
    constexpr int J  = (NT  * 256) / NTHR;
    constexpr int JN = (NTN * 256) / NTHR;
    constexpr int JM = (J > JN) ? J : JN;
    u16x8 wreg[JM];
    #pragma unroll
    for (int kc = 0; kc < NKC; ++kc) {
        __syncthreads();
        if (kc + 1 < NKC) {
            #pragma unroll
            for (int j = 0; j < J; ++j) {
                const int c = tid + NTHR * j;
                wreg[j] = *(const u16x8*)(Wg + (size_t)(c >> 3) * Kw + (kc + 1) * 64 + (c & 7) * 8);
            }
        } else if (!LAST) {
            #pragma unroll
            for (int j = 0; j < JN; ++j) {
                const int c = tid + NTHR * j;
                wreg[j] = *(const u16x8*)(nextWg + (size_t)(c >> 3) * nKw + (c & 7) * 8);
            }
        }
        const int ab = (kc == 0) ? ab0 : ((kc == 1) ? ab1 : ab2);
        const int rd = (kc & 1) ? off1 : off0;
        #pragma unroll
        for (int sub = 0; sub < 2; ++sub) {
            const int kk = sub * 32 + ((lane >> 4) << 3);
            short8 a = *(const short8*)&A[swz(arow0 + (lane & 15), ab + kk, lda)];
            #pragma unroll
            for (int n = 0; n < NT; ++n) {
                short8 b = *(const short8*)&Wb[rd + swz(wc * (NT * 16) + n * 16 + (lane & 15), kk, 64)];
                if (SWAP) acc[n] = __builtin_amdgcn_mfma_f32_16x16x32_bf16(b, a, acc[n], 0, 0, 0);
                else      acc[n] = __builtin_amdgcn_mfma_f32_16x16x32_bf16(a, b, acc[n], 0, 0, 0);
            }
        }
        if (kc + 1 < NKC) {
            const int wr_ = (kc & 1) ? off0 : off1;
            #pragma unroll
            for (int j = 0; j < J; ++j) {
                const int c = tid + NTHR * j;
                *(u16x8*)&Wb[wr_ + swz(c >> 3, (c & 7) * 8, 64)] = wreg[j];
            }
        } else if (!LAST) {
            #pragma unroll
            for (int j = 0; j < JN; ++j) {
                const int c = tid + NTHR * j;
                *(u16x8*)&Wb[wrN + swz(c >> 3, (c & 7) * 8, 64)] = wreg[j];
            }
        }
    }
    __syncthreads();
}

template<int NT, int NTHR>
DEVI void preloadW(const US* __restrict__ Wg, int Kw, US* Wb, int off, int tid)
{
    constexpr int J = (NT * 256) / NTHR;
    #pragma unroll
    for (int j = 0; j < J; ++j) {
        const int c = tid + NTHR * j;
        u16x8 v = *(const u16x8*)(Wg + (size_t)(c >> 3) * Kw + (c & 7) * 8);
        *(u16x8*)&Wb[off + swz(c >> 3, (c & 7) * 8, 64)] = v;
    }
}

// ---------------------------------------------------------------------------
// Fused embedder v3: fully chained S1 -> S2 -> S3a -> S3b.
// Buffer walk: S1 reads 0/16384 alt (ends 16384; kc7 preloads S2slab0 -> 0);
// S2 (slab 8K) reads 0 -> 8192, kc1 preloads S3a slab0 -> 16384;
// S3a reads 16384 -> 0, kc1 preloads S3b slab0 -> 16384; S3b reads 16384 -> 0.
// ---------------------------------------------------------------------------
__global__ __launch_bounds__(1024, 4)
void embed_fused(const float* __restrict__ x, const US* __restrict__ WB,
                 const float* __restrict__ b_in, const float* __restrict__ b_proj,
                 const float* __restrict__ b_hid, const float* __restrict__ b_out,
                 US* __restrict__ Ss)
{
    __shared__ __align__(16) US T1[128 * 256];
    __shared__ __align__(16) US Wb[2 * 16384];
    const int tid = threadIdx.x, lane = tid & 63, w = tid >> 6;
    const int wr = w >> 1, wc = w & 1;
    const int h = lane >> 4;
    const int grow0 = blockIdx.x * 128;
    const int rowT = wr * 16 + (lane & 15);

    { // ---- S1: [gelu(x@Wi+bi) | x@Wp+bp], K=512 (8 kc), SWAP ----
        f32x4 acc[8];
        #pragma unroll
        for (int n = 0; n < 8; ++n) acc[n] = (f32x4){0.f, 0.f, 0.f, 0.f};
        const float* xp = x + (size_t)(grow0 + rowT) * 512 + h * 8;
        float4 p00, p01, p10, p11;
        u16x8 wreg[2];
        auto loadA = [&](int kc) {
            p00 = *(const float4*)(xp + kc * 64);
            p01 = *(const float4*)(xp + kc * 64 + 4);
            p10 = *(const float4*)(xp + kc * 64 + 32);
            p11 = *(const float4*)(xp + kc * 64 + 36);
        };
        auto loadW = [&](int kc) {
            #pragma unroll
            for (int j = 0; j < 2; ++j) {
                const int c = tid + 1024 * j;
                wreg[j] = *(const u16x8*)(WB + O_EmW1 + (size_t)(c >> 3) * 512 + kc * 64 + (c & 7) * 8);
            }
        };
        auto writeW = [&](int buf) {
            #pragma unroll
            for (int j = 0; j < 2; ++j) {
                const int c = tid + 1024 * j;
                *(u16x8*)&Wb[buf * 16384 + swz(c >> 3, (c & 7) * 8, 64)] = wreg[j];
            }
        };
        loadA(0); loadW(0); writeW(0);
        for (int kc = 0; kc < 8; ++kc) {
            __syncthreads();
            short8 a0, a1;
            {
                uint4 q;
                q.x = pkbf(p00.x, p00.y); q.y = pkbf(p00.z, p00.w);
                q.z = pkbf(p01.x, p01.y); q.w = pkbf(p01.z, p01.w);
                __builtin_memcpy(&a0, &q, 16);
                q.x = pkbf(p10.x, p10.y); q.y = pkbf(p10.z, p10.w);
                q.z = pkbf(p11.x, p11.y); q.w = pkbf(p11.z, p11.w);
                __builtin_memcpy(&a1, &q, 16);
            }
            u16x8 nx;
            if (kc < 7) { loadA(kc + 1); loadW(kc + 1); }
            else        { nx = *(const u16x8*)(WB + O_EmWh + (size_t)(tid >> 3) * 128 + (tid & 7) * 8); }
            const int bufr = (kc & 1) * 16384;
            #pragma unroll
            for (int n = 0; n < 8; ++n) {
                short8 b = *(const short8*)&Wb[bufr + swz(wc * 128 + n * 16 + (lane & 15), h * 8, 64)];
                acc[n] = __builtin_amdgcn_mfma_f32_16x16x32_bf16(b, a0, acc[n], 0, 0, 0);
            }
            #pragma unroll
            for (int n = 0; n < 8; ++n) {
                short8 b = *(const short8*)&Wb[bufr + swz(wc * 128 + n * 16 + (lane & 15), 32 + h * 8, 64)];
                acc[n] = __builtin_amdgcn_mfma_f32_16x16x32_bf16(b, a1, acc[n], 0, 0, 0);
            }
            if (kc < 7) writeW((kc + 1) & 1);
            else        *(u16x8*)&Wb[swz(tid >> 3, (tid & 7) * 8, 64)] = nx;  // S2 slab0 -> 0
        }
        #pragma unroll
        for (int n = 0; n < 8; ++n) {
            const int col = wc * 128 + n * 16 + h * 4;
            float4 bv = (col < 128) ? *(const float4*)&b_in[col]
                                    : *(const float4*)&b_proj[col - 128];
            float v0 = acc[n][0] + bv.x, v1 = acc[n][1] + bv.y;
            float v2 = acc[n][2] + bv.z, v3 = acc[n][3] + bv.w;
            if (col < 128) { v0 = gelu_f(v0); v1 = gelu_f(v1); v2 = gelu_f(v2); v3 = gelu_f(v3); }
            st4(T1, rowT, col, v0, v1, v2, v3);
        }
    }
    { // ---- S2: U = s + gelu(t1@Wh+bh) -> T1 lo, SWAP (next = EmWo p0) ----
        f32x4 acc[4];
        stageWC<4, 8, 2, 1024, false, true>(WB + O_EmWh, 128, WB + O_EmWo, 128,
                                            T1, 256, 0, 64, 0, wr * 16,
                                            Wb, 0, 8192, 16384, tid, acc);
        #pragma unroll
        for (int n = 0; n < 4; ++n) {
            const int col = wc * 64 + n * 16 + h * 4;
            float4 bv = *(const float4*)&b_hid[col];
            float s0, s1, s2, s3;
            ld4(T1, rowT, 128 + col, s0, s1, s2, s3);
            st4(T1, rowT, col,
                gelu_f(acc[n][0] + bv.x) + s0, gelu_f(acc[n][1] + bv.y) + s1,
                gelu_f(acc[n][2] + bv.z) + s2, gelu_f(acc[n][3] + bv.w) + s3);
        }
    }
    { // ---- S3a: cols 0..255 of EmWo, sum8 (non-swap; next = EmWo p1) ----
        f32x4 acc[8];
        stageWC<8, 8, 2, 1024, false, false>(WB + O_EmWo, 128, WB + O_EmWo + (size_t)256 * 128, 128,
                                             T1, 256, 0, 64, 0, wr * 16,
                                             Wb, 16384, 0, 16384, tid, acc);
        #pragma unroll
        for (int n = 0; n < 8; ++n) {
            const int col = wc * 128 + n * 16 + (lane & 15);
            const float bv = b_out[col];
            float s = 0.f;
            #pragma unroll
            for (int r = 0; r < 4; ++r) s += gelu_f(acc[n][r] + bv);
            s += __shfl_xor(s, 16);
            if (((lane >> 4) & 1) == 0) {
                const int node = (grow0 >> 3) + wr * 2 + (lane >> 5);
                Ss[(size_t)node * 512 + col] = f2bf(s);
            }
        }
    }
    { // ---- S3b: cols 256..511, sum8 (non-swap, LAST) ----
        f32x4 acc[8];
        stageWC<8, 8, 2, 1024, true, false>(WB + O_EmWo + (size_t)256 * 128, 128, (const US*)nullptr, 0,
                                            T1, 256, 0, 64, 0, wr * 16,
                                            Wb, 16384, 0, 16384, tid, acc);
        #pragma unroll
        for (int n = 0; n < 8; ++n) {
            const int col = wc * 128 + n * 16 + (lane & 15);
            const float bv = b_out[256 + col];
            float s = 0.f;
            #pragma unroll
            for (int r = 0; r < 4; ++r) s += gelu_f(acc[n][r] + bv);
            s += __shfl_xor(s, 16);
            if (((lane >> 4) & 1) == 0) {
                const int node = (grow0 >> 3) + wr * 2 + (lane >> 5);
                Ss[(size_t)node * 512 + 256 + col] = f2bf(s);
            }
        }
    }
}

// ---------------------------------------------------------------------------
// Fused rho v2 (as R12).
// ---------------------------------------------------------------------------
__global__ __launch_bounds__(512, 2)
void rho_fused(const US* __restrict__ Ss, const US* __restrict__ WB,
               const float* __restrict__ b_in, const float* __restrict__ b_proj,
               const float* __restrict__ b_hid, const float* __restrict__ b_out,
               US* __restrict__ zo, int N)
{
    __shared__ __align__(16) US T1[64 * 256];
    __shared__ __align__(16) US Wb[256 * 64];
    const int tid = threadIdx.x, lane = tid & 63, w = tid >> 6;
    const int wr = w >> 1, wc = w & 1;
    const int h = lane >> 4;
    const int grow0 = blockIdx.x * 64;
    const int rowT = wr * 16 + (lane & 15);

    { // ---- S1: out 256, K=512, SWAP, A direct from global ----
        f32x4 acc[8];
        #pragma unroll
        for (int n = 0; n < 8; ++n) acc[n] = (f32x4){0.f, 0.f, 0.f, 0.f};
        int arow = grow0 + rowT; if (arow >= N) arow = N - 1;
        const US* sp = Ss + (size_t)arow * 512 + h * 8;
        u16x8 a0r, a1r, wreg[4];
        auto loadA = [&](int kc) {
            a0r = *(const u16x8*)(sp + kc * 64);
            a1r = *(const u16x8*)(sp + kc * 64 + 32);
        };
        auto loadW = [&](int kc) {
            #pragma unroll
            for (int j = 0; j < 4; ++j) {
                const int c = tid + 512 * j;
                wreg[j] = *(const u16x8*)(WB + O_RhoW1 + (size_t)(c >> 3) * 512 + kc * 64 + (c & 7) * 8);
            }
        };
        loadA(0); loadW(0);
        for (int kc = 0; kc < 8; ++kc) {
            __syncthreads();
            #pragma unroll
            for (int j = 0; j < 4; ++j) {
                const int c = tid + 512 * j;
                *(u16x8*)&Wb[swz(c >> 3, (c & 7) * 8, 64)] = wreg[j];
            }
            __syncthreads();
            if (kc < 7) loadW(kc + 1);
            short8 a0, a1;
            __builtin_memcpy(&a0, &a0r, 16);
            __builtin_memcpy(&a1, &a1r, 16);
            #pragma unroll
            for (int n = 0; n < 8; ++n) {
                short8 b = *(const short8*)&Wb[swz(wc * 128 + n * 16 + (lane & 15), h * 8, 64)];
                acc[n] = __builtin_amdgcn_mfma_f32_16x16x32_bf16(b, a0, acc[n], 0, 0, 0);
            }
            #pragma unroll
            for (int n = 0; n < 8; ++n) {
                short8 b = *(const short8*)&Wb[swz(wc * 128 + n * 16 + (lane & 15), 32 + h * 8, 64)];
                acc[n] = __builtin_amdgcn_mfma_f32_16x16x32_bf16(b, a1, acc[n], 0, 0, 0);
            }
            if (kc < 7) loadA(kc + 1);
        }
        __syncthreads();
        #pragma unroll
        for (int n = 0; n < 8; ++n) {
            const int col = wc * 128 + n * 16 + h * 4;
            float4 bv = (col < 128) ? *(const float4*)&b_in[col]
                                    : *(const float4*)&b_proj[col - 128];
            float v0 = acc[n][0] + bv.x, v1 = acc[n][1] + bv.y;
            float v2 = acc[n][2] + bv.z, v3 = acc[n][3] + bv.w;
            if (col < 128) { v0 = gelu_f(v0); v1 = gelu_f(v1); v2 = gelu_f(v2); v3 = gelu_f(v3); }
            st4(T1, rowT, col, v0, v1, v2, v3);
        }
    }
    { // ---- S2: RU -> T1 lo, SWAP ----
        f32x4 acc[4];
        stageWD<4, 2, 512, true>(WB + O_RhoWh, 128, T1, 256, 0, 64, 0, wr * 16, Wb, tid, acc);
        #pragma unroll
        for (int n = 0; n < 4; ++n) {
            const int col = wc * 64 + n * 16 + h * 4;
            float4 bv = *(const float4*)&b_hid[col];
            float s0, s1, s2, s3;
            ld4(T1, rowT, 128 + col, s0, s1, s2, s3);
            st4(T1, rowT, col,
                gelu_f(acc[n][0] + bv.x) + s0, gelu_f(acc[n][1] + bv.y) + s1,
                gelu_f(acc[n][2] + bv.z) + s2, gelu_f(acc[n][3] + bv.w) + s3);
        }
    }
    { // ---- S3: out 64 ----
        f32x4 acc[2];
        stageWD<2, 2, 512>(WB + O_RhoWo, 128, T1, 256, 0, 64, 0, wr * 16, Wb, tid, acc);
        #pragma unroll
        for (int n = 0; n < 2; ++n) {
            const int col = wc * 32 + n * 16 + (lane & 15);
            const float bv = b_out[col];
            #pragma unroll
            for (int r = 0; r < 4; ++r) {
                const int node = grow0 + wr * 16 + h * 4 + r;
                if (node < N) zo[(size_t)node * 64 + col] = f2bf(acc[n][r] + bv);
            }
        }
    }
}

// ---------------------------------------------------------------------------
// Fused head v7 (as R12, measured 570us).
// ---------------------------------------------------------------------------
__global__ __launch_bounds__(1024, 4)
void head_fused(const int* __restrict__ srcq, const int* __restrict__ dstq,
                const int* __restrict__ batch, const US* __restrict__ z,
                const US* __restrict__ geb, const US* __restrict__ WB,
                const float* __restrict__ b1_in, const float* __restrict__ b1_proj,
                const float* __restrict__ b1_hid, const float* __restrict__ b1_out,
                const float* __restrict__ b2_in, const float* __restrict__ b2_hid,
                const float* __restrict__ w2_out, const float* __restrict__ b2_out,
                float* __restrict__ outH, float* __restrict__ outXY, int Q)
{
    __shared__ __align__(16) US A0[64 * 192];
    __shared__ __align__(16) US T1[128 * 256];
    __shared__ __align__(16) US Wb[2 * 16384];
    __shared__ float wout_s[128];
    const int tid = threadIdx.x, lane = tid & 63, w = tid >> 6;
    const int wr = w >> 1, wc = w & 1;
    const int q0 = blockIdx.x * 64;
    const int s1a = (wr < 4) ? 0 : 64;
    const int s1b = (wr < 4) ? 64 : 0;
    const int arowS1 = (wr & 3) * 16;
    const int rowS1 = (wr >> 2) * 64 + arowS1 + (lane & 15);
    const int rowT  = wr * 16 + (lane & 15);

    preloadW<8, 1024>(WB + O_H1W1, 192, Wb, 0, tid);

    { // gather: 8 threads per query row (512 threads active)
        if (tid < 512) {
            const int r = tid >> 3, hh = tid & 7;
            const int q = q0 + r;
            const int qc = (q < Q) ? q : (Q - 1);
            const int s = srcq[qc], d = dstq[qc];
            const int g = batch[s];
            *(u16x8*)&A0[swz(r, hh * 8, 192)]       = *(const u16x8*)(z + (size_t)s * 64 + hh * 8);
            *(u16x8*)&A0[swz(r, 64 + hh * 8, 192)]  = *(const u16x8*)(z + (size_t)d * 64 + hh * 8);
            *(u16x8*)&A0[swz(r, 128 + hh * 8, 192)] = *(const u16x8*)(geb + (size_t)g * 64 + hh * 8);
        }
        if (tid < 128) wout_s[tid] = w2_out[tid];
    }
    __syncthreads();
    { // xy output (f32)
        const int row = tid >> 4;
        const int qu  = tid & 15;
        #pragma unroll
        for (int jj = 0; jj < 3; ++jj) {
            const int c4 = (jj * 16 + qu) * 4;
            if (q0 + row < Q) {
                const US* p = &A0[swz(row, c4, 192)];
                float4 o;
                o.x = bf2f(p[0]); o.y = bf2f(p[1]); o.z = bf2f(p[2]); o.w = bf2f(p[3]);
                *(float4*)&outXY[(size_t)(q0 + row) * 192 + c4] = o;
            }
        }
    }
    { // S1 merged: [t1 | s1], out 256 cols, K=192 (chained: next = H1Wh)
        f32x4 acc8[8];
        stageWC<8, 4, 3, 1024, false>(WB + O_H1W1, 192, WB + O_H1Wh, 128,
                                      A0, 192, s1a, s1b, 128, arowS1,
                                      Wb, 0, 16384, 16384, tid, acc8);
        #pragma unroll
        for (int n = 0; n < 8; ++n) {
            const int col = wc * 128 + n * 16 + ((lane >> 4) << 2);
            float4 bv = (col < 128) ? *(const float4*)&b1_in[col]
                                    : *(const float4*)&b1_proj[col - 128];
            float v0 = acc8[n][0] + bv.x, v1 = acc8[n][1] + bv.y;
            float v2 = acc8[n][2] + bv.z, v3 = acc8[n][3] + bv.w;
            if (col < 128) { v0 = gelu_f(v0); v1 = gelu_f(v1); v2 = gelu_f(v2); v3 = gelu_f(v3); }
            st4(T1, rowS1, col, v0, v1, v2, v3);
        }
    }
    f32x4 acc[4];
    // S2: U = s1 + gelu(t1@Wh + bh) -> T1 lo (next = H1Wo)
    stageWC<4, 4, 2, 1024, false>(WB + O_H1Wh, 128, WB + O_H1Wo, 128,
                                  T1, 256, 0, 64, 0, wr * 16,
                                  Wb, 16384, 24576, 16384, tid, acc);
    #pragma unroll
    for (int n = 0; n < 4; ++n) {
        const int col = wc * 64 + n * 16 + ((lane >> 4) << 2);
        float4 bv = *(const float4*)&b1_hid[col];
        float s0, s1, s2, s3;
        ld4(T1, rowT, 128 + col, s0, s1, s2, s3);
        st4(T1, rowT, col,
            gelu_f(acc[n][0] + bv.x) + s0, gelu_f(acc[n][1] + bv.y) + s1,
            gelu_f(acc[n][2] + bv.z) + s2, gelu_f(acc[n][3] + bv.w) + s3);
    }
    // S3: T = relu(U@Wo + bo) -> T1 hi (next = H2W1)
    stageWC<4, 4, 2, 1024, false>(WB + O_H1Wo, 128, WB + O_H2W1, 128,
                                  T1, 256, 0, 64, 0, wr * 16,
                                  Wb, 16384, 24576, 16384, tid, acc);
    #pragma unroll
    for (int n = 0; n < 4; ++n) {
        const int col = wc * 64 + n * 16 + ((lane >> 4) << 2);
        float4 bv = *(const float4*)&b1_out[col];
        st4(T1, rowT, 128 + col,
            fmaxf(acc[n][0] + bv.x, 0.f), fmaxf(acc[n][1] + bv.y, 0.f),
            fmaxf(acc[n][2] + bv.z, 0.f), fmaxf(acc[n][3] + bv.w, 0.f));
    }
    // S4: B1 = gelu(T@W2 + b2) -> T1 lo (A = T1 hi; next = H2Wh)
    stageWC<4, 4, 2, 1024, false>(WB + O_H2W1, 128, WB + O_H2Wh, 128,
                                  T1, 256, 128, 192, 0, wr * 16,
                                  Wb, 16384, 24576, 16384, tid, acc);
    #pragma unroll
    for (int n = 0; n < 4; ++n) {
        const int col = wc * 64 + n * 16 + ((lane >> 4) << 2);
        float4 bv = *(const float4*)&b2_in[col];
        st4(T1, rowT, col,
            gelu_f(acc[n][0] + bv.x), gelu_f(acc[n][1] + bv.y),
            gelu_f(acc[n][2] + bv.z), gelu_f(acc[n][3] + bv.w));
    }
    // S5: U2 = T + gelu(B1@Wh2 + bh2) -> T1 lo (last stage)
    stageWC<4, 4, 2, 1024, true>(WB + O_H2Wh, 128, (const US*)nullptr, 0,
                                 T1, 256, 0, 64, 0, wr * 16,
                                 Wb, 16384, 24576, 16384, tid, acc);
    #pragma unroll
    for (int n = 0; n < 4; ++n) {
        const int col = wc * 64 + n * 16 + ((lane >> 4) << 2);
        float4 bv = *(const float4*)&b2_hid[col];
        float t0, t1, t2, t3;
        ld4(T1, rowT, 128 + col, t0, t1, t2, t3);
        st4(T1, rowT, col,
            gelu_f(acc[n][0] + bv.x) + t0, gelu_f(acc[n][1] + bv.y) + t1,
            gelu_f(acc[n][2] + bv.z) + t2, gelu_f(acc[n][3] + bv.w) + t3);
    }
    __syncthreads();
    // S6: scalar head: 128 rows x 8 threads, 16 cols each
    {
        const int r = tid >> 3, hh = tid & 7;
        float a = 0.f;
        u16x8 v0 = *(const u16x8*)&T1[swz(r, hh * 16, 256)];
        u16x8 v1 = *(const u16x8*)&T1[swz(r, hh * 16 + 8, 256)];
        #pragma unroll
        for (int e = 0; e < 8; ++e) {
            a += bf2f(v0[e]) * wout_s[hh * 16 + e];
            a += bf2f(v1[e]) * wout_s[hh * 16 + 8 + e];
        }
        a += __shfl_xor(a, 4);
        a += __shfl_xor(a, 2);
        a += __shfl_xor(a, 1);
        const int q = q0 + (r & 63);
        if ((lane & 7) == 0 && q < Q) outH[(size_t)(r >> 6) * Q + q] = a + b2_out[0];
    }
}

// ---------------------------------------------------------------------------
// SAGE layer: zout = zin + gelu( [agg|zin] @ Wcat^T + bl ), K=128, out 64
// ---------------------------------------------------------------------------
__global__ __launch_bounds__(256, 2)
void sage_gemm(const US* __restrict__ zin, const US* __restrict__ agg,
               const US* __restrict__ Wc, const float* __restrict__ bias,
               US* __restrict__ zout, int N)
{
    __shared__ __align__(16) US As[128 * 128];
    __shared__ __align__(16) US Ws[64 * 128];
    const int tid = threadIdx.x, lane = tid & 63, w = tid >> 6;
    const int grow0 = blockIdx.x * 128;
    {
        const int r = tid >> 1, hh = tid & 1;
        int row = grow0 + r; if (row >= N) row = N - 1;
        const US* src = hh ? (zin + (size_t)row * 64) : (agg + (size_t)row * 64);
        #pragma unroll
        for (int j = 0; j < 8; ++j)
            *(u16x8*)&As[swz(r, hh * 64 + 8 * j, 128)] = *(const u16x8*)(src + 8 * j);
    }
    #pragma unroll
    for (int j = 0; j < 4; ++j) {
        const int c = tid + 256 * j;
        *(u16x8*)&Ws[swz(c >> 4, (c & 15) * 8, 128)] =
            *(const u16x8*)(Wc + (size_t)(c >> 4) * 128 + (c & 15) * 8);
    }
    __syncthreads();
    const int rbw = w * 32;
    f32x4 acc[2][4];
    #pragma unroll
    for (int m = 0; m < 2; ++m)
        #pragma unroll
        for (int n = 0; n < 4; ++n) acc[m][n] = (f32x4){0.f, 0.f, 0.f, 0.f};
    #pragma unroll
    for (int kc = 0; kc < 2; ++kc)
        #pragma unroll
        for (int sub = 0; sub < 2; ++sub) {
            const int kk = kc * 64 + sub * 32 + ((lane >> 4) << 3);
            short8 a[2], b[4];
            #pragma unroll
            for (int m = 0; m < 2; ++m) a[m] = *(const short8*)&As[swz(rbw + m * 16 + (lane & 15), kk, 128)];
            #pragma unroll
            for (int n = 0; n < 4; ++n) b[n] = *(const short8*)&Ws[swz(n * 16 + (lane & 15), kk, 128)];
            #pragma unroll
            for (int m = 0; m < 2; ++m)
                #pragma unroll
                for (int n = 0; n < 4; ++n)
                    acc[m][n] = __builtin_amdgcn_mfma_f32_16x16x32_bf16(a[m], b[n], acc[m][n], 0, 0, 0);
        }
    #pragma unroll
    for (int m = 0; m < 2; ++m) {
        const int row0 = rbw + m * 16 + ((lane >> 4) << 2);
        #pragma unroll
        for (int n = 0; n < 4; ++n) {
            const int col = n * 16 + (lane & 15);
            const float bv = bias[col];
            #pragma unroll
            for (int r = 0; r < 4; ++r) {
                const int node = grow0 + row0 + r;
                if (node < N) {
                    const float v = gelu_f(acc[m][n][r] + bv) + bf2f(zin[(size_t)node * 64 + col]);
                    zout[(size_t)node * 64 + col] = f2bf(v);
                }
            }
        }
    }
}

// ---------------------------------------------------------------------------
// Weight prep (f32 -> bf16, strided stacking)
// ---------------------------------------------------------------------------
struct WSeg { const float* src; int dst; int n; int rl; int ldd; };
struct WPrm { WSeg s[20]; };

__global__ void prep_w(WPrm p, US* __restrict__ wb)
{
    WSeg sg = p.s[blockIdx.x];
    for (int i = threadIdx.x; i < sg.n; i += 256) {
        const int idx = sg.dst + (i / sg.rl) * sg.ldd + (i % sg.rl);
        wb[idx] = f2bf(sg.src[i]);
    }
}

// ---------------------------------------------------------------------------
// CSR build + aggregate + segment max + misc
// ---------------------------------------------------------------------------
__global__ void count_k(const int* __restrict__ dst, int* __restrict__ cnt, int E)
{
    int e = blockIdx.x * 256 + threadIdx.x;
    if (e < E) atomicAdd(&cnt[dst[e]], 1);
}

__global__ void scan_csr(const int* __restrict__ cnt, int n, int* __restrict__ indp, int* __restrict__ curs)
{
    __shared__ int wsum[16];
    __shared__ int carry_s;
    const int tid = threadIdx.x, lane = tid & 63, w = tid >> 6;
    if (tid == 0) carry_s = 0;
    __syncthreads();
    for (int base = 0; base < n; base += 1024) {
        const int i = base + tid;
        const int v = (i < n) ? cnt[i] : 0;
        int s = v;
        #pragma unroll
        for (int o = 1; o < 64; o <<= 1) { int t = __shfl_up(s, o); if (lane >= o) s += t; }
        if (lane == 63) wsum[w] = s;
        __syncthreads();
        if (w == 0 && lane < 16) {
            int ws2 = wsum[lane];
            #pragma unroll
            for (int o = 1; o < 16; o <<= 1) { int t = __shfl_up(ws2, o); if (lane >= o) ws2 += t; }
            wsum[lane] = ws2;
        }
        __syncthreads();
        const int carry = carry_s;
        const int woff  = (w == 0) ? 0 : wsum[w - 1];
        if (i < n) { const int excl = carry + woff + s - v; indp[i] = excl; curs[i] = excl; }
        __syncthreads();
        if (tid == 0) carry_s = carry + wsum[15];
        __syncthreads();
    }
    if (threadIdx.x == 0) indp[n] = carry_s;
}

__global__ void fill_k(const int* __restrict__ src, const int* __restrict__ dst,
                       int* __restrict__ curs, int* __restrict__ esrc, int E)
{
    int e = blockIdx.x * 256 + threadIdx.x;
    if (e < E) { int p = atomicAdd(&curs[dst[e]], 1); esrc[p] = src[e]; }
}

__global__ void sage_agg(const US* __restrict__ z, const int* __restrict__ indp,
                         const int* __restrict__ esrc, US* __restrict__ agg, int n)
{
    const int w = blockIdx.x * 4 + (threadIdx.x >> 6);
    const int lane = threadIdx.x & 63;
    if (w >= n) return;
    const int beg = indp[w], end = indp[w + 1];
    float acc = 0.f;
    int j = beg;
    for (; j + 4 <= end; j += 4) {
        const int s0 = esrc[j], s1 = esrc[j + 1], s2 = esrc[j + 2], s3 = esrc[j + 3];
        const float v0 = bf2f(z[(size_t)s0 * 64 + lane]);
        const float v1 = bf2f(z[(size_t)s1 * 64 + lane]);
        const float v2 = bf2f(z[(size_t)s2 * 64 + lane]);
        const float v3 = bf2f(z[(size_t)s3 * 64 + lane]);
        acc += (v0 + v1) + (v2 + v3);
    }
    for (; j < end; ++j) acc += bf2f(z[(size_t)esrc[j] * 64 + lane]);
    const float d = (float)(end - beg);
    agg[(size_t)w * 64 + lane] = f2bf(acc / fmaxf(d, 1.0f));
}

__global__ void segmax_k(const US* __restrict__ z, const int* __restrict__ batch,
                         UI* __restrict__ enc, int n, int per)
{
    const int w = blockIdx.x * 4 + (threadIdx.x >> 6);
    const int lane = threadIdx.x & 63;
    const int start = w * per;
    if (start >= n) return;
    const int end = (start + per < n) ? start + per : n;
    int g = batch[start];
    float m = -3.0e38f;
    for (int i = start; i < end; ++i) {
        const int b = batch[i];
        if (b != g) { atomicMax(&enc[(size_t)g * 64 + lane], encf(m)); g = b; m = -3.0e38f; }
        m = fmaxf(m, bf2f(z[(size_t)i * 64 + lane]));
    }
    atomicMax(&enc[(size_t)g * 64 + lane], encf(m));
}

__global__ void decode_ge(const UI* __restrict__ enc, US* __restrict__ geb)
{
    const int i = blockIdx.x * 256 + threadIdx.x;
    if (i < 4096) geb[i] = f2bf(decf(enc[i]));
}

__global__ void copy_bf2f(const US* __restrict__ z, float* __restrict__ o, long n)
{
    long i = (long)blockIdx.x * blockDim.x + threadIdx.x;
    const long stride = (long)gridDim.x * blockDim.x;
    for (; i < n; i += stride) o[i] = bf2f(z[i]);
}

// ---------------------------------------------------------------------------
extern "C" void kernel_launch(void* const* d_in, const int* in_sizes, int n_in,
                              void* d_out, int out_size, void* d_ws, size_t ws_size,
                              hipStream_t stream)
{
    (void)in_sizes; (void)n_in; (void)out_size; (void)ws_size;

    const float* x      = (const float*)d_in[0];
    const int*   batch  = (const int*)d_in[1];
    const int*   eidx   = (const int*)d_in[2];
    const int*   srcq   = (const int*)d_in[3];
    const int*   dstq   = (const int*)d_in[4];
    const float* em_in_b   = (const float*)d_in[6];
    const float* em_hid_b  = (const float*)d_in[8];
    const float* em_out_b  = (const float*)d_in[10];
    const float* em_proj_b = (const float*)d_in[12];
    const float* rho_in_b  = (const float*)d_in[14];
    const float* rho_hid_b = (const float*)d_in[16];
    const float* rho_out_b = (const float*)d_in[18];
    const float* rho_proj_b= (const float*)d_in[20];
    const float* c_ll_W[3] = {(const float*)d_in[21], (const float*)d_in[24], (const float*)d_in[27]};
    const float* c_ll_b[3] = {(const float*)d_in[22], (const float*)d_in[25], (const float*)d_in[28]};
    const float* c_lr_W[3] = {(const float*)d_in[23], (const float*)d_in[26], (const float*)d_in[29]};
    const float* h1_in_b   = (const float*)d_in[31];
    const float* h1_hid_b  = (const float*)d_in[33];
    const float* h1_out_b  = (const float*)d_in[35];
    const float* h1_proj_b = (const float*)d_in[37];
    const float* h2_in_b   = (const float*)d_in[39];
    const float* h2_hid_b  = (const float*)d_in[41];
    const float* h2_out_W  = (const float*)d_in[42];
    const float* h2_out_b  = (const float*)d_in[43];

    const int N = 50000, E = 1600000, Q = 500000;
    float* out = (float*)d_out;

    // ---- workspace layout ----
    char* wsb = (char*)d_ws;
    size_t off = 0;
    auto ALLOC = [&](size_t bytes) -> char* {
        char* p = wsb + off; off = (off + bytes + 255) & ~(size_t)255; return p;
    };
    US*  WB   = (US*)ALLOC((size_t)W_TOTAL * 2);
    US*  Ss   = (US*)ALLOC((size_t)N * 512 * 2);
    US*  z0   = (US*)ALLOC((size_t)N * 64 * 2);
    US*  z1   = (US*)ALLOC((size_t)N * 64 * 2);
    US*  aggB = (US*)ALLOC((size_t)N * 64 * 2);
    int* cnt  = (int*)ALLOC((size_t)N * 4);
    int* indp = (int*)ALLOC((size_t)(N + 1) * 4);
    int* curs = (int*)ALLOC((size_t)N * 4);
    int* esrc = (int*)ALLOC((size_t)E * 4);
    UI*  enc  = (UI*)ALLOC(4096 * 4);
    US*  geb  = (US*)ALLOC(4096 * 2);

    const int catOff[3] = {O_Cat1, O_Cat2, O_Cat3};

    WPrm pw; int si = 0;
    auto SEG = [&](const float* s, int o, int n, int rl, int ldd) {
        pw.s[si].src = s; pw.s[si].dst = o; pw.s[si].n = n; pw.s[si].rl = rl; pw.s[si].ldd = ldd; ++si;
    };
    SEG((const float*)d_in[5],  O_EmW1,          65536, 65536, 65536);
    SEG((const float*)d_in[11], O_EmW1 + 65536,  65536, 65536, 65536);
    SEG((const float*)d_in[7],  O_EmWh,          16384, 16384, 16384);
    SEG((const float*)d_in[9],  O_EmWo,          65536, 65536, 65536);
    SEG((const float*)d_in[13], O_RhoW1,         65536, 65536, 65536);
    SEG((const float*)d_in[19], O_RhoW1 + 65536, 65536, 65536, 65536);
    SEG((const float*)d_in[15], O_RhoWh,         16384, 16384, 16384);
    SEG((const float*)d_in[17], O_RhoWo,          8192,  8192,  8192);
    for (int i = 0; i < 3; ++i) {
        SEG(c_ll_W[i], catOff[i],      4096, 64, 128);
        SEG(c_lr_W[i], catOff[i] + 64, 4096, 64, 128);
    }
    SEG((const float*)d_in[30], O_H1W1,          24576, 24576, 24576);
    SEG((const float*)d_in[36], O_H1W1 + 24576,  24576, 24576, 24576);
    SEG((const float*)d_in[32], O_H1Wh,          16384, 16384, 16384);
    SEG((const float*)d_in[34], O_H1Wo,          16384, 16384, 16384);
    SEG((const float*)d_in[38], O_H2W1,          16384, 16384, 16384);
    SEG((const float*)d_in[40], O_H2Wh,          16384, 16384, 16384);
    prep_w<<<dim3(20), dim3(256), 0, stream>>>(pw, WB);

    // ---- CSR build ----
    hipMemsetAsync(cnt, 0, (size_t)N * 4, stream);
    count_k<<<dim3((E + 255) / 256), dim3(256), 0, stream>>>(eidx + E, cnt, E);
    scan_csr<<<dim3(1), dim3(1024), 0, stream>>>(cnt, N, indp, curs);
    fill_k<<<dim3((E + 255) / 256), dim3(256), 0, stream>>>(eidx, eidx + E, curs, esrc, E);

    // ---- Embedder + rho ----
    embed_fused<<<dim3(3125), dim3(1024), 0, stream>>>(x, WB, em_in_b, em_proj_b, em_hid_b, em_out_b, Ss);
    rho_fused<<<dim3((N + 63) / 64), dim3(512), 0, stream>>>(Ss, WB, rho_in_b, rho_proj_b, rho_hid_b, rho_out_b, z0, N);

    // ---- 3x SAGE residual ----
    US* zin = z0; US* zout = z1;
    for (int ci = 0; ci < 3; ++ci) {
        sage_agg<<<dim3((N + 3) / 4), dim3(256), 0, stream>>>(zin, indp, esrc, aggB, N);
        sage_gemm<<<dim3((N + 127) / 128), dim3(256), 0, stream>>>(zin, aggB, WB + catOff[ci], c_ll_b[ci], zout, N);
        US* t = zin; zin = zout; zout = t;
    }
    US* zf = zin;

    // ---- graph max-pool ----
    hipMemsetAsync(enc, 0, 4096 * 4, stream);
    segmax_k<<<dim3((N + 511) / 512), dim3(256), 0, stream>>>(zf, batch, enc, N, 128);
    decode_ge<<<dim3(16), dim3(256), 0, stream>>>(enc, geb);

    // ---- node_embeddings output ----
    copy_bf2f<<<dim3(2048), dim3(256), 0, stream>>>(zf, out, (long)N * 64);

    // ---- fused heads (64 queries/block, both sides, 16 waves/block) ----
    head_fused<<<dim3((Q + 63) / 64), dim3(1024), 0, stream>>>(
        srcq, dstq, batch, zf, geb, WB,
        h1_in_b, h1_proj_b, h1_hid_b, h1_out_b, h2_in_b, h2_hid_b, h2_out_W, h2_out_b,
        out + (size_t)N * 64, out + (size_t)N * 64 + 2 * (size_t)Q, Q);
}

// Round 14
// 1543.690 us; speedup vs baseline: 1.1891x; 1.0044x over previous
//
#include <hip/hip_runtime.h>

typedef unsigned short US;
typedef unsigned int   UI;
typedef short  short8 __attribute__((ext_vector_type(8)));
typedef US     u16x8  __attribute__((ext_vector_type(8)));
typedef float  f32x4  __attribute__((ext_vector_type(4)));

#define DEVI __device__ __forceinline__

DEVI float bf2f(US u){ UI i = ((UI)u) << 16; float f; __builtin_memcpy(&f, &i, 4); return f; }
DEVI US f2bf(float x){ UI i; __builtin_memcpy(&i, &x, 4); UI r = (i + 0x7FFFu + ((i >> 16) & 1u)) >> 16; return (US)r; }
// gelu (tanh-form as sigmoid), exp2+rcp hardware ops, no float-div sequence.
DEVI float gelu_f(float x){
    float x2 = x * x;
    float m  = x * fmaf(x2, -0.1029432f, -2.3022052f);
    float e  = __builtin_amdgcn_exp2f(m);
    return x * __builtin_amdgcn_rcpf(1.0f + e);
}
DEVI UI encf(float f){ UI u; __builtin_memcpy(&u, &f, 4); return (u & 0x80000000u) ? ~u : (u | 0x80000000u); }
DEVI float decf(UI u){ UI b = (u & 0x80000000u) ? (u ^ 0x80000000u) : ~u; float f; __builtin_memcpy(&f, &b, 4); return f; }
DEVI int swz(int r, int c, int ld){ int i = r * ld + c; return i ^ ((r & 7) << 3); }

// packed f32x2 -> bf16x2 (hardware RNE)
DEVI UI pkbf(float a, float b){ UI u; asm("v_cvt_pk_bf16_f32 %0, %1, %2" : "=v"(u) : "v"(a), "v"(b)); return u; }
DEVI void st4(US* T, int row, int col, float v0, float v1, float v2, float v3){
    uint2 p; p.x = pkbf(v0, v1); p.y = pkbf(v2, v3);
    *(uint2*)&T[swz(row, col, 256)] = p;
}
DEVI void ld4(const US* T, int row, int col, float& v0, float& v1, float& v2, float& v3){
    uint2 q = *(const uint2*)&T[swz(row, col, 256)];
    v0 = bf2f((US)(q.x & 0xffff)); v1 = bf2f((US)(q.x >> 16));
    v2 = bf2f((US)(q.y & 0xffff)); v3 = bf2f((US)(q.y >> 16));
}

// bf16 weight-buffer offsets (elements)
enum : int { O_EmW1 = 0, O_EmWh = 131072, O_EmWo = 147456, O_RhoW1 = 212992,
             O_RhoWh = 344064, O_RhoWo = 360448, O_Cat1 = 368640, O_Cat2 = 376832,
             O_Cat3 = 385024, O_H1W1 = 393216, O_H1Wh = 442368, O_H1Wo = 458752,
             O_H2W1 = 475136, O_H2Wh = 491520, W_TOTAL = 507904 };

// ---------------------------------------------------------------------------
// Double-buffered W-streaming stage (rho). SWAP=true: C^T epilogue.
// ---------------------------------------------------------------------------
template<int NT, int NKC, int NTHR, bool SWAP = false>
DEVI void stageWD(const US* __restrict__ Wg, int Kw, const US* __restrict__ A, int lda,
                  int ab0, int ab1, int ab2, int arow0, US* Wb, int tid, f32x4 (&acc)[NT])
{
    const int lane = tid & 63;
    const int wc = (tid >> 6) & 1;
    constexpr int SLAB = NT * 32 * 64;
    #pragma unroll
    for (int n = 0; n < NT; ++n) acc[n] = (f32x4){0.f, 0.f, 0.f, 0.f};
    constexpr int J = (NT * 256) / NTHR;
    u16x8 wreg[J];
    #pragma unroll
    for (int j = 0; j < J; ++j) {
        const int c = tid + NTHR * j;
        wreg[j] = *(const u16x8*)(Wg + (size_t)(c >> 3) * Kw + (c & 7) * 8);
    }
    #pragma unroll
    for (int j = 0; j < J; ++j) {
        const int c = tid + NTHR * j;
        *(u16x8*)&Wb[swz(c >> 3, (c & 7) * 8, 64)] = wreg[j];
    }
    #pragma unroll
    for (int kc = 0; kc < NKC; ++kc) {
        __syncthreads();
        if (kc + 1 < NKC) {
            #pragma unroll
            for (int j = 0; j < J; ++j) {
                const int c = tid + NTHR * j;
                wreg[j] = *(const u16x8*)(Wg + (size_t)(c >> 3) * Kw + (kc + 1) * 64 + (c & 7) * 8);
            }
        }
        const int ab = (kc == 0) ? ab0 : ((kc == 1) ? ab1 : ab2);
        const int bufr = (kc & 1) * SLAB;
        #pragma unroll
        for (int sub = 0; sub < 2; ++sub) {
            const int kk = sub * 32 + ((lane >> 4) << 3);
            short8 a = *(const short8*)&A[swz(arow0 + (lane & 15), ab + kk, lda)];
            #pragma unroll
            for (int n = 0; n < NT; ++n) {
                short8 b = *(const short8*)&Wb[bufr + swz(wc * (NT * 16) + n * 16 + (lane & 15), kk, 64)];
                if (SWAP) acc[n] = __builtin_amdgcn_mfma_f32_16x16x32_bf16(b, a, acc[n], 0, 0, 0);
                else      acc[n] = __builtin_amdgcn_mfma_f32_16x16x32_bf16(a, b, acc[n], 0, 0, 0);
            }
        }
        if (kc + 1 < NKC) {
            const int bufw = ((kc + 1) & 1) * SLAB;
            #pragma unroll
            for (int j = 0; j < J; ++j) {
                const int c = tid + NTHR * j;
                *(u16x8*)&Wb[bufw + swz(c >> 3, (c & 7) * 8, 64)] = wreg[j];
            }
        }
    }
    __syncthreads();
}

// ---------------------------------------------------------------------------
// Chained stage: per kc [bar; prefetch regs (next kc, or NEXT STAGE's slab0);
// MFMA; write regs to the slab not being read]. SWAP selects operand order.
// ---------------------------------------------------------------------------
template<int NT, int NTN, int NKC, int NTHR, bool LAST, bool SWAP = true>
DEVI void stageWC(const US* __restrict__ Wg, int Kw, const US* __restrict__ nextWg, int nKw,
                  const US* __restrict__ A, int lda, int ab0, int ab1, int ab2, int arow0,
                  US* Wb, int off0, int off1, int wrN, int tid, f32x4 (&acc)[NT])
{
    const int lane = tid & 63;
    const int wc = (tid >> 6) & 1;
    #pragma unroll
    for (int n = 0; n < NT; ++n) acc[n] = (f32x4){0.f, 0.f, 0.f, 0.f};
    constexpr int J  = (NT  * 256) / NTHR;
    constexpr int JN = (NTN * 256) / NTHR;
    constexpr int JM = (J > JN) ? J : JN;
    u16x8 wreg[JM];
    #pragma unroll
    for (int kc = 0; kc < NKC; ++kc) {
        __syncthreads();
        if (kc + 1 < NKC) {
            #pragma unroll
            for (int j = 0; j < J; ++j) {
                const int c = tid + NTHR * j;
                wreg[j] = *(const u16x8*)(Wg + (size_t)(c >> 3) * Kw + (kc + 1) * 64 + (c & 7) * 8);
            }
        } else if (!LAST) {
            #pragma unroll
            for (int j = 0; j < JN; ++j) {
                const int c = tid + NTHR * j;
                wreg[j] = *(const u16x8*)(nextWg + (size_t)(c >> 3) * nKw + (c & 7) * 8);
            }
        }
        const int ab = (kc == 0) ? ab0 : ((kc == 1) ? ab1 : ab2);
        const int rd = (kc & 1) ? off1 : off0;
        #pragma unroll
        for (int sub = 0; sub < 2; ++sub) {
            const int kk = sub * 32 + ((lane >> 4) << 3);
            short8 a = *(const short8*)&A[swz(arow0 + (lane & 15), ab + kk, lda)];
            #pragma unroll
            for (int n = 0; n < NT; ++n) {
                short8 b = *(const short8*)&Wb[rd + swz(wc * (NT * 16) + n * 16 + (lane & 15), kk, 64)];
                if (SWAP) acc[n] = __builtin_amdgcn_mfma_f32_16x16x32_bf16(b, a, acc[n], 0, 0, 0);
                else      acc[n] = __builtin_amdgcn_mfma_f32_16x16x32_bf16(a, b, acc[n], 0, 0, 0);
            }
        }
        if (kc + 1 < NKC) {
            const int wr_ = (kc & 1) ? off0 : off1;
            #pragma unroll
            for (int j = 0; j < J; ++j) {
                const int c = tid + NTHR * j;
                *(u16x8*)&Wb[wr_ + swz(c >> 3, (c & 7) * 8, 64)] = wreg[j];
            }
        } else if (!LAST) {
            #pragma unroll
            for (int j = 0; j < JN; ++j) {
                const int c = tid + NTHR * j;
                *(u16x8*)&Wb[wrN + swz(c >> 3, (c & 7) * 8, 64)] = wreg[j];
            }
        }
    }
    __syncthreads();
}

template<int NT, int NTHR>
DEVI void preloadW(const US* __restrict__ Wg, int Kw, US* Wb, int off, int tid)
{
    constexpr int J = (NT * 256) / NTHR;
    #pragma unroll
    for (int j = 0; j < J; ++j) {
        const int c = tid + NTHR * j;
        u16x8 v = *(const u16x8*)(Wg + (size_t)(c >> 3) * Kw + (c & 7) * 8);
        *(u16x8*)&Wb[off + swz(c >> 3, (c & 7) * 8, 64)] = v;
    }
}

// ---------------------------------------------------------------------------
// Fused embedder v4: chained stages + 2-deep x prefetch in S1 (pA/pB named
// register sets, unrolled 2-kc body -> static indexing; hides ~900cy HBM
// latency under 2 kc of MFMA).
// ---------------------------------------------------------------------------
__global__ __launch_bounds__(1024, 4)
void embed_fused(const float* __restrict__ x, const US* __restrict__ WB,
                 const float* __restrict__ b_in, const float* __restrict__ b_proj,
                 const float* __restrict__ b_hid, const float* __restrict__ b_out,
                 US* __restrict__ Ss)
{
    __shared__ __align__(16) US T1[128 * 256];
    __shared__ __align__(16) US Wb[2 * 16384];
    const int tid = threadIdx.x, lane = tid & 63, w = tid >> 6;
    const int wr = w >> 1, wc = w & 1;
    const int h = lane >> 4;
    const int grow0 = blockIdx.x * 128;
    const int rowT = wr * 16 + (lane & 15);

    { // ---- S1: [gelu(x@Wi+bi) | x@Wp+bp], K=512 (8 kc), SWAP, 2-deep A ----
        f32x4 acc[8];
        #pragma unroll
        for (int n = 0; n < 8; ++n) acc[n] = (f32x4){0.f, 0.f, 0.f, 0.f};
        const float* xp = x + (size_t)(grow0 + rowT) * 512 + h * 8;
        float4 pA0, pA1, pA2, pA3, pB0, pB1, pB2, pB3;
        u16x8 wreg[2];
        auto loadW = [&](int kc) {
            #pragma unroll
            for (int j = 0; j < 2; ++j) {
                const int c = tid + 1024 * j;
                wreg[j] = *(const u16x8*)(WB + O_EmW1 + (size_t)(c >> 3) * 512 + kc * 64 + (c & 7) * 8);
            }
        };
        auto writeW = [&](int buf) {
            #pragma unroll
            for (int j = 0; j < 2; ++j) {
                const int c = tid + 1024 * j;
                *(u16x8*)&Wb[buf * 16384 + swz(c >> 3, (c & 7) * 8, 64)] = wreg[j];
            }
        };
        // A prefetch depth 2: pA=kc0, pB=kc1
        pA0 = *(const float4*)(xp +   0); pA1 = *(const float4*)(xp +   4);
        pA2 = *(const float4*)(xp +  32); pA3 = *(const float4*)(xp +  36);
        loadW(0);
        pB0 = *(const float4*)(xp +  64); pB1 = *(const float4*)(xp +  68);
        pB2 = *(const float4*)(xp +  96); pB3 = *(const float4*)(xp + 100);
        writeW(0);
        #pragma unroll
        for (int k2 = 0; k2 < 4; ++k2) {
            const int kce = 2 * k2, kco = 2 * k2 + 1;
            // ---- even kc (reads buf0) ----
            __syncthreads();
            short8 a0, a1;
            {
                uint4 q;
                q.x = pkbf(pA0.x, pA0.y); q.y = pkbf(pA0.z, pA0.w);
                q.z = pkbf(pA1.x, pA1.y); q.w = pkbf(pA1.z, pA1.w);
                __builtin_memcpy(&a0, &q, 16);
                q.x = pkbf(pA2.x, pA2.y); q.y = pkbf(pA2.z, pA2.w);
                q.z = pkbf(pA3.x, pA3.y); q.w = pkbf(pA3.z, pA3.w);
                __builtin_memcpy(&a1, &q, 16);
            }
            if (kce + 2 < 8) {
                pA0 = *(const float4*)(xp + (kce + 2) * 64);
                pA1 = *(const float4*)(xp + (kce + 2) * 64 + 4);
                pA2 = *(const float4*)(xp + (kce + 2) * 64 + 32);
                pA3 = *(const float4*)(xp + (kce + 2) * 64 + 36);
            }
            loadW(kco);
            #pragma unroll
            for (int n = 0; n < 8; ++n) {
                short8 b = *(const short8*)&Wb[swz(wc * 128 + n * 16 + (lane & 15), h * 8, 64)];
                acc[n] = __builtin_amdgcn_mfma_f32_16x16x32_bf16(b, a0, acc[n], 0, 0, 0);
            }
            #pragma unroll
            for (int n = 0; n < 8; ++n) {
                short8 b = *(const short8*)&Wb[swz(wc * 128 + n * 16 + (lane & 15), 32 + h * 8, 64)];
                acc[n] = __builtin_amdgcn_mfma_f32_16x16x32_bf16(b, a1, acc[n], 0, 0, 0);
            }
            writeW(1);
            // ---- odd kc (reads buf1) ----
            __syncthreads();
            {
                uint4 q;
                q.x = pkbf(pB0.x, pB0.y); q.y = pkbf(pB0.z, pB0.w);
                q.z = pkbf(pB1.x, pB1.y); q.w = pkbf(pB1.z, pB1.w);
                __builtin_memcpy(&a0, &q, 16);
                q.x = pkbf(pB2.x, pB2.y); q.y = pkbf(pB2.z, pB2.w);
                q.z = pkbf(pB3.x, pB3.y); q.w = pkbf(pB3.z, pB3.w);
                __builtin_memcpy(&a1, &q, 16);
            }
            if (kco + 2 < 8) {
                pB0 = *(const float4*)(xp + (kco + 2) * 64);
                pB1 = *(const float4*)(xp + (kco + 2) * 64 + 4);
                pB2 = *(const float4*)(xp + (kco + 2) * 64 + 32);
                pB3 = *(const float4*)(xp + (kco + 2) * 64 + 36);
            }
            u16x8 nx;
            if (kco < 7) loadW(kco + 1);
            else         nx = *(const u16x8*)(WB + O_EmWh + (size_t)(tid >> 3) * 128 + (tid & 7) * 8);
            #pragma unroll
            for (int n = 0; n < 8; ++n) {
                short8 b = *(const short8*)&Wb[16384 + swz(wc * 128 + n * 16 + (lane & 15), h * 8, 64)];
                acc[n] = __builtin_amdgcn_mfma_f32_16x16x32_bf16(b, a0, acc[n], 0, 0, 0);
            }
            #pragma unroll
            for (int n = 0; n < 8; ++n) {
                short8 b = *(const short8*)&Wb[16384 + swz(wc * 128 + n * 16 + (lane & 15), 32 + h * 8, 64)];
                acc[n] = __builtin_amdgcn_mfma_f32_16x16x32_bf16(b, a1, acc[n], 0, 0, 0);
            }
            if (kco < 7) writeW(0);
            else         *(u16x8*)&Wb[swz(tid >> 3, (tid & 7) * 8, 64)] = nx;  // S2 slab0 -> 0
        }
        #pragma unroll
        for (int n = 0; n < 8; ++n) {
            const int col = wc * 128 + n * 16 + h * 4;
            float4 bv = (col < 128) ? *(const float4*)&b_in[col]
                                    : *(const float4*)&b_proj[col - 128];
            float v0 = acc[n][0] + bv.x, v1 = acc[n][1] + bv.y;
            float v2 = acc[n][2] + bv.z, v3 = acc[n][3] + bv.w;
            if (col < 128) { v0 = gelu_f(v0); v1 = gelu_f(v1); v2 = gelu_f(v2); v3 = gelu_f(v3); }
            st4(T1, rowT, col, v0, v1, v2, v3);
        }
    }
    { // ---- S2: U = s + gelu(t1@Wh+bh) -> T1 lo, SWAP (next = EmWo p0) ----
        f32x4 acc[4];
        stageWC<4, 8, 2, 1024, false, true>(WB + O_EmWh, 128, WB + O_EmWo, 128,
                                            T1, 256, 0, 64, 0, wr * 16,
                                            Wb, 0, 8192, 16384, tid, acc);
        #pragma unroll
        for (int n = 0; n < 4; ++n) {
            const int col = wc * 64 + n * 16 + h * 4;
            float4 bv = *(const float4*)&b_hid[col];
            float s0, s1, s2, s3;
            ld4(T1, rowT, 128 + col, s0, s1, s2, s3);
            st4(T1, rowT, col,
                gelu_f(acc[n][0] + bv.x) + s0, gelu_f(acc[n][1] + bv.y) + s1,
                gelu_f(acc[n][2] + bv.z) + s2, gelu_f(acc[n][3] + bv.w) + s3);
        }
    }
    { // ---- S3a: cols 0..255 of EmWo, sum8 (non-swap; next = EmWo p1) ----
        f32x4 acc[8];
        stageWC<8, 8, 2, 1024, false, false>(WB + O_EmWo, 128, WB + O_EmWo + (size_t)256 * 128, 128,
                                             T1, 256, 0, 64, 0, wr * 16,
                                             Wb, 16384, 0, 16384, tid, acc);
        #pragma unroll
        for (int n = 0; n < 8; ++n) {
            const int col = wc * 128 + n * 16 + (lane & 15);
            const float bv = b_out[col];
            float s = 0.f;
            #pragma unroll
            for (int r = 0; r < 4; ++r) s += gelu_f(acc[n][r] + bv);
            s += __shfl_xor(s, 16);
            if (((lane >> 4) & 1) == 0) {
                const int node = (grow0 >> 3) + wr * 2 + (lane >> 5);
                Ss[(size_t)node * 512 + col] = f2bf(s);
            }
        }
    }
    { // ---- S3b: cols 256..511, sum8 (non-swap, LAST) ----
        f32x4 acc[8];
        stageWC<8, 8, 2, 1024, true, false>(WB + O_EmWo + (size_t)256 * 128, 128, (const US*)nullptr, 0,
                                            T1, 256, 0, 64, 0, wr * 16,
                                            Wb, 16384, 0, 16384, tid, acc);
        #pragma unroll
        for (int n = 0; n < 8; ++n) {
            const int col = wc * 128 + n * 16 + (lane & 15);
            const float bv = b_out[256 + col];
            float s = 0.f;
            #pragma unroll
            for (int r = 0; r < 4; ++r) s += gelu_f(acc[n][r] + bv);
            s += __shfl_xor(s, 16);
            if (((lane >> 4) & 1) == 0) {
                const int node = (grow0 >> 3) + wr * 2 + (lane >> 5);
                Ss[(size_t)node * 512 + 256 + col] = f2bf(s);
            }
        }
    }
}

// ---------------------------------------------------------------------------
// Fused rho v2 (as R13).
// ---------------------------------------------------------------------------
__global__ __launch_bounds__(512, 2)
void rho_fused(const US* __restrict__ Ss, const US* __restrict__ WB,
               const float* __restrict__ b_in, const float* __restrict__ b_proj,
               const float* __restrict__ b_hid, const float* __restrict__ b_out,
               US* __restrict__ zo, int N)
{
    __shared__ __align__(16) US T1[64 * 256];
    __shared__ __align__(16) US Wb[256 * 64];
    const int tid = threadIdx.x, lane = tid & 63, w = tid >> 6;
    const int wr = w >> 1, wc = w & 1;
    const int h = lane >> 4;
    const int grow0 = blockIdx.x * 64;
    const int rowT = wr * 16 + (lane & 15);

    { // ---- S1: out 256, K=512, SWAP, A direct from global ----
        f32x4 acc[8];
        #pragma unroll
        for (int n = 0; n < 8; ++n) acc[n] = (f32x4){0.f, 0.f, 0.f, 0.f};
        int arow = grow0 + rowT; if (arow >= N) arow = N - 1;
        const US* sp = Ss + (size_t)arow * 512 + h * 8;
        u16x8 a0r, a1r, wreg[4];
        auto loadA = [&](int kc) {
            a0r = *(const u16x8*)(sp + kc * 64);
            a1r = *(const u16x8*)(sp + kc * 64 + 32);
        };
        auto loadW = [&](int kc) {
            #pragma unroll
            for (int j = 0; j < 4; ++j) {
                const int c = tid + 512 * j;
                wreg[j] = *(const u16x8*)(WB + O_RhoW1 + (size_t)(c >> 3) * 512 + kc * 64 + (c & 7) * 8);
            }
        };
        loadA(0); loadW(0);
        for (int kc = 0; kc < 8; ++kc) {
            __syncthreads();
            #pragma unroll
            for (int j = 0; j < 4; ++j) {
                const int c = tid + 512 * j;
                *(u16x8*)&Wb[swz(c >> 3, (c & 7) * 8, 64)] = wreg[j];
            }
            __syncthreads();
            if (kc < 7) loadW(kc + 1);
            short8 a0, a1;
            __builtin_memcpy(&a0, &a0r, 16);
            __builtin_memcpy(&a1, &a1r, 16);
            #pragma unroll
            for (int n = 0; n < 8; ++n) {
                short8 b = *(const short8*)&Wb[swz(wc * 128 + n * 16 + (lane & 15), h * 8, 64)];
                acc[n] = __builtin_amdgcn_mfma_f32_16x16x32_bf16(b, a0, acc[n], 0, 0, 0);
            }
            #pragma unroll
            for (int n = 0; n < 8; ++n) {
                short8 b = *(const short8*)&Wb[swz(wc * 128 + n * 16 + (lane & 15), 32 + h * 8, 64)];
                acc[n] = __builtin_amdgcn_mfma_f32_16x16x32_bf16(b, a1, acc[n], 0, 0, 0);
            }
            if (kc < 7) loadA(kc + 1);
        }
        __syncthreads();
        #pragma unroll
        for (int n = 0; n < 8; ++n) {
            const int col = wc * 128 + n * 16 + h * 4;
            float4 bv = (col < 128) ? *(const float4*)&b_in[col]
                                    : *(const float4*)&b_proj[col - 128];
            float v0 = acc[n][0] + bv.x, v1 = acc[n][1] + bv.y;
            float v2 = acc[n][2] + bv.z, v3 = acc[n][3] + bv.w;
            if (col < 128) { v0 = gelu_f(v0); v1 = gelu_f(v1); v2 = gelu_f(v2); v3 = gelu_f(v3); }
            st4(T1, rowT, col, v0, v1, v2, v3);
        }
    }
    { // ---- S2: RU -> T1 lo, SWAP ----
        f32x4 acc[4];
        stageWD<4, 2, 512, true>(WB + O_RhoWh, 128, T1, 256, 0, 64, 0, wr * 16, Wb, tid, acc);
        #pragma unroll
        for (int n = 0; n < 4; ++n) {
            const int col = wc * 64 + n * 16 + h * 4;
            float4 bv = *(const float4*)&b_hid[col];
            float s0, s1, s2, s3;
            ld4(T1, rowT, 128 + col, s0, s1, s2, s3);
            st4(T1, rowT, col,
                gelu_f(acc[n][0] + bv.x) + s0, gelu_f(acc[n][1] + bv.y) + s1,
                gelu_f(acc[n][2] + bv.z) + s2, gelu_f(acc[n][3] + bv.w) + s3);
        }
    }
    { // ---- S3: out 64 ----
        f32x4 acc[2];
        stageWD<2, 2, 512>(WB + O_RhoWo, 128, T1, 256, 0, 64, 0, wr * 16, Wb, tid, acc);
        #pragma unroll
        for (int n = 0; n < 2; ++n) {
            const int col = wc * 32 + n * 16 + (lane & 15);
            const float bv = b_out[col];
            #pragma unroll
            for (int r = 0; r < 4; ++r) {
                const int node = grow0 + wr * 16 + h * 4 + r;
                if (node < N) zo[(size_t)node * 64 + col] = f2bf(acc[n][r] + bv);
            }
        }
    }
}

// ---------------------------------------------------------------------------
// Fused head v7 (as R12/R13, measured 570us).
// ---------------------------------------------------------------------------
__global__ __launch_bounds__(1024, 4)
void head_fused(const int* __restrict__ srcq, const int* __restrict__ dstq,
                const int* __restrict__ batch, const US* __restrict__ z,
                const US* __restrict__ geb, const US* __restrict__ WB,
                const float* __restrict__ b1_in, const float* __restrict__ b1_proj,
                const float* __restrict__ b1_hid, const float* __restrict__ b1_out,
                const float* __restrict__ b2_in, const float* __restrict__ b2_hid,
                const float* __restrict__ w2_out, const float* __restrict__ b2_out,
                float* __restrict__ outH, float* __restrict__ outXY, int Q)
{
    __shared__ __align__(16) US A0[64 * 192];
    __shared__ __align__(16) US T1[128 * 256];
    __shared__ __align__(16) US Wb[2 * 16384];
    __shared__ float wout_s[128];
    const int tid = threadIdx.x, lane = tid & 63, w = tid >> 6;
    const int wr = w >> 1, wc = w & 1;
    const int q0 = blockIdx.x * 64;
    const int s1a = (wr < 4) ? 0 : 64;
    const int s1b = (wr < 4) ? 64 : 0;
    const int arowS1 = (wr & 3) * 16;
    const int rowS1 = (wr >> 2) * 64 + arowS1 + (lane & 15);
    const int rowT  = wr * 16 + (lane & 15);

    preloadW<8, 1024>(WB + O_H1W1, 192, Wb, 0, tid);

    { // gather: 8 threads per query row (512 threads active)
        if (tid < 512) {
            const int r = tid >> 3, hh = tid & 7;
            const int q = q0 + r;
            const int qc = (q < Q) ? q : (Q - 1);
            const int s = srcq[qc], d = dstq[qc];
            const int g = batch[s];
            *(u16x8*)&A0[swz(r, hh * 8, 192)]       = *(const u16x8*)(z + (size_t)s * 64 + hh * 8);
            *(u16x8*)&A0[swz(r, 64 + hh * 8, 192)]  = *(const u16x8*)(z + (size_t)d * 64 + hh * 8);
            *(u16x8*)&A0[swz(r, 128 + hh * 8, 192)] = *(const u16x8*)(geb + (size_t)g * 64 + hh * 8);
        }
        if (tid < 128) wout_s[tid] = w2_out[tid];
    }
    __syncthreads();
    { // xy output (f32)
        const int row = tid >> 4;
        const int qu  = tid & 15;
        #pragma unroll
        for (int jj = 0; jj < 3; ++jj) {
            const int c4 = (jj * 16 + qu) * 4;
            if (q0 + row < Q) {
                const US* p = &A0[swz(row, c4, 192)];
                float4 o;
                o.x = bf2f(p[0]); o.y = bf2f(p[1]); o.z = bf2f(p[2]); o.w = bf2f(p[3]);
                *(float4*)&outXY[(size_t)(q0 + row) * 192 + c4] = o;
            }
        }
    }
    { // S1 merged: [t1 | s1], out 256 cols, K=192 (chained: next = H1Wh)
        f32x4 acc8[8];
        stageWC<8, 4, 3, 1024, false>(WB + O_H1W1, 192, WB + O_H1Wh, 128,
                                      A0, 192, s1a, s1b, 128, arowS1,
                                      Wb, 0, 16384, 16384, tid, acc8);
        #pragma unroll
        for (int n = 0; n < 8; ++n) {
            const int col = wc * 128 + n * 16 + ((lane >> 4) << 2);
            float4 bv = (col < 128) ? *(const float4*)&b1_in[col]
                                    : *(const float4*)&b1_proj[col - 128];
            float v0 = acc8[n][0] + bv.x, v1 = acc8[n][1] + bv.y;
            float v2 = acc8[n][2] + bv.z, v3 = acc8[n][3] + bv.w;
            if (col < 128) { v0 = gelu_f(v0); v1 = gelu_f(v1); v2 = gelu_f(v2); v3 = gelu_f(v3); }
            st4(T1, rowS1, col, v0, v1, v2, v3);
        }
    }
    f32x4 acc[4];
    // S2: U = s1 + gelu(t1@Wh + bh) -> T1 lo (next = H1Wo)
    stageWC<4, 4, 2, 1024, false>(WB + O_H1Wh, 128, WB + O_H1Wo, 128,
                                  T1, 256, 0, 64, 0, wr * 16,
                                  Wb, 16384, 24576, 16384, tid, acc);
    #pragma unroll
    for (int n = 0; n < 4; ++n) {
        const int col = wc * 64 + n * 16 + ((lane >> 4) << 2);
        float4 bv = *(const float4*)&b1_hid[col];
        float s0, s1, s2, s3;
        ld4(T1, rowT, 128 + col, s0, s1, s2, s3);
        st4(T1, rowT, col,
            gelu_f(acc[n][0] + bv.x) + s0, gelu_f(acc[n][1] + bv.y) + s1,
            gelu_f(acc[n][2] + bv.z) + s2, gelu_f(acc[n][3] + bv.w) + s3);
    }
    // S3: T = relu(U@Wo + bo) -> T1 hi (next = H2W1)
    stageWC<4, 4, 2, 1024, false>(WB + O_H1Wo, 128, WB + O_H2W1, 128,
                                  T1, 256, 0, 64, 0, wr * 16,
                                  Wb, 16384, 24576, 16384, tid, acc);
    #pragma unroll
    for (int n = 0; n < 4; ++n) {
        const int col = wc * 64 + n * 16 + ((lane >> 4) << 2);
        float4 bv = *(const float4*)&b1_out[col];
        st4(T1, rowT, 128 + col,
            fmaxf(acc[n][0] + bv.x, 0.f), fmaxf(acc[n][1] + bv.y, 0.f),
            fmaxf(acc[n][2] + bv.z, 0.f), fmaxf(acc[n][3] + bv.w, 0.f));
    }
    // S4: B1 = gelu(T@W2 + b2) -> T1 lo (A = T1 hi; next = H2Wh)
    stageWC<4, 4, 2, 1024, false>(WB + O_H2W1, 128, WB + O_H2Wh, 128,
                                  T1, 256, 128, 192, 0, wr * 16,
                                  Wb, 16384, 24576, 16384, tid, acc);
    #pragma unroll
    for (int n = 0; n < 4; ++n) {
        const int col = wc * 64 + n * 16 + ((lane >> 4) << 2);
        float4 bv = *(const float4*)&b2_in[col];
        st4(T1, rowT, col,
            gelu_f(acc[n][0] + bv.x), gelu_f(acc[n][1] + bv.y),
            gelu_f(acc[n][2] + bv.z), gelu_f(acc[n][3] + bv.w));
    }
    // S5: U2 = T + gelu(B1@Wh2 + bh2) -> T1 lo (last stage)
    stageWC<4, 4, 2, 1024, true>(WB + O_H2Wh, 128, (const US*)nullptr, 0,
                                 T1, 256, 0, 64, 0, wr * 16,
                                 Wb, 16384, 24576, 16384, tid, acc);
    #pragma unroll
    for (int n = 0; n < 4; ++n) {
        const int col = wc * 64 + n * 16 + ((lane >> 4) << 2);
        float4 bv = *(const float4*)&b2_hid[col];
        float t0, t1, t2, t3;
        ld4(T1, rowT, 128 + col, t0, t1, t2, t3);
        st4(T1, rowT, col,
            gelu_f(acc[n][0] + bv.x) + t0, gelu_f(acc[n][1] + bv.y) + t1,
            gelu_f(acc[n][2] + bv.z) + t2, gelu_f(acc[n][3] + bv.w) + t3);
    }
    __syncthreads();
    // S6: scalar head: 128 rows x 8 threads, 16 cols each
    {
        const int r = tid >> 3, hh = tid & 7;
        float a = 0.f;
        u16x8 v0 = *(const u16x8*)&T1[swz(r, hh * 16, 256)];
        u16x8 v1 = *(const u16x8*)&T1[swz(r, hh * 16 + 8, 256)];
        #pragma unroll
        for (int e = 0; e < 8; ++e) {
            a += bf2f(v0[e]) * wout_s[hh * 16 + e];
            a += bf2f(v1[e]) * wout_s[hh * 16 + 8 + e];
        }
        a += __shfl_xor(a, 4);
        a += __shfl_xor(a, 2);
        a += __shfl_xor(a, 1);
        const int q = q0 + (r & 63);
        if ((lane & 7) == 0 && q < Q) outH[(size_t)(r >> 6) * Q + q] = a + b2_out[0];
    }
}

// ---------------------------------------------------------------------------
// SAGE layer: zout = zin + gelu( [agg|zin] @ Wcat^T + bl ); optional fused
// f32 node_embeddings write (bf16-rounded) on the last layer.
// ---------------------------------------------------------------------------
__global__ __launch_bounds__(256, 2)
void sage_gemm(const US* __restrict__ zin, const US* __restrict__ agg,
               const US* __restrict__ Wc, const float* __restrict__ bias,
               US* __restrict__ zout, float* __restrict__ fout, int N)
{
    __shared__ __align__(16) US As[128 * 128];
    __shared__ __align__(16) US Ws[64 * 128];
    const int tid = threadIdx.x, lane = tid & 63, w = tid >> 6;
    const int grow0 = blockIdx.x * 128;
    {
        const int r = tid >> 1, hh = tid & 1;
        int row = grow0 + r; if (row >= N) row = N - 1;
        const US* src = hh ? (zin + (size_t)row * 64) : (agg + (size_t)row * 64);
        #pragma unroll
        for (int j = 0; j < 8; ++j)
            *(u16x8*)&As[swz(r, hh * 64 + 8 * j, 128)] = *(const u16x8*)(src + 8 * j);
    }
    #pragma unroll
    for (int j = 0; j < 4; ++j) {
        const int c = tid + 256 * j;
        *(u16x8*)&Ws[swz(c >> 4, (c & 15) * 8, 128)] =
            *(const u16x8*)(Wc + (size_t)(c >> 4) * 128 + (c & 15) * 8);
    }
    __syncthreads();
    const int rbw = w * 32;
    f32x4 acc[2][4];
    #pragma unroll
    for (int m = 0; m < 2; ++m)
        #pragma unroll
        for (int n = 0; n < 4; ++n) acc[m][n] = (f32x4){0.f, 0.f, 0.f, 0.f};
    #pragma unroll
    for (int kc = 0; kc < 2; ++kc)
        #pragma unroll
        for (int sub = 0; sub < 2; ++sub) {
            const int kk = kc * 64 + sub * 32 + ((lane >> 4) << 3);
            short8 a[2], b[4];
            #pragma unroll
            for (int m = 0; m < 2; ++m) a[m] = *(const short8*)&As[swz(rbw + m * 16 + (lane & 15), kk, 128)];
            #pragma unroll
            for (int n = 0; n < 4; ++n) b[n] = *(const short8*)&Ws[swz(n * 16 + (lane & 15), kk, 128)];
            #pragma unroll
            for (int m = 0; m < 2; ++m)
                #pragma unroll
                for (int n = 0; n < 4; ++n)
                    acc[m][n] = __builtin_amdgcn_mfma_f32_16x16x32_bf16(a[m], b[n], acc[m][n], 0, 0, 0);
        }
    #pragma unroll
    for (int m = 0; m < 2; ++m) {
        const int row0 = rbw + m * 16 + ((lane >> 4) << 2);
        #pragma unroll
        for (int n = 0; n < 4; ++n) {
            const int col = n * 16 + (lane & 15);
            const float bv = bias[col];
            #pragma unroll
            for (int r = 0; r < 4; ++r) {
                const int node = grow0 + row0 + r;
                if (node < N) {
                    const float v = gelu_f(acc[m][n][r] + bv) + bf2f(zin[(size_t)node * 64 + col]);
                    const US bb = f2bf(v);
                    zout[(size_t)node * 64 + col] = bb;
                    if (fout) fout[(size_t)node * 64 + col] = bf2f(bb);
                }
            }
        }
    }
}

// ---------------------------------------------------------------------------
// Weight prep (f32 -> bf16, strided stacking)
// ---------------------------------------------------------------------------
struct WSeg { const float* src; int dst; int n; int rl; int ldd; };
struct WPrm { WSeg s[20]; };

__global__ void prep_w(WPrm p, US* __restrict__ wb)
{
    WSeg sg = p.s[blockIdx.x];
    for (int i = threadIdx.x; i < sg.n; i += 256) {
        const int idx = sg.dst + (i / sg.rl) * sg.ldd + (i % sg.rl);
        wb[idx] = f2bf(sg.src[i]);
    }
}

// ---------------------------------------------------------------------------
// CSR build + aggregate + segment max + misc
// ---------------------------------------------------------------------------
__global__ void count_k(const int* __restrict__ dst, int* __restrict__ cnt, int E)
{
    int e = blockIdx.x * 256 + threadIdx.x;
    if (e < E) atomicAdd(&cnt[dst[e]], 1);
}

__global__ void scan_csr(const int* __restrict__ cnt, int n, int* __restrict__ indp, int* __restrict__ curs)
{
    __shared__ int wsum[16];
    __shared__ int carry_s;
    const int tid = threadIdx.x, lane = tid & 63, w = tid >> 6;
    if (tid == 0) carry_s = 0;
    __syncthreads();
    for (int base = 0; base < n; base += 1024) {
        const int i = base + tid;
        const int v = (i < n) ? cnt[i] : 0;
        int s = v;
        #pragma unroll
        for (int o = 1; o < 64; o <<= 1) { int t = __shfl_up(s, o); if (lane >= o) s += t; }
        if (lane == 63) wsum[w] = s;
        __syncthreads();
        if (w == 0 && lane < 16) {
            int ws2 = wsum[lane];
            #pragma unroll
            for (int o = 1; o < 16; o <<= 1) { int t = __shfl_up(ws2, o); if (lane >= o) ws2 += t; }
            wsum[lane] = ws2;
        }
        __syncthreads();
        const int carry = carry_s;
        const int woff  = (w == 0) ? 0 : wsum[w - 1];
        if (i < n) { const int excl = carry + woff + s - v; indp[i] = excl; curs[i] = excl; }
        __syncthreads();
        if (tid == 0) carry_s = carry + wsum[15];
        __syncthreads();
    }
    if (threadIdx.x == 0) indp[n] = carry_s;
}

__global__ void fill_k(const int* __restrict__ src, const int* __restrict__ dst,
                       int* __restrict__ curs, int* __restrict__ esrc, int E)
{
    int e = blockIdx.x * 256 + threadIdx.x;
    if (e < E) { int p = atomicAdd(&curs[dst[e]], 1); esrc[p] = src[e]; }
}

__global__ void sage_agg(const US* __restrict__ z, const int* __restrict__ indp,
                         const int* __restrict__ esrc, US* __restrict__ agg, int n)
{
    const int w = blockIdx.x * 4 + (threadIdx.x >> 6);
    const int lane = threadIdx.x & 63;
    if (w >= n) return;
    const int beg = indp[w], end = indp[w + 1];
    float acc = 0.f;
    int j = beg;
    for (; j + 4 <= end; j += 4) {
        const int s0 = esrc[j], s1 = esrc[j + 1], s2 = esrc[j + 2], s3 = esrc[j + 3];
        const float v0 = bf2f(z[(size_t)s0 * 64 + lane]);
        const float v1 = bf2f(z[(size_t)s1 * 64 + lane]);
        const float v2 = bf2f(z[(size_t)s2 * 64 + lane]);
        const float v3 = bf2f(z[(size_t)s3 * 64 + lane]);
        acc += (v0 + v1) + (v2 + v3);
    }
    for (; j < end; ++j) acc += bf2f(z[(size_t)esrc[j] * 64 + lane]);
    const float d = (float)(end - beg);
    agg[(size_t)w * 64 + lane] = f2bf(acc / fmaxf(d, 1.0f));
}

__global__ void segmax_k(const US* __restrict__ z, const int* __restrict__ batch,
                         UI* __restrict__ enc, int n, int per)
{
    const int w = blockIdx.x * 4 + (threadIdx.x >> 6);
    const int lane = threadIdx.x & 63;
    const int start = w * per;
    if (start >= n) return;
    const int end = (start + per < n) ? start + per : n;
    int g = batch[start];
    float m = -3.0e38f;
    for (int i = start; i < end; ++i) {
        const int b = batch[i];
        if (b != g) { atomicMax(&enc[(size_t)g * 64 + lane], encf(m)); g = b; m = -3.0e38f; }
        m = fmaxf(m, bf2f(z[(size_t)i * 64 + lane]));
    }
    atomicMax(&enc[(size_t)g * 64 + lane], encf(m));
}

__global__ void decode_ge(const UI* __restrict__ enc, US* __restrict__ geb)
{
    const int i = blockIdx.x * 256 + threadIdx.x;
    if (i < 4096) geb[i] = f2bf(decf(enc[i]));
}

// ---------------------------------------------------------------------------
extern "C" void kernel_launch(void* const* d_in, const int* in_sizes, int n_in,
                              void* d_out, int out_size, void* d_ws, size_t ws_size,
                              hipStream_t stream)
{
    (void)in_sizes; (void)n_in; (void)out_size; (void)ws_size;

    const float* x      = (const float*)d_in[0];
    const int*   batch  = (const int*)d_in[1];
    const int*   eidx   = (const int*)d_in[2];
    const int*   srcq   = (const int*)d_in[3];
    const int*   dstq   = (const int*)d_in[4];
    const float* em_in_b   = (const float*)d_in[6];
    const float* em_hid_b  = (const float*)d_in[8];
    const float* em_out_b  = (const float*)d_in[10];
    const float* em_proj_b = (const float*)d_in[12];
    const float* rho_in_b  = (const float*)d_in[14];
    const float* rho_hid_b = (const float*)d_in[16];
    const float* rho_out_b = (const float*)d_in[18];
    const float* rho_proj_b= (const float*)d_in[20];
    const float* c_ll_W[3] = {(const float*)d_in[21], (const float*)d_in[24], (const float*)d_in[27]};
    const float* c_ll_b[3] = {(const float*)d_in[22], (const float*)d_in[25], (const float*)d_in[28]};
    const float* c_lr_W[3] = {(const float*)d_in[23], (const float*)d_in[26], (const float*)d_in[29]};
    const float* h1_in_b   = (const float*)d_in[31];
    const float* h1_hid_b  = (const float*)d_in[33];
    const float* h1_out_b  = (const float*)d_in[35];
    const float* h1_proj_b = (const float*)d_in[37];
    const float* h2_in_b   = (const float*)d_in[39];
    const float* h2_hid_b  = (const float*)d_in[41];
    const float* h2_out_W  = (const float*)d_in[42];
    const float* h2_out_b  = (const float*)d_in[43];

    const int N = 50000, E = 1600000, Q = 500000;
    float* out = (float*)d_out;

    // ---- workspace layout ----
    char* wsb = (char*)d_ws;
    size_t off = 0;
    auto ALLOC = [&](size_t bytes) -> char* {
        char* p = wsb + off; off = (off + bytes + 255) & ~(size_t)255; return p;
    };
    US*  WB   = (US*)ALLOC((size_t)W_TOTAL * 2);
    US*  Ss   = (US*)ALLOC((size_t)N * 512 * 2);
    US*  z0   = (US*)ALLOC((size_t)N * 64 * 2);
    US*  z1   = (US*)ALLOC((size_t)N * 64 * 2);
    US*  aggB = (US*)ALLOC((size_t)N * 64 * 2);
    int* cnt  = (int*)ALLOC((size_t)N * 4);
    int* indp = (int*)ALLOC((size_t)(N + 1) * 4);
    int* curs = (int*)ALLOC((size_t)N * 4);
    int* esrc = (int*)ALLOC((size_t)E * 4);
    UI*  enc  = (UI*)ALLOC(4096 * 4);
    US*  geb  = (US*)ALLOC(4096 * 2);

    const int catOff[3] = {O_Cat1, O_Cat2, O_Cat3};

    WPrm pw; int si = 0;
    auto SEG = [&](const float* s, int o, int n, int rl, int ldd) {
        pw.s[si].src = s; pw.s[si].dst = o; pw.s[si].n = n; pw.s[si].rl = rl; pw.s[si].ldd = ldd; ++si;
    };
    SEG((const float*)d_in[5],  O_EmW1,          65536, 65536, 65536);
    SEG((const float*)d_in[11], O_EmW1 + 65536,  65536, 65536, 65536);
    SEG((const float*)d_in[7],  O_EmWh,          16384, 16384, 16384);
    SEG((const float*)d_in[9],  O_EmWo,          65536, 65536, 65536);
    SEG((const float*)d_in[13], O_RhoW1,         65536, 65536, 65536);
    SEG((const float*)d_in[19], O_RhoW1 + 65536, 65536, 65536, 65536);
    SEG((const float*)d_in[15], O_RhoWh,         16384, 16384, 16384);
    SEG((const float*)d_in[17], O_RhoWo,          8192,  8192,  8192);
    for (int i = 0; i < 3; ++i) {
        SEG(c_ll_W[i], catOff[i],      4096, 64, 128);
        SEG(c_lr_W[i], catOff[i] + 64, 4096, 64, 128);
    }
    SEG((const float*)d_in[30], O_H1W1,          24576, 24576, 24576);
    SEG((const float*)d_in[36], O_H1W1 + 24576,  24576, 24576, 24576);
    SEG((const float*)d_in[32], O_H1Wh,          16384, 16384, 16384);
    SEG((const float*)d_in[34], O_H1Wo,          16384, 16384, 16384);
    SEG((const float*)d_in[38], O_H2W1,          16384, 16384, 16384);
    SEG((const float*)d_in[40], O_H2Wh,          16384, 16384, 16384);
    prep_w<<<dim3(20), dim3(256), 0, stream>>>(pw, WB);

    // ---- CSR build ----
    hipMemsetAsync(cnt, 0, (size_t)N * 4, stream);
    count_k<<<dim3((E + 255) / 256), dim3(256), 0, stream>>>(eidx + E, cnt, E);
    scan_csr<<<dim3(1), dim3(1024), 0, stream>>>(cnt, N, indp, curs);
    fill_k<<<dim3((E + 255) / 256), dim3(256), 0, stream>>>(eidx, eidx + E, curs, esrc, E);

    // ---- Embedder + rho ----
    embed_fused<<<dim3(3125), dim3(1024), 0, stream>>>(x, WB, em_in_b, em_proj_b, em_hid_b, em_out_b, Ss);
    rho_fused<<<dim3((N + 63) / 64), dim3(512), 0, stream>>>(Ss, WB, rho_in_b, rho_proj_b, rho_hid_b, rho_out_b, z0, N);

    // ---- 3x SAGE residual (last layer fuses the f32 node_embeddings out) ----
    US* zin = z0; US* zout = z1;
    for (int ci = 0; ci < 3; ++ci) {
        sage_agg<<<dim3((N + 3) / 4), dim3(256), 0, stream>>>(zin, indp, esrc, aggB, N);
        sage_gemm<<<dim3((N + 127) / 128), dim3(256), 0, stream>>>(
            zin, aggB, WB + catOff[ci], c_ll_b[ci], zout,
            (ci == 2) ? out : (float*)nullptr, N);
        US* t = zin; zin = zout; zout = t;
    }
    US* zf = zin;

    // ---- graph max-pool ----
    hipMemsetAsync(enc, 0, 4096 * 4, stream);
    segmax_k<<<dim3((N + 511) / 512), dim3(256), 0, stream>>>(zf, batch, enc, N, 128);
    decode_ge<<<dim3(16), dim3(256), 0, stream>>>(enc, geb);

    // ---- fused heads (64 queries/block, both sides, 16 waves/block) ----
    head_fused<<<dim3((Q + 63) / 64), dim3(1024), 0, stream>>>(
        srcq, dstq, batch, zf, geb, WB,
        h1_in_b, h1_proj_b, h1_hid_b, h1_out_b, h2_in_b, h2_hid_b, h2_out_W, h2_out_b,
        out + (size_t)N * 64, out + (size_t)N * 64 + 2 * (size_t)Q, Q);
}

// Round 15
// 1455.876 us; speedup vs baseline: 1.2608x; 1.0603x over previous
//
#include <hip/hip_runtime.h>

typedef unsigned short US;
typedef unsigned int   UI;
typedef short  short8 __attribute__((ext_vector_type(8)));
typedef US     u16x8  __attribute__((ext_vector_type(8)));
typedef float  f32x4  __attribute__((ext_vector_type(4)));

#define DEVI __device__ __forceinline__

DEVI float bf2f(US u){ UI i = ((UI)u) << 16; float f; __builtin_memcpy(&f, &i, 4); return f; }
DEVI US f2bf(float x){ UI i; __builtin_memcpy(&i, &x, 4); UI r = (i + 0x7FFFu + ((i >> 16) & 1u)) >> 16; return (US)r; }
// gelu (tanh-form as sigmoid), exp2+rcp hardware ops, no float-div sequence.
DEVI float gelu_f(float x){
    float x2 = x * x;
    float m  = x * fmaf(x2, -0.1029432f, -2.3022052f);
    float e  = __builtin_amdgcn_exp2f(m);
    return x * __builtin_amdgcn_rcpf(1.0f + e);
}
DEVI UI encf(float f){ UI u; __builtin_memcpy(&u, &f, 4); return (u & 0x80000000u) ? ~u : (u | 0x80000000u); }
DEVI float decf(UI u){ UI b = (u & 0x80000000u) ? (u ^ 0x80000000u) : ~u; float f; __builtin_memcpy(&f, &b, 4); return f; }
DEVI int swz(int r, int c, int ld){ int i = r * ld + c; return i ^ ((r & 7) << 3); }

// packed f32x2 -> bf16x2 (hardware RNE)
DEVI UI pkbf(float a, float b){ UI u; asm("v_cvt_pk_bf16_f32 %0, %1, %2" : "=v"(u) : "v"(a), "v"(b)); return u; }
DEVI void st4(US* T, int row, int col, float v0, float v1, float v2, float v3){
    uint2 p; p.x = pkbf(v0, v1); p.y = pkbf(v2, v3);
    *(uint2*)&T[swz(row, col, 256)] = p;
}
DEVI void ld4(const US* T, int row, int col, float& v0, float& v1, float& v2, float& v3){
    uint2 q = *(const uint2*)&T[swz(row, col, 256)];
    v0 = bf2f((US)(q.x & 0xffff)); v1 = bf2f((US)(q.x >> 16));
    v2 = bf2f((US)(q.y & 0xffff)); v3 = bf2f((US)(q.y >> 16));
}

// bf16 weight-buffer offsets (elements)
enum : int { O_EmW1 = 0, O_EmWh = 131072, O_EmWo = 147456, O_RhoW1 = 212992,
             O_RhoWh = 344064, O_RhoWo = 360448, O_Cat1 = 368640, O_Cat2 = 376832,
             O_Cat3 = 385024, O_H1W1 = 393216, O_H1Wh = 442368, O_H1Wo = 458752,
             O_H2W1 = 475136, O_H2Wh = 491520, W_TOTAL = 507904 };

// ---------------------------------------------------------------------------
// Double-buffered W-streaming stage (rho). SWAP=true: C^T epilogue.
// ---------------------------------------------------------------------------
template<int NT, int NKC, int NTHR, bool SWAP = false>
DEVI void stageWD(const US* __restrict__ Wg, int Kw, const US* __restrict__ A, int lda,
                  int ab0, int ab1, int ab2, int arow0, US* Wb, int tid, f32x4 (&acc)[NT])
{
    const int lane = tid & 63;
    const int wc = (tid >> 6) & 1;
    constexpr int SLAB = NT * 32 * 64;
    #pragma unroll
    for (int n = 0; n < NT; ++n) acc[n] = (f32x4){0.f, 0.f, 0.f, 0.f};
    constexpr int J = (NT * 256) / NTHR;
    u16x8 wreg[J];
    #pragma unroll
    for (int j = 0; j < J; ++j) {
        const int c = tid + NTHR * j;
        wreg[j] = *(const u16x8*)(Wg + (size_t)(c >> 3) * Kw + (c & 7) * 8);
    }
    #pragma unroll
    for (int j = 0; j < J; ++j) {
        const int c = tid + NTHR * j;
        *(u16x8*)&Wb[swz(c >> 3, (c & 7) * 8, 64)] = wreg[j];
    }
    #pragma unroll
    for (int kc = 0; kc < NKC; ++kc) {
        __syncthreads();
        if (kc + 1 < NKC) {
            #pragma unroll
            for (int j = 0; j < J; ++j) {
                const int c = tid + NTHR * j;
                wreg[j] = *(const u16x8*)(Wg + (size_t)(c >> 3) * Kw + (kc + 1) * 64 + (c & 7) * 8);
            }
        }
        const int ab = (kc == 0) ? ab0 : ((kc == 1) ? ab1 : ab2);
        const int bufr = (kc & 1) * SLAB;
        #pragma unroll
        for (int sub = 0; sub < 2; ++sub) {
            const int kk = sub * 32 + ((lane >> 4) << 3);
            short8 a = *(const short8*)&A[swz(arow0 + (lane & 15), ab + kk, lda)];
            #pragma unroll
            for (int n = 0; n < NT; ++n) {
                short8 b = *(const short8*)&Wb[bufr + swz(wc * (NT * 16) + n * 16 + (lane & 15), kk, 64)];
                if (SWAP) acc[n] = __builtin_amdgcn_mfma_f32_16x16x32_bf16(b, a, acc[n], 0, 0, 0);
                else      acc[n] = __builtin_amdgcn_mfma_f32_16x16x32_bf16(a, b, acc[n], 0, 0, 0);
            }
        }
        if (kc + 1 < NKC) {
            const int bufw = ((kc + 1) & 1) * SLAB;
            #pragma unroll
            for (int j = 0; j < J; ++j) {
                const int c = tid + NTHR * j;
                *(u16x8*)&Wb[bufw + swz(c >> 3, (c & 7) * 8, 64)] = wreg[j];
            }
        }
    }
    __syncthreads();
}

// ---------------------------------------------------------------------------
// Chained MR=2 stage (1024 thr): each B-fragment read feeds TWO MFMAs
// (row-sets arowA and arowA+rofB, with independent per-kc A-chunk maps
// aA*/aB* -- head S1 uses rofB=0 + swapped maps for the two sides).
// Per kc: [bar; prefetch regs (next kc or next stage slab0); MFMA; write].
// TOTC = total out cols of this stage (slab = TOTC x 64), TOTCN = next's.
// ---------------------------------------------------------------------------
template<int NT, int TOTC, int TOTCN, int NKC, bool LAST, bool SWAP>
DEVI void stageWC2(const US* __restrict__ Wg, int Kw, const US* __restrict__ nextWg, int nKw,
                   const US* __restrict__ A, int lda,
                   int aA0, int aA1, int aA2, int aB0, int aB1, int aB2,
                   int arowA, int rofB, int colb,
                   US* Wb, int off0, int off1, int wrN, int tid,
                   f32x4 (&accA)[NT], f32x4 (&accB)[NT])
{
    const int lane = tid & 63;
    const int l15 = lane & 15;
    const int h8 = (lane >> 4) << 3;
    #pragma unroll
    for (int n = 0; n < NT; ++n) {
        accA[n] = (f32x4){0.f, 0.f, 0.f, 0.f};
        accB[n] = (f32x4){0.f, 0.f, 0.f, 0.f};
    }
    constexpr int J  = TOTC  / 128;
    constexpr int JN = TOTCN / 128;
    constexpr int JM = (J > JN) ? J : JN;
    u16x8 wreg[JM];
    #pragma unroll
    for (int kc = 0; kc < NKC; ++kc) {
        __syncthreads();
        if (kc + 1 < NKC) {
            #pragma unroll
            for (int j = 0; j < J; ++j) {
                const int c = tid + 1024 * j;
                wreg[j] = *(const u16x8*)(Wg + (size_t)(c >> 3) * Kw + (kc + 1) * 64 + (c & 7) * 8);
            }
        } else if (!LAST) {
            #pragma unroll
            for (int j = 0; j < JN; ++j) {
                const int c = tid + 1024 * j;
                wreg[j] = *(const u16x8*)(nextWg + (size_t)(c >> 3) * nKw + (c & 7) * 8);
            }
        }
        const int abA = (kc == 0) ? aA0 : ((kc == 1) ? aA1 : aA2);
        const int abB = (kc == 0) ? aB0 : ((kc == 1) ? aB1 : aB2);
        const int rd = (kc & 1) ? off1 : off0;
        #pragma unroll
        for (int sub = 0; sub < 2; ++sub) {
            const int kk = sub * 32 + h8;
            short8 aA = *(const short8*)&A[swz(arowA + l15, abA + kk, lda)];
            short8 aB = *(const short8*)&A[swz(arowA + rofB + l15, abB + kk, lda)];
            #pragma unroll
            for (int n = 0; n < NT; ++n) {
                short8 b = *(const short8*)&Wb[rd + swz(colb + n * 16 + l15, kk, 64)];
                if (SWAP) {
                    accA[n] = __builtin_amdgcn_mfma_f32_16x16x32_bf16(b, aA, accA[n], 0, 0, 0);
                    accB[n] = __builtin_amdgcn_mfma_f32_16x16x32_bf16(b, aB, accB[n], 0, 0, 0);
                } else {
                    accA[n] = __builtin_amdgcn_mfma_f32_16x16x32_bf16(aA, b, accA[n], 0, 0, 0);
                    accB[n] = __builtin_amdgcn_mfma_f32_16x16x32_bf16(aB, b, accB[n], 0, 0, 0);
                }
            }
        }
        if (kc + 1 < NKC) {
            const int wr_ = (kc & 1) ? off0 : off1;
            #pragma unroll
            for (int j = 0; j < J; ++j) {
                const int c = tid + 1024 * j;
                *(u16x8*)&Wb[wr_ + swz(c >> 3, (c & 7) * 8, 64)] = wreg[j];
            }
        } else if (!LAST) {
            #pragma unroll
            for (int j = 0; j < JN; ++j) {
                const int c = tid + 1024 * j;
                *(u16x8*)&Wb[wrN + swz(c >> 3, (c & 7) * 8, 64)] = wreg[j];
            }
        }
    }
    __syncthreads();
}

template<int NT, int NTHR>
DEVI void preloadW(const US* __restrict__ Wg, int Kw, US* Wb, int off, int tid)
{
    constexpr int J = (NT * 256) / NTHR;
    #pragma unroll
    for (int j = 0; j < J; ++j) {
        const int c = tid + NTHR * j;
        u16x8 v = *(const u16x8*)(Wg + (size_t)(c >> 3) * Kw + (c & 7) * 8);
        *(u16x8*)&Wb[off + swz(c >> 3, (c & 7) * 8, 64)] = v;
    }
}

// ---------------------------------------------------------------------------
// Fused embedder v5: S1 as R14 (2-deep A prefetch); S2/S3 in MR=2 form.
// ---------------------------------------------------------------------------
__global__ __launch_bounds__(1024, 4)
void embed_fused(const float* __restrict__ x, const US* __restrict__ WB,
                 const float* __restrict__ b_in, const float* __restrict__ b_proj,
                 const float* __restrict__ b_hid, const float* __restrict__ b_out,
                 US* __restrict__ Ss)
{
    __shared__ __align__(16) US T1[128 * 256];
    __shared__ __align__(16) US Wb[2 * 16384];
    const int tid = threadIdx.x, lane = tid & 63, w = tid >> 6;
    const int wr = w >> 1, wc = w & 1;
    const int h = lane >> 4;
    const int l15 = lane & 15;
    const int grow0 = blockIdx.x * 128;
    const int rowT = wr * 16 + l15;
    // MR=2 wave map (S2/S3): 4 row-groups x 4 col-groups
    const int wr4 = w & 3, cq = w >> 2;
    const int arowA = wr4 * 16;
    const int rA = arowA + l15, rB = rA + 64;

    { // ---- S1: [gelu(x@Wi+bi) | x@Wp+bp], K=512 (8 kc), SWAP, 2-deep A ----
        f32x4 acc[8];
        #pragma unroll
        for (int n = 0; n < 8; ++n) acc[n] = (f32x4){0.f, 0.f, 0.f, 0.f};
        const float* xp = x + (size_t)(grow0 + rowT) * 512 + h * 8;
        float4 pA0, pA1, pA2, pA3, pB0, pB1, pB2, pB3;
        u16x8 wreg[2];
        auto loadW = [&](int kc) {
            #pragma unroll
            for (int j = 0; j < 2; ++j) {
                const int c = tid + 1024 * j;
                wreg[j] = *(const u16x8*)(WB + O_EmW1 + (size_t)(c >> 3) * 512 + kc * 64 + (c & 7) * 8);
            }
        };
        auto writeW = [&](int buf) {
            #pragma unroll
            for (int j = 0; j < 2; ++j) {
                const int c = tid + 1024 * j;
                *(u16x8*)&Wb[buf * 16384 + swz(c >> 3, (c & 7) * 8, 64)] = wreg[j];
            }
        };
        pA0 = *(const float4*)(xp +   0); pA1 = *(const float4*)(xp +   4);
        pA2 = *(const float4*)(xp +  32); pA3 = *(const float4*)(xp +  36);
        loadW(0);
        pB0 = *(const float4*)(xp +  64); pB1 = *(const float4*)(xp +  68);
        pB2 = *(const float4*)(xp +  96); pB3 = *(const float4*)(xp + 100);
        writeW(0);
        #pragma unroll
        for (int k2 = 0; k2 < 4; ++k2) {
            const int kce = 2 * k2, kco = 2 * k2 + 1;
            __syncthreads();
            short8 a0, a1;
            {
                uint4 q;
                q.x = pkbf(pA0.x, pA0.y); q.y = pkbf(pA0.z, pA0.w);
                q.z = pkbf(pA1.x, pA1.y); q.w = pkbf(pA1.z, pA1.w);
                __builtin_memcpy(&a0, &q, 16);
                q.x = pkbf(pA2.x, pA2.y); q.y = pkbf(pA2.z, pA2.w);
                q.z = pkbf(pA3.x, pA3.y); q.w = pkbf(pA3.z, pA3.w);
                __builtin_memcpy(&a1, &q, 16);
            }
            if (kce + 2 < 8) {
                pA0 = *(const float4*)(xp + (kce + 2) * 64);
                pA1 = *(const float4*)(xp + (kce + 2) * 64 + 4);
                pA2 = *(const float4*)(xp + (kce + 2) * 64 + 32);
                pA3 = *(const float4*)(xp + (kce + 2) * 64 + 36);
            }
            loadW(kco);
            #pragma unroll
            for (int n = 0; n < 8; ++n) {
                short8 b = *(const short8*)&Wb[swz(wc * 128 + n * 16 + l15, h * 8, 64)];
                acc[n] = __builtin_amdgcn_mfma_f32_16x16x32_bf16(b, a0, acc[n], 0, 0, 0);
            }
            #pragma unroll
            for (int n = 0; n < 8; ++n) {
                short8 b = *(const short8*)&Wb[swz(wc * 128 + n * 16 + l15, 32 + h * 8, 64)];
                acc[n] = __builtin_amdgcn_mfma_f32_16x16x32_bf16(b, a1, acc[n], 0, 0, 0);
            }
            writeW(1);
            __syncthreads();
            {
                uint4 q;
                q.x = pkbf(pB0.x, pB0.y); q.y = pkbf(pB0.z, pB0.w);
                q.z = pkbf(pB1.x, pB1.y); q.w = pkbf(pB1.z, pB1.w);
                __builtin_memcpy(&a0, &q, 16);
                q.x = pkbf(pB2.x, pB2.y); q.y = pkbf(pB2.z, pB2.w);
                q.z = pkbf(pB3.x, pB3.y); q.w = pkbf(pB3.z, pB3.w);
                __builtin_memcpy(&a1, &q, 16);
            }
            if (kco + 2 < 8) {
                pB0 = *(const float4*)(xp + (kco + 2) * 64);
                pB1 = *(const float4*)(xp + (kco + 2) * 64 + 4);
                pB2 = *(const float4*)(xp + (kco + 2) * 64 + 32);
                pB3 = *(const float4*)(xp + (kco + 2) * 64 + 36);
            }
            u16x8 nx;
            if (kco < 7) loadW(kco + 1);
            else         nx = *(const u16x8*)(WB + O_EmWh + (size_t)(tid >> 3) * 128 + (tid & 7) * 8);
            #pragma unroll
            for (int n = 0; n < 8; ++n) {
                short8 b = *(const short8*)&Wb[16384 + swz(wc * 128 + n * 16 + l15, h * 8, 64)];
                acc[n] = __builtin_amdgcn_mfma_f32_16x16x32_bf16(b, a0, acc[n], 0, 0, 0);
            }
            #pragma unroll
            for (int n = 0; n < 8; ++n) {
                short8 b = *(const short8*)&Wb[16384 + swz(wc * 128 + n * 16 + l15, 32 + h * 8, 64)];
                acc[n] = __builtin_amdgcn_mfma_f32_16x16x32_bf16(b, a1, acc[n], 0, 0, 0);
            }
            if (kco < 7) writeW(0);
            else         *(u16x8*)&Wb[swz(tid >> 3, (tid & 7) * 8, 64)] = nx;  // S2 slab0 -> 0
        }
        #pragma unroll
        for (int n = 0; n < 8; ++n) {
            const int col = wc * 128 + n * 16 + h * 4;
            float4 bv = (col < 128) ? *(const float4*)&b_in[col]
                                    : *(const float4*)&b_proj[col - 128];
            float v0 = acc[n][0] + bv.x, v1 = acc[n][1] + bv.y;
            float v2 = acc[n][2] + bv.z, v3 = acc[n][3] + bv.w;
            if (col < 128) { v0 = gelu_f(v0); v1 = gelu_f(v1); v2 = gelu_f(v2); v3 = gelu_f(v3); }
            st4(T1, rowT, col, v0, v1, v2, v3);
        }
    }
    { // ---- S2: U = s + gelu(t1@Wh+bh) -> T1 lo, SWAP, MR=2 (next EmWo) ----
        f32x4 accA[2], accB[2];
        stageWC2<2, 128, 256, 2, false, true>(WB + O_EmWh, 128, WB + O_EmWo, 128,
                                              T1, 256, 0, 64, 0, 0, 64, 0,
                                              arowA, 64, cq * 32,
                                              Wb, 0, 8192, 16384, tid, accA, accB);
        #pragma unroll
        for (int n = 0; n < 2; ++n) {
            const int col = cq * 32 + n * 16 + h * 4;
            float4 bv = *(const float4*)&b_hid[col];
            float s0, s1, s2, s3;
            ld4(T1, rA, 128 + col, s0, s1, s2, s3);
            st4(T1, rA, col,
                gelu_f(accA[n][0] + bv.x) + s0, gelu_f(accA[n][1] + bv.y) + s1,
                gelu_f(accA[n][2] + bv.z) + s2, gelu_f(accA[n][3] + bv.w) + s3);
            ld4(T1, rB, 128 + col, s0, s1, s2, s3);
            st4(T1, rB, col,
                gelu_f(accB[n][0] + bv.x) + s0, gelu_f(accB[n][1] + bv.y) + s1,
                gelu_f(accB[n][2] + bv.z) + s2, gelu_f(accB[n][3] + bv.w) + s3);
        }
    }
    // ---- S3: 2 passes of 256 cols, MR=2, non-swap, sum8 epilogue ----
    #pragma unroll
    for (int p2 = 0; p2 < 2; ++p2) {
        f32x4 accA[4], accB[4];
        if (p2 == 0)
            stageWC2<4, 256, 256, 2, false, false>(WB + O_EmWo, 128, WB + O_EmWo + (size_t)256 * 128, 128,
                                                   T1, 256, 0, 64, 0, 0, 64, 0,
                                                   arowA, 64, cq * 64,
                                                   Wb, 16384, 0, 16384, tid, accA, accB);
        else
            stageWC2<4, 256, 256, 2, true, false>(WB + O_EmWo + (size_t)256 * 128, 128, (const US*)nullptr, 0,
                                                  T1, 256, 0, 64, 0, 0, 64, 0,
                                                  arowA, 64, cq * 64,
                                                  Wb, 16384, 0, 16384, tid, accA, accB);
        #pragma unroll
        for (int n = 0; n < 4; ++n) {
            const int col = cq * 64 + n * 16 + l15;
            const float bv = b_out[p2 * 256 + col];
            float sA = 0.f, sB = 0.f;
            #pragma unroll
            for (int r = 0; r < 4; ++r) { sA += gelu_f(accA[n][r] + bv); sB += gelu_f(accB[n][r] + bv); }
            sA += __shfl_xor(sA, 16);
            sB += __shfl_xor(sB, 16);
            if (((lane >> 4) & 1) == 0) {
                const int nodeA = (grow0 >> 3) + wr4 * 2 + (lane >> 5);
                Ss[(size_t)nodeA * 512 + p2 * 256 + col] = f2bf(sA);
                Ss[(size_t)(nodeA + 8) * 512 + p2 * 256 + col] = f2bf(sB);
            }
        }
    }
}

// ---------------------------------------------------------------------------
// Fused rho v2 (as R14).
// ---------------------------------------------------------------------------
__global__ __launch_bounds__(512, 2)
void rho_fused(const US* __restrict__ Ss, const US* __restrict__ WB,
               const float* __restrict__ b_in, const float* __restrict__ b_proj,
               const float* __restrict__ b_hid, const float* __restrict__ b_out,
               US* __restrict__ zo, int N)
{
    __shared__ __align__(16) US T1[64 * 256];
    __shared__ __align__(16) US Wb[256 * 64];
    const int tid = threadIdx.x, lane = tid & 63, w = tid >> 6;
    const int wr = w >> 1, wc = w & 1;
    const int h = lane >> 4;
    const int grow0 = blockIdx.x * 64;
    const int rowT = wr * 16 + (lane & 15);

    { // ---- S1: out 256, K=512, SWAP, A direct from global ----
        f32x4 acc[8];
        #pragma unroll
        for (int n = 0; n < 8; ++n) acc[n] = (f32x4){0.f, 0.f, 0.f, 0.f};
        int arow = grow0 + rowT; if (arow >= N) arow = N - 1;
        const US* sp = Ss + (size_t)arow * 512 + h * 8;
        u16x8 a0r, a1r, wreg[4];
        auto loadA = [&](int kc) {
            a0r = *(const u16x8*)(sp + kc * 64);
            a1r = *(const u16x8*)(sp + kc * 64 + 32);
        };
        auto loadW = [&](int kc) {
            #pragma unroll
            for (int j = 0; j < 4; ++j) {
                const int c = tid + 512 * j;
                wreg[j] = *(const u16x8*)(WB + O_RhoW1 + (size_t)(c >> 3) * 512 + kc * 64 + (c & 7) * 8);
            }
        };
        loadA(0); loadW(0);
        for (int kc = 0; kc < 8; ++kc) {
            __syncthreads();
            #pragma unroll
            for (int j = 0; j < 4; ++j) {
                const int c = tid + 512 * j;
                *(u16x8*)&Wb[swz(c >> 3, (c & 7) * 8, 64)] = wreg[j];
            }
            __syncthreads();
            if (kc < 7) loadW(kc + 1);
            short8 a0, a1;
            __builtin_memcpy(&a0, &a0r, 16);
            __builtin_memcpy(&a1, &a1r, 16);
            #pragma unroll
            for (int n = 0; n < 8; ++n) {
                short8 b = *(const short8*)&Wb[swz(wc * 128 + n * 16 + (lane & 15), h * 8, 64)];
                acc[n] = __builtin_amdgcn_mfma_f32_16x16x32_bf16(b, a0, acc[n], 0, 0, 0);
            }
            #pragma unroll
            for (int n = 0; n < 8; ++n) {
                short8 b = *(const short8*)&Wb[swz(wc * 128 + n * 16 + (lane & 15), 32 + h * 8, 64)];
                acc[n] = __builtin_amdgcn_mfma_f32_16x16x32_bf16(b, a1, acc[n], 0, 0, 0);
            }
            if (kc < 7) loadA(kc + 1);
        }
        __syncthreads();
        #pragma unroll
        for (int n = 0; n < 8; ++n) {
            const int col = wc * 128 + n * 16 + h * 4;
            float4 bv = (col < 128) ? *(const float4*)&b_in[col]
                                    : *(const float4*)&b_proj[col - 128];
            float v0 = acc[n][0] + bv.x, v1 = acc[n][1] + bv.y;
            float v2 = acc[n][2] + bv.z, v3 = acc[n][3] + bv.w;
            if (col < 128) { v0 = gelu_f(v0); v1 = gelu_f(v1); v2 = gelu_f(v2); v3 = gelu_f(v3); }
            st4(T1, rowT, col, v0, v1, v2, v3);
        }
    }
    { // ---- S2: RU -> T1 lo, SWAP ----
        f32x4 acc[4];
        stageWD<4, 2, 512, true>(WB + O_RhoWh, 128, T1, 256, 0, 64, 0, wr * 16, Wb, tid, acc);
        #pragma unroll
        for (int n = 0; n < 4; ++n) {
            const int col = wc * 64 + n * 16 + h * 4;
            float4 bv = *(const float4*)&b_hid[col];
            float s0, s1, s2, s3;
            ld4(T1, rowT, 128 + col, s0, s1, s2, s3);
            st4(T1, rowT, col,
                gelu_f(acc[n][0] + bv.x) + s0, gelu_f(acc[n][1] + bv.y) + s1,
                gelu_f(acc[n][2] + bv.z) + s2, gelu_f(acc[n][3] + bv.w) + s3);
        }
    }
    { // ---- S3: out 64 ----
        f32x4 acc[2];
        stageWD<2, 2, 512>(WB + O_RhoWo, 128, T1, 256, 0, 64, 0, wr * 16, Wb, tid, acc);
        #pragma unroll
        for (int n = 0; n < 2; ++n) {
            const int col = wc * 32 + n * 16 + (lane & 15);
            const float bv = b_out[col];
            #pragma unroll
            for (int r = 0; r < 4; ++r) {
                const int node = grow0 + wr * 16 + h * 4 + r;
                if (node < N) zo[(size_t)node * 64 + col] = f2bf(acc[n][r] + bv);
            }
        }
    }
}

// ---------------------------------------------------------------------------
// Fused head v8: MR=2 row-pairing everywhere. Wave = (wr4 = w&3 row group,
// cq = w>>2 col group). S1: row-sets = the two SIDES (same A0 rows, swapped
// k-chunk maps). S2-S5: row-sets = T1 rows r and r+64.
// ---------------------------------------------------------------------------
__global__ __launch_bounds__(1024, 4)
void head_fused(const int* __restrict__ srcq, const int* __restrict__ dstq,
                const int* __restrict__ batch, const US* __restrict__ z,
                const US* __restrict__ geb, const US* __restrict__ WB,
                const float* __restrict__ b1_in, const float* __restrict__ b1_proj,
                const float* __restrict__ b1_hid, const float* __restrict__ b1_out,
                const float* __restrict__ b2_in, const float* __restrict__ b2_hid,
                const float* __restrict__ w2_out, const float* __restrict__ b2_out,
                float* __restrict__ outH, float* __restrict__ outXY, int Q)
{
    __shared__ __align__(16) US A0[64 * 192];
    __shared__ __align__(16) US T1[128 * 256];
    __shared__ __align__(16) US Wb[2 * 16384];
    __shared__ float wout_s[128];
    const int tid = threadIdx.x, lane = tid & 63, w = tid >> 6;
    const int l15 = lane & 15;
    const int h4 = (lane >> 4) << 2;
    const int q0 = blockIdx.x * 64;
    const int wr4 = w & 3, cq = w >> 2;
    const int arowA = wr4 * 16;
    const int rA = arowA + l15, rB = rA + 64;

    preloadW<8, 1024>(WB + O_H1W1, 192, Wb, 0, tid);

    { // gather: 8 threads per query row (512 threads active)
        if (tid < 512) {
            const int r = tid >> 3, hh = tid & 7;
            const int q = q0 + r;
            const int qc = (q < Q) ? q : (Q - 1);
            const int s = srcq[qc], d = dstq[qc];
            const int g = batch[s];
            *(u16x8*)&A0[swz(r, hh * 8, 192)]       = *(const u16x8*)(z + (size_t)s * 64 + hh * 8);
            *(u16x8*)&A0[swz(r, 64 + hh * 8, 192)]  = *(const u16x8*)(z + (size_t)d * 64 + hh * 8);
            *(u16x8*)&A0[swz(r, 128 + hh * 8, 192)] = *(const u16x8*)(geb + (size_t)g * 64 + hh * 8);
        }
        if (tid < 128) wout_s[tid] = w2_out[tid];
    }
    __syncthreads();
    { // xy output (f32)
        const int row = tid >> 4;
        const int qu  = tid & 15;
        #pragma unroll
        for (int jj = 0; jj < 3; ++jj) {
            const int c4 = (jj * 16 + qu) * 4;
            if (q0 + row < Q) {
                const US* p = &A0[swz(row, c4, 192)];
                float4 o;
                o.x = bf2f(p[0]); o.y = bf2f(p[1]); o.z = bf2f(p[2]); o.w = bf2f(p[3]);
                *(float4*)&outXY[(size_t)(q0 + row) * 192 + c4] = o;
            }
        }
    }
    { // S1 merged: [t1 | s1], out 256 cols, K=192; sides share B (rofB=0)
        f32x4 accA[4], accB[4];
        stageWC2<4, 256, 128, 3, false, true>(WB + O_H1W1, 192, WB + O_H1Wh, 128,
                                              A0, 192, 0, 64, 128, 64, 0, 128,
                                              arowA, 0, cq * 64,
                                              Wb, 0, 16384, 16384, tid, accA, accB);
        #pragma unroll
        for (int n = 0; n < 4; ++n) {
            const int col = cq * 64 + n * 16 + h4;
            float4 bv = (col < 128) ? *(const float4*)&b1_in[col]
                                    : *(const float4*)&b1_proj[col - 128];
            float v0 = accA[n][0] + bv.x, v1 = accA[n][1] + bv.y;
            float v2 = accA[n][2] + bv.z, v3 = accA[n][3] + bv.w;
            float u0 = accB[n][0] + bv.x, u1 = accB[n][1] + bv.y;
            float u2 = accB[n][2] + bv.z, u3 = accB[n][3] + bv.w;
            if (col < 128) {
                v0 = gelu_f(v0); v1 = gelu_f(v1); v2 = gelu_f(v2); v3 = gelu_f(v3);
                u0 = gelu_f(u0); u1 = gelu_f(u1); u2 = gelu_f(u2); u3 = gelu_f(u3);
            }
            st4(T1, rA, col, v0, v1, v2, v3);
            st4(T1, rB, col, u0, u1, u2, u3);
        }
    }
    f32x4 accA[2], accB[2];
    const int colb2 = cq * 32;
    // S2: U = s1 + gelu(t1@Wh + bh) -> T1 lo (next = H1Wo)
    stageWC2<2, 128, 128, 2, false, true>(WB + O_H1Wh, 128, WB + O_H1Wo, 128,
                                          T1, 256, 0, 64, 0, 0, 64, 0,
                                          arowA, 64, colb2,
                                          Wb, 16384, 24576, 16384, tid, accA, accB);
    #pragma unroll
    for (int n = 0; n < 2; ++n) {
        const int col = colb2 + n * 16 + h4;
        float4 bv = *(const float4*)&b1_hid[col];
        float s0, s1, s2, s3;
        ld4(T1, rA, 128 + col, s0, s1, s2, s3);
        st4(T1, rA, col,
            gelu_f(accA[n][0] + bv.x) + s0, gelu_f(accA[n][1] + bv.y) + s1,
            gelu_f(accA[n][2] + bv.z) + s2, gelu_f(accA[n][3] + bv.w) + s3);
        ld4(T1, rB, 128 + col, s0, s1, s2, s3);
        st4(T1, rB, col,
            gelu_f(accB[n][0] + bv.x) + s0, gelu_f(accB[n][1] + bv.y) + s1,
            gelu_f(accB[n][2] + bv.z) + s2, gelu_f(accB[n][3] + bv.w) + s3);
    }
    // S3: T = relu(U@Wo + bo) -> T1 hi (next = H2W1)
    stageWC2<2, 128, 128, 2, false, true>(WB + O_H1Wo, 128, WB + O_H2W1, 128,
                                          T1, 256, 0, 64, 0, 0, 64, 0,
                                          arowA, 64, colb2,
                                          Wb, 16384, 24576, 16384, tid, accA, accB);
    #pragma unroll
    for (int n = 0; n < 2; ++n) {
        const int col = colb2 + n * 16 + h4;
        float4 bv = *(const float4*)&b1_out[col];
        st4(T1, rA, 128 + col,
            fmaxf(accA[n][0] + bv.x, 0.f), fmaxf(accA[n][1] + bv.y, 0.f),
            fmaxf(accA[n][2] + bv.z, 0.f), fmaxf(accA[n][3] + bv.w, 0.f));
        st4(T1, rB, 128 + col,
            fmaxf(accB[n][0] + bv.x, 0.f), fmaxf(accB[n][1] + bv.y, 0.f),
            fmaxf(accB[n][2] + bv.z, 0.f), fmaxf(accB[n][3] + bv.w, 0.f));
    }
    // S4: B1 = gelu(T@W2 + b2) -> T1 lo (A = T1 hi; next = H2Wh)
    stageWC2<2, 128, 128, 2, false, true>(WB + O_H2W1, 128, WB + O_H2Wh, 128,
                                          T1, 256, 128, 192, 0, 128, 192, 0,
                                          arowA, 64, colb2,
                                          Wb, 16384, 24576, 16384, tid, accA, accB);
    #pragma unroll
    for (int n = 0; n < 2; ++n) {
        const int col = colb2 + n * 16 + h4;
        float4 bv = *(const float4*)&b2_in[col];
        st4(T1, rA, col,
            gelu_f(accA[n][0] + bv.x), gelu_f(accA[n][1] + bv.y),
            gelu_f(accA[n][2] + bv.z), gelu_f(accA[n][3] + bv.w));
        st4(T1, rB, col,
            gelu_f(accB[n][0] + bv.x), gelu_f(accB[n][1] + bv.y),
            gelu_f(accB[n][2] + bv.z), gelu_f(accB[n][3] + bv.w));
    }
    // S5: U2 = T + gelu(B1@Wh2 + bh2) -> T1 lo (last stage)
    stageWC2<2, 128, 128, 2, true, true>(WB + O_H2Wh, 128, (const US*)nullptr, 0,
                                         T1, 256, 0, 64, 0, 0, 64, 0,
                                         arowA, 64, colb2,
                                         Wb, 16384, 24576, 16384, tid, accA, accB);
    #pragma unroll
    for (int n = 0; n < 2; ++n) {
        const int col = colb2 + n * 16 + h4;
        float4 bv = *(const float4*)&b2_hid[col];
        float t0, t1, t2, t3;
        ld4(T1, rA, 128 + col, t0, t1, t2, t3);
        st4(T1, rA, col,
            gelu_f(accA[n][0] + bv.x) + t0, gelu_f(accA[n][1] + bv.y) + t1,
            gelu_f(accA[n][2] + bv.z) + t2, gelu_f(accA[n][3] + bv.w) + t3);
        ld4(T1, rB, 128 + col, t0, t1, t2, t3);
        st4(T1, rB, col,
            gelu_f(accB[n][0] + bv.x) + t0, gelu_f(accB[n][1] + bv.y) + t1,
            gelu_f(accB[n][2] + bv.z) + t2, gelu_f(accB[n][3] + bv.w) + t3);
    }
    __syncthreads();
    // S6: scalar head: 128 rows x 8 threads, 16 cols each
    {
        const int r = tid >> 3, hh = tid & 7;
        float a = 0.f;
        u16x8 v0 = *(const u16x8*)&T1[swz(r, hh * 16, 256)];
        u16x8 v1 = *(const u16x8*)&T1[swz(r, hh * 16 + 8, 256)];
        #pragma unroll
        for (int e = 0; e < 8; ++e) {
            a += bf2f(v0[e]) * wout_s[hh * 16 + e];
            a += bf2f(v1[e]) * wout_s[hh * 16 + 8 + e];
        }
        a += __shfl_xor(a, 4);
        a += __shfl_xor(a, 2);
        a += __shfl_xor(a, 1);
        const int q = q0 + (r & 63);
        if ((lane & 7) == 0 && q < Q) outH[(size_t)(r >> 6) * Q + q] = a + b2_out[0];
    }
}

// ---------------------------------------------------------------------------
// SAGE layer: zout = zin + gelu( [agg|zin] @ Wcat^T + bl ); optional fused
// f32 node_embeddings write (bf16-rounded) on the last layer.
// ---------------------------------------------------------------------------
__global__ __launch_bounds__(256, 2)
void sage_gemm(const US* __restrict__ zin, const US* __restrict__ agg,
               const US* __restrict__ Wc, const float* __restrict__ bias,
               US* __restrict__ zout, float* __restrict__ fout, int N)
{
    __shared__ __align__(16) US As[128 * 128];
    __shared__ __align__(16) US Ws[64 * 128];
    const int tid = threadIdx.x, lane = tid & 63, w = tid >> 6;
    const int grow0 = blockIdx.x * 128;
    {
        const int r = tid >> 1, hh = tid & 1;
        int row = grow0 + r; if (row >= N) row = N - 1;
        const US* src = hh ? (zin + (size_t)row * 64) : (agg + (size_t)row * 64);
        #pragma unroll
        for (int j = 0; j < 8; ++j)
            *(u16x8*)&As[swz(r, hh * 64 + 8 * j, 128)] = *(const u16x8*)(src + 8 * j);
    }
    #pragma unroll
    for (int j = 0; j < 4; ++j) {
        const int c = tid + 256 * j;
        *(u16x8*)&Ws[swz(c >> 4, (c & 15) * 8, 128)] =
            *(const u16x8*)(Wc + (size_t)(c >> 4) * 128 + (c & 15) * 8);
    }
    __syncthreads();
    const int rbw = w * 32;
    f32x4 acc[2][4];
    #pragma unroll
    for (int m = 0; m < 2; ++m)
        #pragma unroll
        for (int n = 0; n < 4; ++n) acc[m][n] = (f32x4){0.f, 0.f, 0.f, 0.f};
    #pragma unroll
    for (int kc = 0; kc < 2; ++kc)
        #pragma unroll
        for (int sub = 0; sub < 2; ++sub) {
            const int kk = kc * 64 + sub * 32 + ((lane >> 4) << 3);
            short8 a[2], b[4];
            #pragma unroll
            for (int m = 0; m < 2; ++m) a[m] = *(const short8*)&As[swz(rbw + m * 16 + (lane & 15), kk, 128)];
            #pragma unroll
            for (int n = 0; n < 4; ++n) b[n] = *(const short8*)&Ws[swz(n * 16 + (lane & 15), kk, 128)];
            #pragma unroll
            for (int m = 0; m < 2; ++m)
                #pragma unroll
                for (int n = 0; n < 4; ++n)
                    acc[m][n] = __builtin_amdgcn_mfma_f32_16x16x32_bf16(a[m], b[n], acc[m][n], 0, 0, 0);
        }
    #pragma unroll
    for (int m = 0; m < 2; ++m) {
        const int row0 = rbw + m * 16 + ((lane >> 4) << 2);
        #pragma unroll
        for (int n = 0; n < 4; ++n) {
            const int col = n * 16 + (lane & 15);
            const float bv = bias[col];
            #pragma unroll
            for (int r = 0; r < 4; ++r) {
                const int node = grow0 + row0 + r;
                if (node < N) {
                    const float v = gelu_f(acc[m][n][r] + bv) + bf2f(zin[(size_t)node * 64 + col]);
                    const US bb = f2bf(v);
                    zout[(size_t)node * 64 + col] = bb;
                    if (fout) fout[(size_t)node * 64 + col] = bf2f(bb);
                }
            }
        }
    }
}

// ---------------------------------------------------------------------------
// Weight prep (f32 -> bf16, strided stacking)
// ---------------------------------------------------------------------------
struct WSeg { const float* src; int dst; int n; int rl; int ldd; };
struct WPrm { WSeg s[20]; };

__global__ void prep_w(WPrm p, US* __restrict__ wb)
{
    WSeg sg = p.s[blockIdx.x];
    for (int i = threadIdx.x; i < sg.n; i += 256) {
        const int idx = sg.dst + (i / sg.rl) * sg.ldd + (i % sg.rl);
        wb[idx] = f2bf(sg.src[i]);
    }
}

// ---------------------------------------------------------------------------
// CSR build + aggregate + segment max
// ---------------------------------------------------------------------------
__global__ void count_k(const int* __restrict__ dst, int* __restrict__ cnt, int E)
{
    int e = blockIdx.x * 256 + threadIdx.x;
    if (e < E) atomicAdd(&cnt[dst[e]], 1);
}

__global__ void scan_csr(const int* __restrict__ cnt, int n, int* __restrict__ indp, int* __restrict__ curs)
{
    __shared__ int wsum[16];
    __shared__ int carry_s;
    const int tid = threadIdx.x, lane = tid & 63, w = tid >> 6;
    if (tid == 0) carry_s = 0;
    __syncthreads();
    for (int base = 0; base < n; base += 1024) {
        const int i = base + tid;
        const int v = (i < n) ? cnt[i] : 0;
        int s = v;
        #pragma unroll
        for (int o = 1; o < 64; o <<= 1) { int t = __shfl_up(s, o); if (lane >= o) s += t; }
        if (lane == 63) wsum[w] = s;
        __syncthreads();
        if (w == 0 && lane < 16) {
            int ws2 = wsum[lane];
            #pragma unroll
            for (int o = 1; o < 16; o <<= 1) { int t = __shfl_up(ws2, o); if (lane >= o) ws2 += t; }
            wsum[lane] = ws2;
        }
        __syncthreads();
        const int carry = carry_s;
        const int woff  = (w == 0) ? 0 : wsum[w - 1];
        if (i < n) { const int excl = carry + woff + s - v; indp[i] = excl; curs[i] = excl; }
        __syncthreads();
        if (tid == 0) carry_s = carry + wsum[15];
        __syncthreads();
    }
    if (threadIdx.x == 0) indp[n] = carry_s;
}

__global__ void fill_k(const int* __restrict__ src, const int* __restrict__ dst,
                       int* __restrict__ curs, int* __restrict__ esrc, int E)
{
    int e = blockIdx.x * 256 + threadIdx.x;
    if (e < E) { int p = atomicAdd(&curs[dst[e]], 1); esrc[p] = src[e]; }
}

__global__ void sage_agg(const US* __restrict__ z, const int* __restrict__ indp,
                         const int* __restrict__ esrc, US* __restrict__ agg, int n)
{
    const int w = blockIdx.x * 4 + (threadIdx.x >> 6);
    const int lane = threadIdx.x & 63;
    if (w >= n) return;
    const int beg = indp[w], end = indp[w + 1];
    float acc = 0.f;
    int j = beg;
    for (; j + 4 <= end; j += 4) {
        const int s0 = esrc[j], s1 = esrc[j + 1], s2 = esrc[j + 2], s3 = esrc[j + 3];
        const float v0 = bf2f(z[(size_t)s0 * 64 + lane]);
        const float v1 = bf2f(z[(size_t)s1 * 64 + lane]);
        const float v2 = bf2f(z[(size_t)s2 * 64 + lane]);
        const float v3 = bf2f(z[(size_t)s3 * 64 + lane]);
        acc += (v0 + v1) + (v2 + v3);
    }
    for (; j < end; ++j) acc += bf2f(z[(size_t)esrc[j] * 64 + lane]);
    const float d = (float)(end - beg);
    agg[(size_t)w * 64 + lane] = f2bf(acc / fmaxf(d, 1.0f));
}

__global__ void segmax_k(const US* __restrict__ z, const int* __restrict__ batch,
                         UI* __restrict__ enc, int n, int per)
{
    const int w = blockIdx.x * 4 + (threadIdx.x >> 6);
    const int lane = threadIdx.x & 63;
    const int start = w * per;
    if (start >= n) return;
    const int end = (start + per < n) ? start + per : n;
    int g = batch[start];
    float m = -3.0e38f;
    for (int i = start; i < end; ++i) {
        const int b = batch[i];
        if (b != g) { atomicMax(&enc[(size_t)g * 64 + lane], encf(m)); g = b; m = -3.0e38f; }
        m = fmaxf(m, bf2f(z[(size_t)i * 64 + lane]));
    }
    atomicMax(&enc[(size_t)g * 64 + lane], encf(m));
}

__global__ void decode_ge(const UI* __restrict__ enc, US* __restrict__ geb)
{
    const int i = blockIdx.x * 256 + threadIdx.x;
    if (i < 4096) geb[i] = f2bf(decf(enc[i]));
}

// ---------------------------------------------------------------------------
extern "C" void kernel_launch(void* const* d_in, const int* in_sizes, int n_in,
                              void* d_out, int out_size, void* d_ws, size_t ws_size,
                              hipStream_t stream)
{
    (void)in_sizes; (void)n_in; (void)out_size; (void)ws_size;

    const float* x      = (const float*)d_in[0];
    const int*   batch  = (const int*)d_in[1];
    const int*   eidx   = (const int*)d_in[2];
    const int*   srcq   = (const int*)d_in[3];
    const int*   dstq   = (const int*)d_in[4];
    const float* em_in_b   = (const float*)d_in[6];
    const float* em_hid_b  = (const float*)d_in[8];
    const float* em_out_b  = (const float*)d_in[10];
    const float* em_proj_b = (const float*)d_in[12];
    const float* rho_in_b  = (const float*)d_in[14];
    const float* rho_hid_b = (const float*)d_in[16];
    const float* rho_out_b = (const float*)d_in[18];
    const float* rho_proj_b= (const float*)d_in[20];
    const float* c_ll_W[3] = {(const float*)d_in[21], (const float*)d_in[24], (const float*)d_in[27]};
    const float* c_ll_b[3] = {(const float*)d_in[22], (const float*)d_in[25], (const float*)d_in[28]};
    const float* c_lr_W[3] = {(const float*)d_in[23], (const float*)d_in[26], (const float*)d_in[29]};
    const float* h1_in_b   = (const float*)d_in[31];
    const float* h1_hid_b  = (const float*)d_in[33];
    const float* h1_out_b  = (const float*)d_in[35];
    const float* h1_proj_b = (const float*)d_in[37];
    const float* h2_in_b   = (const float*)d_in[39];
    const float* h2_hid_b  = (const float*)d_in[41];
    const float* h2_out_W  = (const float*)d_in[42];
    const float* h2_out_b  = (const float*)d_in[43];

    const int N = 50000, E = 1600000, Q = 500000;
    float* out = (float*)d_out;

    // ---- workspace layout ----
    char* wsb = (char*)d_ws;
    size_t off = 0;
    auto ALLOC = [&](size_t bytes) -> char* {
        char* p = wsb + off; off = (off + bytes + 255) & ~(size_t)255; return p;
    };
    US*  WB   = (US*)ALLOC((size_t)W_TOTAL * 2);
    US*  Ss   = (US*)ALLOC((size_t)N * 512 * 2);
    US*  z0   = (US*)ALLOC((size_t)N * 64 * 2);
    US*  z1   = (US*)ALLOC((size_t)N * 64 * 2);
    US*  aggB = (US*)ALLOC((size_t)N * 64 * 2);
    int* cnt  = (int*)ALLOC((size_t)N * 4);
    int* indp = (int*)ALLOC((size_t)(N + 1) * 4);
    int* curs = (int*)ALLOC((size_t)N * 4);
    int* esrc = (int*)ALLOC((size_t)E * 4);
    UI*  enc  = (UI*)ALLOC(4096 * 4);
    US*  geb  = (US*)ALLOC(4096 * 2);

    const int catOff[3] = {O_Cat1, O_Cat2, O_Cat3};

    WPrm pw; int si = 0;
    auto SEG = [&](const float* s, int o, int n, int rl, int ldd) {
        pw.s[si].src = s; pw.s[si].dst = o; pw.s[si].n = n; pw.s[si].rl = rl; pw.s[si].ldd = ldd; ++si;
    };
    SEG((const float*)d_in[5],  O_EmW1,          65536, 65536, 65536);
    SEG((const float*)d_in[11], O_EmW1 + 65536,  65536, 65536, 65536);
    SEG((const float*)d_in[7],  O_EmWh,          16384, 16384, 16384);
    SEG((const float*)d_in[9],  O_EmWo,          65536, 65536, 65536);
    SEG((const float*)d_in[13], O_RhoW1,         65536, 65536, 65536);
    SEG((const float*)d_in[19], O_RhoW1 + 65536, 65536, 65536, 65536);
    SEG((const float*)d_in[15], O_RhoWh,         16384, 16384, 16384);
    SEG((const float*)d_in[17], O_RhoWo,          8192,  8192,  8192);
    for (int i = 0; i < 3; ++i) {
        SEG(c_ll_W[i], catOff[i],      4096, 64, 128);
        SEG(c_lr_W[i], catOff[i] + 64, 4096, 64, 128);
    }
    SEG((const float*)d_in[30], O_H1W1,          24576, 24576, 24576);
    SEG((const float*)d_in[36], O_H1W1 + 24576,  24576, 24576, 24576);
    SEG((const float*)d_in[32], O_H1Wh,          16384, 16384, 16384);
    SEG((const float*)d_in[34], O_H1Wo,          16384, 16384, 16384);
    SEG((const float*)d_in[38], O_H2W1,          16384, 16384, 16384);
    SEG((const float*)d_in[40], O_H2Wh,          16384, 16384, 16384);
    prep_w<<<dim3(20), dim3(256), 0, stream>>>(pw, WB);

    // ---- CSR build ----
    hipMemsetAsync(cnt, 0, (size_t)N * 4, stream);
    count_k<<<dim3((E + 255) / 256), dim3(256), 0, stream>>>(eidx + E, cnt, E);
    scan_csr<<<dim3(1), dim3(1024), 0, stream>>>(cnt, N, indp, curs);
    fill_k<<<dim3((E + 255) / 256), dim3(256), 0, stream>>>(eidx, eidx + E, curs, esrc, E);

    // ---- Embedder + rho ----
    embed_fused<<<dim3(3125), dim3(1024), 0, stream>>>(x, WB, em_in_b, em_proj_b, em_hid_b, em_out_b, Ss);
    rho_fused<<<dim3((N + 63) / 64), dim3(512), 0, stream>>>(Ss, WB, rho_in_b, rho_proj_b, rho_hid_b, rho_out_b, z0, N);

    // ---- 3x SAGE residual (last layer fuses the f32 node_embeddings out) ----
    US* zin = z0; US* zout = z1;
    for (int ci = 0; ci < 3; ++ci) {
        sage_agg<<<dim3((N + 3) / 4), dim3(256), 0, stream>>>(zin, indp, esrc, aggB, N);
        sage_gemm<<<dim3((N + 127) / 128), dim3(256), 0, stream>>>(
            zin, aggB, WB + catOff[ci], c_ll_b[ci], zout,
            (ci == 2) ? out : (float*)nullptr, N);
        US* t = zin; zin = zout; zout = t;
    }
    US* zf = zin;

    // ---- graph max-pool ----
    hipMemsetAsync(enc, 0, 4096 * 4, stream);
    segmax_k<<<dim3((N + 511) / 512), dim3(256), 0, stream>>>(zf, batch, enc, N, 128);
    decode_ge<<<dim3(16), dim3(256), 0, stream>>>(enc, geb);

    // ---- fused heads (64 queries/block, both sides, 16 waves/block) ----
    head_fused<<<dim3((Q + 63) / 64), dim3(1024), 0, stream>>>(
        srcq, dstq, batch, zf, geb, WB,
        h1_in_b, h1_proj_b, h1_hid_b, h1_out_b, h2_in_b, h2_hid_b, h2_out_W, h2_out_b,
        out + (size_t)N * 64, out + (size_t)N * 64 + 2 * (size_t)Q, Q);
}